// Round 1
// 1800.378 us; speedup vs baseline: 1.0148x; 1.0148x over previous
//
#include <hip/hip_runtime.h>
#include <hip/hip_bf16.h>
#include <math.h>

typedef unsigned int u32;
typedef __hip_bfloat16 bf16;
typedef __attribute__((ext_vector_type(8))) short bh8;
typedef __attribute__((ext_vector_type(4))) float fx4;
typedef __attribute__((ext_vector_type(2))) unsigned int u32x2;
typedef __attribute__((ext_vector_type(4))) unsigned int u32x4;

#define CDIM   768
#define BATCH  32
#define SEQ    513
#define NT     (BATCH*SEQ)     // 16416 rows incl cls
#define NR     16384           // BG
#define NHEAD  12
#define HD     64
#define FFDIM  3072
#define NCLUST 2048
#define D1SEG  6272
#define NVIEW  6
#define MIDD   12
#define H1N    6
#define N1V    128
#define NB1    128
#define CHROWS 8208            // FFN row chunk (2 chunks)

// ---------------- workspace layout (float-slot offsets; ≈229.8 MB total) ----
#define A_FS      ((size_t)0)          // 6,303,744 fs : y / obuf / y2 / yv  (NT*768 bf16)
#define B_FS      ((size_t)6303744)    // 18,911,232 fs: qkv bf16 | h+xffn bf16 | qkv1a+o1all+svs
#define X1_FS     ((size_t)25214976)   // 6,303,744 fs : x1 bf16
#define AH_FS     ((size_t)31518720)   // 262,656 fs   : ah fp32
#define D_FS      ((size_t)31781376)   // 9,640,064 fs : index arrays | bf16 weights
#define DTOT_FS   9640064
#define X3D_FS    ((size_t)(D_FS + DTOT_FS))          // 1,572,864 fs x3d fp32
#define BNV_FS    (X3D_FS + 1572864)                  // 14,450,688 fs bnv bf16
#define STATM_FS  (BNV_FS + 14450688)                 // 768
#define STATR_FS  (STATM_FS + 768)                    // 768
#define DI_CNT    (D_FS)
#define DI_BASE   (D_FS + 6272)
#define DI_CUR    (D_FS + 12544)
#define DI_ORD    (D_FS + 18816)
#define DW_FS     (D_FS + 40960)
#define DWV_FS    (D_FS + 3600000)

__device__ inline float b2f(bf16 v){ return __bfloat162float(v); }
__device__ inline float ldv(const float* p, size_t i){ return p[i]; }
__device__ inline float ldv(const bf16*  p, size_t i){ return __bfloat162float(p[i]); }
__device__ inline void  stv(float* p, size_t i, float v){ p[i] = v; }
__device__ inline void  stv(bf16*  p, size_t i, float v){ p[i] = __float2bfloat16(v); }
__device__ inline short f2bs(float f){ bf16 h = __float2bfloat16(f); return *(short*)&h; }
__device__ inline void gload_lds16(const bf16* g, short* l){
    __builtin_amdgcn_global_load_lds((const __attribute__((address_space(1))) void*)g,
                                     (__attribute__((address_space(3))) void*)l, 16, 0, 0);
}
// gfx950 LDS transpose-read: per-lane address, 4 bf16 at +0/+32/+64/+96 bytes
__device__ inline u32x2 ds_tr16(unsigned a){
    u32x2 d;
    asm volatile("ds_read_b64_tr_b16 %0, %1" : "=v"(d) : "v"(a));
    return d;
}

// ---------------- utility ----------------

__global__ __launch_bounds__(256) void k_zero(float* p, int n){
    for (int i = blockIdx.x*256 + threadIdx.x; i < n; i += gridDim.x*256) p[i] = 0.0f;
}

__global__ __launch_bounds__(256) void k_f2b(const float* __restrict__ in, bf16* __restrict__ out, int n){
    for (int i = blockIdx.x*256 + threadIdx.x; i < n; i += gridDim.x*256)
        out[i] = __float2bfloat16(in[i]);
}

// LayerNorm over C=768, one block per row; out bf16
template<typename TI>
__global__ __launch_bounds__(256) void k_ln(const TI* __restrict__ in, bf16* __restrict__ out,
                                            const float* __restrict__ g, const float* __restrict__ b){
    int i = blockIdx.x;
    int tid = threadIdx.x;
    const TI* r = in + (size_t)i*CDIM;
    float v0 = ldv(r,(size_t)tid), v1 = ldv(r,(size_t)tid+256), v2 = ldv(r,(size_t)tid+512);
    float s  = v0+v1+v2;
    float s2 = v0*v0+v1*v1+v2*v2;
    __shared__ float t1[4], t2[4];
    #pragma unroll
    for (int o=32;o;o>>=1){ s += __shfl_down(s,o,64); s2 += __shfl_down(s2,o,64); }
    int lane = tid & 63, wid = tid >> 6;
    if (!lane){ t1[wid]=s; t2[wid]=s2; }
    __syncthreads();
    float S  = t1[0]+t1[1]+t1[2]+t1[3];
    float S2 = t2[0]+t2[1]+t2[2]+t2[3];
    float m  = S * (1.0f/CDIM);
    float var = S2 * (1.0f/CDIM) - m*m;
    float rstd = rsqrtf(var + 1e-5f);
    bf16* o_ = out + (size_t)i*CDIM;
    stv(o_,(size_t)tid,     (v0-m)*rstd*g[tid]     + b[tid]);
    stv(o_,(size_t)tid+256, (v1-m)*rstd*g[tid+256] + b[tid+256]);
    stv(o_,(size_t)tid+512, (v2-m)*rstd*g[tid+512] + b[tid+512]);
}

// normalize-only LN (affine folded into downstream weights), token-row map on input
__global__ __launch_bounds__(256) void k_lnn(const float* __restrict__ in, bf16* __restrict__ out){
    int i = blockIdx.x;
    size_t ri = (size_t)(i + (i>>9) + 1);
    int tid = threadIdx.x;
    const float* r = in + ri*CDIM;
    float v0 = r[tid], v1 = r[tid+256], v2 = r[tid+512];
    float s  = v0+v1+v2;
    float s2 = v0*v0+v1*v1+v2*v2;
    __shared__ float t1[4], t2[4];
    #pragma unroll
    for (int o=32;o;o>>=1){ s += __shfl_down(s,o,64); s2 += __shfl_down(s2,o,64); }
    int lane = tid & 63, wid = tid >> 6;
    if (!lane){ t1[wid]=s; t2[wid]=s2; }
    __syncthreads();
    float S  = t1[0]+t1[1]+t1[2]+t1[3];
    float S2 = t2[0]+t2[1]+t2[2]+t2[3];
    float m  = S * (1.0f/CDIM);
    float var = S2 * (1.0f/CDIM) - m*m;
    float rstd = rsqrtf(var + 1e-5f);
    bf16* o_ = out + (size_t)i*CDIM;
    stv(o_,(size_t)tid,     (v0-m)*rstd);
    stv(o_,(size_t)tid+256, (v1-m)*rstd);
    stv(o_,(size_t)tid+512, (v2-m)*rstd);
}

// fold per-view LN affine into view-qkv weights
__global__ __launch_bounds__(256) void k_foldw(const float* __restrict__ aqw, const float* __restrict__ aqb,
                                               const float* __restrict__ n3g, const float* __restrict__ n3b,
                                               bf16* __restrict__ Wv, float* __restrict__ bv){
    int row = blockIdx.x;                  // 0..215
    int v = row/36;
    const float* w = aqw + (size_t)row*768;
    const float* g = n3g + v*768;
    const float* b = n3b + v*768;
    int tid = threadIdx.x;
    float s = 0.0f;
    #pragma unroll
    for (int j=tid; j<768; j+=256){
        float wv = w[j];
        Wv[(size_t)row*768 + j] = __float2bfloat16(wv*g[j]);
        s += wv*b[j];
    }
    __shared__ float t1[4];
    #pragma unroll
    for (int o=32;o;o>>=1) s += __shfl_down(s,o,64);
    int lane = tid & 63, wid = tid >> 6;
    if (!lane) t1[wid]=s;
    __syncthreads();
    if (tid==0) bv[row] = aqb[row] + t1[0]+t1[1]+t1[2]+t1[3];
}

// ---------------- MFMA GEMM (async global_load_lds staging + XOR swizzle) ----------------
// out[M,N] = A[M,K](bf16) @ W[N,K]^T(bf16) + bias. 128x128 tile, BK=32, 4 waves of 64x64.
// 1D grid + m204 bijective XCD-chunked remap: each XCD owns a contiguous row-major band
// of tiles -> A-panel reuse stays inside one (non-coherent) per-XCD L2.
template<typename TO, int ACT, int RES>
__global__ __launch_bounds__(256) void k_gemm_mfma(const bf16* __restrict__ A, const bf16* __restrict__ W,
                                                   const float* __restrict__ bias, const float* __restrict__ res,
                                                   TO* __restrict__ out, int M, int N, int K){
    __shared__ short As[128*32];
    __shared__ short Ws[128*32];
    int nbx = (N + 127) >> 7;
    int nwg = gridDim.x;
    int orig = blockIdx.x;
    int xcd = orig & 7, sl = orig >> 3;
    int q8 = nwg >> 3, r8 = nwg & 7;
    int wg = (xcd < r8 ? xcd*(q8+1) : r8*(q8+1) + (xcd - r8)*q8) + sl;
    int by = wg / nbx;
    int bm = by*128, bn = (wg - by*nbx)*128;
    int tid = threadIdx.x, wid = tid>>6, lane = tid&63, quad = lane>>4, l16 = lane&15;
    int wr = (wid>>1)*64, wc = (wid&1)*64;
    fx4 acc[4][4];
    #pragma unroll
    for (int i=0;i<4;i++)
        #pragma unroll
        for (int j=0;j<4;j++) acc[i][j] = (fx4){0.f,0.f,0.f,0.f};
    // staging: wave wid covers rows [wid*32, wid*32+32), 2 calls of 16 rows each
    int lrow = lane>>2;
    int gchunk = (lane&3) ^ ((lane>>3)&3);           // global k-chunk (XOR swizzle)
    int r0a0 = wid*32 + lrow,  r0a1 = wid*32 + 16 + lrow;
    int ra0 = bm + r0a0; if (ra0 > M-1) ra0 = M-1;
    int ra1 = bm + r0a1; if (ra1 > M-1) ra1 = M-1;
    int rw0 = bn + r0a0; if (rw0 > N-1) rw0 = N-1;
    int rw1 = bn + r0a1; if (rw1 > N-1) rw1 = N-1;
    const bf16* pa0 = A + (size_t)ra0*K + gchunk*8;
    const bf16* pa1 = A + (size_t)ra1*K + gchunk*8;
    const bf16* pw0 = W + (size_t)rw0*K + gchunk*8;
    const bf16* pw1 = W + (size_t)rw1*K + gchunk*8;
    short* la0 = &As[(wid*32)*32];
    short* la1 = &As[(wid*32 + 16)*32];
    short* lw0 = &Ws[(wid*32)*32];
    short* lw1 = &Ws[(wid*32 + 16)*32];
    int slotx = (l16>>1)&3;                          // read-side swizzle component
    for (int k0=0; k0<K; k0+=32){
        gload_lds16(pa0 + k0, la0);
        gload_lds16(pa1 + k0, la1);
        gload_lds16(pw0 + k0, lw0);
        gload_lds16(pw1 + k0, lw1);
        __syncthreads();
        bh8 af[4], bf_[4];
        int sa = (quad ^ slotx)*8;
        #pragma unroll
        for (int i=0;i<4;i++) af[i]  = *(const bh8*)&As[(wr + i*16 + l16)*32 + sa];
        #pragma unroll
        for (int j=0;j<4;j++) bf_[j] = *(const bh8*)&Ws[(wc + j*16 + l16)*32 + sa];
        #pragma unroll
        for (int i=0;i<4;i++)
            #pragma unroll
            for (int j=0;j<4;j++)
                acc[i][j] = __builtin_amdgcn_mfma_f32_16x16x32_bf16(af[i], bf_[j], acc[i][j], 0,0,0);
        __syncthreads();
    }
    #pragma unroll
    for (int i=0;i<4;i++){
        #pragma unroll
        for (int r=0;r<4;r++){
            int row = bm + wr + i*16 + quad*4 + r;
            if (row >= M) continue;
            #pragma unroll
            for (int j=0;j<4;j++){
                int col = bn + wc + j*16 + l16;
                if (col >= N) continue;
                float v = acc[i][j][r] + bias[col];
                if (ACT == 1) v = v / (1.0f + __expf(-1.702f*v));
                if (RES) v += res[(size_t)row*N + col];
                stv(out, (size_t)row*N + col, v);
            }
        }
    }
}

// ---------------- flash MFMA attention ----------------
// 1D grid 3456, XCD-affine: the 9 q-tiles of one (b,h) run back-to-back on ONE XCD
// (id%8 selects XCD) so K/V stay in that XCD's L2.
// V staged with vector stores into a tr-subtiled layout, consumed via ds_read_b64_tr_b16.
// Ps strip chunk-XOR-swizzled (2-way = free). Softmax scale folded into Q (exact).
#define KSTR 72
__global__ __launch_bounds__(256) void k_attn_mfma(const bf16* __restrict__ qkv, bf16* __restrict__ obuf){
    __shared__ short Ks[64*KSTR];      // [k][d] row-major, stride 72
    __shared__ short Vs[64*KSTR];      // subtiled: s=(k>>2)*4+(d>>4), S=s^(2*(s>>3)); elem=S*72+(k&3)*16+(d&15)
    __shared__ short Ps[4*16*KSTR];    // per-wave P strip [16 q][64 k], chunk-XOR swizzle
    int id = blockIdx.x;
    int qt = (id>>3) % 9;
    int bh = (id&7) + ((id/72)<<3);
    int h = bh % NHEAD, b = bh / NHEAD;
    int tid = threadIdx.x, wid = tid>>6, lane = tid&63, quad = lane>>4, l16 = lane&15;
    size_t base = (size_t)b*SEQ*2304;
    int q_own = qt*64 + wid*16 + l16;
    int q_cl  = q_own > 512 ? 512 : q_own;
    const bf16* qrow = qkv + base + (size_t)q_cl*2304 + h*HD;
    bh8 qa0 = *(const bh8*)(qrow + quad*8);
    bh8 qa1 = *(const bh8*)(qrow + 32 + quad*8);
    {   // fold softmax scale 1/8 into Q once (exact pow2 scale in bf16)
        union { bh8 v; short s[8]; } u0, u1;
        u0.v = qa0; u1.v = qa1;
        #pragma unroll
        for (int j=0;j<8;j++){
            bf16 a = *(bf16*)&u0.s[j]; u0.s[j] = f2bs(0.125f*b2f(a));
            bf16 c = *(bf16*)&u1.s[j]; u1.s[j] = f2bs(0.125f*b2f(c));
        }
        qa0 = u0.v; qa1 = u1.v;
    }
    fx4 o[4];
    #pragma unroll
    for (int d=0; d<4; d++) o[d] = (fx4){0.f,0.f,0.f,0.f};
    float mrow[4] = {-1e30f,-1e30f,-1e30f,-1e30f};
    float lrow[4] = {0.f,0.f,0.f,0.f};
    int srow = tid>>2, d0 = (tid&3)*16;
    // V store target (vector b128s, aggregate-optimal banks)
    int s_st = (srow>>2)*4 + (tid&3);
    int vsb  = (s_st ^ ((srow>>3)<<1))*KSTR + (srow&3)*16;
    // Ps store/read pointers with chunk-XOR swizzle ch' = ch ^ 2*((row>>2)&3)
    int h8 = l16>>3, l7 = l16&7;
    short* psw[4];
    #pragma unroll
    for (int nt=0;nt<4;nt++)
        psw[nt] = &Ps[(wid*16 + quad*4)*KSTR + (((nt<<1)|h8) ^ (quad<<1))*8 + l7];
    int swr = (l16>>2)<<1;
    const short* prd0 = &Ps[(wid*16+l16)*KSTR + ((quad ^ swr))*8];
    const short* prd1 = &Ps[(wid*16+l16)*KSTR + (((4|quad) ^ swr))*8];
    unsigned vls = (unsigned)(size_t)(__attribute__((address_space(3))) short*)Vs + 2u*l16;
    #define TRA(hf,c,dt) (vls + 144u*(unsigned)(((32*(hf) + 8*quad + 4*(c) + (dt)) ^ (8*(hf) + 2*quad))))
    for (int kt=0; kt<9; kt++){
        int kg = kt*64 + srow; if (kg > 512) kg = 512;   // clamp; last-tile mask zeroes P anyway
        const bf16* krow = qkv + base + 768 + (size_t)kg*2304 + h*HD + d0;
        bh8 kv0 = *(const bh8*)(krow);
        bh8 kv1 = *(const bh8*)(krow + 8);
        bh8 vv0 = *(const bh8*)(krow + 768);
        bh8 vv1 = *(const bh8*)(krow + 776);
        *(bh8*)&Ks[srow*KSTR + d0]     = kv0;
        *(bh8*)&Ks[srow*KSTR + d0 + 8] = kv1;
        *(bh8*)&Vs[vsb]     = vv0;
        *(bh8*)&Vs[vsb + 8] = vv1;
        __syncthreads();
        fx4 s[4];
        #pragma unroll
        for (int nt=0; nt<4; nt++){
            bh8 kb0 = *(const bh8*)&Ks[(nt*16+l16)*KSTR + quad*8];
            bh8 kb1 = *(const bh8*)&Ks[(nt*16+l16)*KSTR + 32 + quad*8];
            fx4 a = (fx4){0.f,0.f,0.f,0.f};
            a = __builtin_amdgcn_mfma_f32_16x16x32_bf16(qa0, kb0, a, 0,0,0);
            a = __builtin_amdgcn_mfma_f32_16x16x32_bf16(qa1, kb1, a, 0,0,0);
            s[nt] = a;
        }
        // issue V^T transpose-reads early; latency hides under softmax
        u32x2 tv[16];
        #pragma unroll
        for (int dt=0; dt<4; dt++){
            tv[dt*4+0] = ds_tr16(TRA(0,0,dt));
            tv[dt*4+1] = ds_tr16(TRA(0,1,dt));
            tv[dt*4+2] = ds_tr16(TRA(1,0,dt));
            tv[dt*4+3] = ds_tr16(TRA(1,1,dt));
        }
        float tmax[4] = {-1e30f,-1e30f,-1e30f,-1e30f};
        if (kt < 8){
            #pragma unroll
            for (int nt=0; nt<4; nt++)
                #pragma unroll
                for (int r=0;r<4;r++) tmax[r] = fmaxf(tmax[r], s[nt][r]);
        } else {
            #pragma unroll
            for (int nt=0; nt<4; nt++){
                bool ok = (nt==0) && (l16==0);          // only k==512 valid in last tile
                #pragma unroll
                for (int r=0;r<4;r++){
                    float v = ok ? s[nt][r] : -1e30f;
                    s[nt][r] = v;
                    tmax[r] = fmaxf(tmax[r], v);
                }
            }
        }
        #pragma unroll
        for (int msk=1; msk<16; msk<<=1)
            #pragma unroll
            for (int r=0;r<4;r++) tmax[r] = fmaxf(tmax[r], __shfl_xor(tmax[r], msk, 64));
        bool grow = (tmax[0]>mrow[0])|(tmax[1]>mrow[1])|(tmax[2]>mrow[2])|(tmax[3]>mrow[3]);
        if (__any(grow)){                                // exact: skipped only when al==1
            #pragma unroll
            for (int r=0;r<4;r++){
                float mn = fmaxf(mrow[r], tmax[r]);
                float al = __expf(mrow[r] - mn);
                mrow[r] = mn;
                lrow[r] *= al;
                #pragma unroll
                for (int d=0; d<4; d++) o[d][r] *= al;
            }
        }
        float ps[4] = {0.f,0.f,0.f,0.f};
        #pragma unroll
        for (int nt=0; nt<4; nt++)
            #pragma unroll
            for (int r=0;r<4;r++){
                float p = __expf(s[nt][r] - mrow[r]);
                s[nt][r] = p;
                ps[r] += p;
            }
        #pragma unroll
        for (int msk=1; msk<16; msk<<=1)
            #pragma unroll
            for (int r=0;r<4;r++) ps[r] += __shfl_xor(ps[r], msk, 64);
        #pragma unroll
        for (int r=0;r<4;r++) lrow[r] += ps[r];
        #pragma unroll
        for (int nt=0; nt<4; nt++)
            #pragma unroll
            for (int r=0;r<4;r++) psw[nt][r*KSTR] = f2bs(s[nt][r]);
        bh8 pa0 = *(const bh8*)prd0;
        bh8 pa1 = *(const bh8*)prd1;
        asm volatile("s_waitcnt lgkmcnt(0)" ::: "memory");
        __builtin_amdgcn_sched_barrier(0);
        #pragma unroll
        for (int dt=0; dt<4; dt++){
            union { u32x4 u; bh8 h; } v0, v1;
            v0.u = (u32x4){tv[dt*4+0][0], tv[dt*4+0][1], tv[dt*4+1][0], tv[dt*4+1][1]};
            v1.u = (u32x4){tv[dt*4+2][0], tv[dt*4+2][1], tv[dt*4+3][0], tv[dt*4+3][1]};
            o[dt] = __builtin_amdgcn_mfma_f32_16x16x32_bf16(pa0, v0.h, o[dt], 0,0,0);
            o[dt] = __builtin_amdgcn_mfma_f32_16x16x32_bf16(pa1, v1.h, o[dt], 0,0,0);
        }
        __syncthreads();
    }
    #undef TRA
    float inv[4];
    #pragma unroll
    for (int r=0;r<4;r++) inv[r] = 1.0f/lrow[r];
    #pragma unroll
    for (int r=0;r<4;r++){
        int q = qt*64 + wid*16 + quad*4 + r;
        if (q < SEQ){
            size_t ob = ((size_t)(b*SEQ+q))*CDIM + h*HD;
            #pragma unroll
            for (int dt=0; dt<4; dt++)
                obuf[ob + dt*16 + l16] = __float2bfloat16(o[dt][r]*inv[r]);
        }
    }
}

// x2 = x1 + xffn + 0.5*(ah @ Wa2^T + ba2) -> d_out (fp32); block per row
__global__ __launch_bounds__(256) void k_comb(const bf16* __restrict__ x1, const bf16* __restrict__ xffn,
                                              const float* __restrict__ ah, const float* __restrict__ Wa2,
                                              const float* __restrict__ ba2, float* __restrict__ x2){
    int i = blockIdx.x; int tid = threadIdx.x;
    __shared__ float ar[16];
    if (tid < 16) ar[tid] = ah[(size_t)i*16 + tid];
    __syncthreads();
    for (int c=tid; c<CDIM; c+=256){
        const float* w = Wa2 + (size_t)c*16;
        float a = ba2[c];
        #pragma unroll
        for (int mm=0; mm<16; mm++) a += ar[mm]*w[mm];
        size_t o = (size_t)i*CDIM + c;
        x2[o] = b2f(x1[o]) + b2f(xffn[o]) + 0.5f*a;
    }
}

// ---------------- segment index build ----------------
__global__ __launch_bounds__(256) void k_icount(const int* __restrict__ idx, int* __restrict__ cnt, int n){
    int i = blockIdx.x*256 + threadIdx.x;
    if (i < n) atomicAdd(&cnt[idx[i]], 1);
}

__global__ __launch_bounds__(256) void k_iscan(const int* __restrict__ cnt, int* __restrict__ base,
                                               int* __restrict__ cur, int nseg){
    __shared__ int part[256], off[256];
    int t = threadIdx.x;
    int chunk = (nseg + 255) >> 8;
    int j0 = t*chunk, j1 = j0 + chunk; if (j1 > nseg) j1 = nseg;
    int s = 0;
    for (int j=j0; j<j1; j++) s += cnt[j];
    part[t] = s; __syncthreads();
    if (t == 0){ int acc=0; for (int i=0;i<256;i++){ off[i]=acc; acc+=part[i]; } }
    __syncthreads();
    int acc = off[t];
    for (int j=j0; j<j1; j++){ base[j]=acc; cur[j]=acc; acc+=cnt[j]; }
}

__global__ __launch_bounds__(256) void k_iscatter(const int* __restrict__ idx, int* __restrict__ cur,
                                                  int* __restrict__ order, int n){
    int i = blockIdx.x*256 + threadIdx.x;
    if (i < n){
        int pos = atomicAdd(&cur[idx[i]], 1);
        order[pos] = i;
    }
}

// gather + segment max/mean for cluster path
__global__ __launch_bounds__(256) void k_gather_seg(const float* __restrict__ outx, const int* __restrict__ basep,
                                                    const int* __restrict__ cntp, const int* __restrict__ order,
                                                    float* __restrict__ dst){
    int sg = blockIdx.x; int tid = threadIdx.x;
    int n = cntp[sg], b0 = basep[sg];
    float mx[3] = {-1e30f,-1e30f,-1e30f};
    float sm[3] = {0.f,0.f,0.f};
    for (int r=0; r<n; r++){
        int i = order[b0+r];
        size_t rb = (size_t)(i + (i>>9) + 1)*CDIM;
        #pragma unroll
        for (int j=0;j<3;j++){
            float v = outx[rb + tid + j*256];
            mx[j] = fmaxf(mx[j], v); sm[j] += v;
        }
    }
    float den = (float)(n > 1 ? n : 1);
    size_t db = (size_t)sg*CDIM;
    #pragma unroll
    for (int j=0;j<3;j++)
        dst[db + tid + j*256] = (n > 0 ? mx[j] : 0.f) + sm[j]/den;
}

// per-view: flat = o1@Wp^T + bp + feat, then segment max/mean
__global__ __launch_bounds__(256) void k_gather_flat(const float* __restrict__ outx, const float* __restrict__ o1v,
                                                     const float* __restrict__ Wp, const float* __restrict__ bp,
                                                     const int* __restrict__ basep, const int* __restrict__ cntp,
                                                     const int* __restrict__ order, float* __restrict__ dst){
    int sg = blockIdx.x; int tid = threadIdx.x;
    int n = cntp[sg], b0 = basep[sg];
    float w[3][MIDD], bb[3];
    #pragma unroll
    for (int j=0;j<3;j++){
        int c = tid + j*256;
        bb[j] = bp[c];
        #pragma unroll
        for (int mm=0;mm<MIDD;mm++) w[j][mm] = Wp[(size_t)c*MIDD + mm];
    }
    float mx[3] = {-1e30f,-1e30f,-1e30f};
    float sm[3] = {0.f,0.f,0.f};
    for (int r=0; r<n; r++){
        int i = order[b0+r];
        const float* orow = o1v + (size_t)i*MIDD;
        float ov[MIDD];
        #pragma unroll
        for (int mm=0;mm<MIDD;mm++) ov[mm] = orow[mm];
        size_t rb = (size_t)(i + (i>>9) + 1)*CDIM;
        #pragma unroll
        for (int j=0;j<3;j++){
            float a = bb[j];
            #pragma unroll
            for (int mm=0;mm<MIDD;mm++) a += ov[mm]*w[j][mm];
            a += outx[rb + tid + j*256];
            mx[j] = fmaxf(mx[j], a); sm[j] += a;
        }
    }
    float den = (float)(n > 1 ? n : 1);
    size_t db = (size_t)sg*CDIM;
    #pragma unroll
    for (int j=0;j<3;j++)
        dst[db + tid + j*256] = (n > 0 ? mx[j] : 0.f) + sm[j]/den;
}

// two-stage column stats
__global__ __launch_bounds__(256) void k_colstats_part(const float* __restrict__ in, int rows,
                                                       float* __restrict__ sumv, float* __restrict__ sumsq){
    int c = blockIdx.x*256 + threadIdx.x;
    if (c >= CDIM) return;
    int chunk = (rows + 31) >> 5;
    int r0 = blockIdx.y*chunk;
    int r1 = r0 + chunk; if (r1 > rows) r1 = rows;
    float s = 0.0f, s2 = 0.0f;
    for (int r=r0; r<r1; r++){
        float v = in[(size_t)r*CDIM + c];
        s += v; s2 += v*v;
    }
    atomicAdd(&sumv[c], s);
    atomicAdd(&sumsq[c], s2);
}

__global__ __launch_bounds__(256) void k_colfin(float* __restrict__ sumv, float* __restrict__ sumsq, int rows){
    int c = blockIdx.x*256 + threadIdx.x;
    if (c >= CDIM) return;
    float m = sumv[c] / (float)rows;
    float var = sumsq[c] / (float)rows - m*m;
    sumv[c]  = m;
    sumsq[c] = rsqrtf(fmaxf(var, 0.0f) + 1e-5f);
}

template<typename TO>
__global__ __launch_bounds__(256) void k_bngelu(const float* __restrict__ in, TO* __restrict__ outp,
                                                const float* __restrict__ m, const float* __restrict__ r,
                                                const float* __restrict__ g, const float* __restrict__ b, int n){
    int i = blockIdx.x*256 + threadIdx.x;
    if (i >= n) return;
    int c = i - (i/CDIM)*CDIM;
    float y = (in[i]-m[c])*r[c]*g[c] + b[c];
    stv(outp, (size_t)i, 0.5f*y*(1.0f + erff(y*0.70710678118654752f)));
}

// per-view micro attention: block per (segblock, view); 256 threads = 2 head-groups x 128 rows.
// mask tile + Q/K/V staged in LDS once per block, shared by all 6 heads.
#define MSTR 33    // mask row stride in dwords (132 B)
__global__ __launch_bounds__(256) void k_attnv(const float* __restrict__ qkv1a,
                                               const unsigned char* __restrict__ mask,
                                               float* __restrict__ o1all){
    __shared__ float Qs[N1V][13], Ksv[N1V][13], Vsv[N1V][13];
    __shared__ int   Ms[N1V*MSTR];
    int blk = blockIdx.x, v = blockIdx.y;
    int tid = threadIdx.x;
    // stage Q/K/V: threads 0..127, one row each (9 float4 = 36 floats)
    if (tid < N1V){
        const float4* rp = (const float4*)(qkv1a + (size_t)(blk*N1V + tid)*216 + v*36);
        #pragma unroll
        for (int j=0;j<3;j++){
            float4 q4 = rp[j], k4 = rp[3+j], v4 = rp[6+j];
            Qs[tid][j*4+0]=q4.x; Qs[tid][j*4+1]=q4.y; Qs[tid][j*4+2]=q4.z; Qs[tid][j*4+3]=q4.w;
            Ksv[tid][j*4+0]=k4.x; Ksv[tid][j*4+1]=k4.y; Ksv[tid][j*4+2]=k4.z; Ksv[tid][j*4+3]=k4.w;
            Vsv[tid][j*4+0]=v4.x; Vsv[tid][j*4+1]=v4.y; Vsv[tid][j*4+2]=v4.z; Vsv[tid][j*4+3]=v4.w;
        }
    }
    // stage mask tile (16 KB) coalesced, write at stride 132 B
    {
        const int4* mp = (const int4*)(mask + ((size_t)v*NB1 + blk)*N1V*N1V);
        #pragma unroll
        for (int it=0; it<4; it++){
            int e = tid + it*256;            // 0..1023 int4s
            int4 m4 = mp[e];
            int row = e >> 3, c4 = (e & 7)*4;
            Ms[row*MSTR + c4 + 0] = m4.x;
            Ms[row*MSTR + c4 + 1] = m4.y;
            Ms[row*MSTR + c4 + 2] = m4.z;
            Ms[row*MSTR + c4 + 3] = m4.w;
        }
    }
    __syncthreads();
    int n = tid & 127, hg = tid >> 7;
    const float scale = 0.28867513459481287f; // 12^-0.5
    #pragma unroll
    for (int hh=0; hh<3; hh++){
        int h = hg*3 + hh;
        float q0 = Qs[n][h*2], q1 = Qs[n][h*2+1];
        float m = -1e30f;
        #pragma unroll 4
        for (int k4=0; k4<32; k4++){
            int mw = Ms[n*MSTR + k4];
            #pragma unroll
            for (int j=0;j<4;j++){
                int k = k4*4 + j;
                float s = (q0*Ksv[k][h*2] + q1*Ksv[k][h*2+1])*scale + (((mw>>(j*8))&0xFF) ? -100000.0f : 0.0f);
                m = fmaxf(m, s);
            }
        }
        float l = 0.f, o0 = 0.f, o1v = 0.f;
        #pragma unroll 4
        for (int k4=0; k4<32; k4++){
            int mw = Ms[n*MSTR + k4];
            #pragma unroll
            for (int j=0;j<4;j++){
                int k = k4*4 + j;
                float s = (q0*Ksv[k][h*2] + q1*Ksv[k][h*2+1])*scale + (((mw>>(j*8))&0xFF) ? -100000.0f : 0.0f);
                float p = __expf(s - m);
                l += p; o0 += p*Vsv[k][h*2]; o1v += p*Vsv[k][h*2+1];
            }
        }
        float inv = 1.0f/l;
        float* orow = o1all + ((size_t)v*NR + blk*N1V + n)*MIDD + h*2;
        orow[0] = o0*inv; orow[1] = o1v*inv;
    }
}

// cossim + sims-normalize + weighted sum + residual; block per token row; in-place on d_out
__global__ __launch_bounds__(256) void k_final(float* __restrict__ outx, const float* __restrict__ x3d,
                                               const bf16* __restrict__ bnv, const int* __restrict__ cluster,
                                               const int* __restrict__ fgi){
    int i = blockIdx.x; int tid = threadIdx.x;
    int cl = cluster[i];
    const float* xr = x3d + (size_t)cl*CDIM;
    const bf16* pr[NVIEW];
    #pragma unroll
    for (int v=0; v<NVIEW; v++)
        pr[v] = bnv + ((size_t)v*D1SEG + fgi[(size_t)v*NR + i])*CDIM;
    size_t rb = (size_t)(i + (i>>9) + 1)*CDIM;
    float pv[NVIEW][3], ft[3];
    float dotv[NVIEW] = {0,0,0,0,0,0};
    float np2[NVIEW]  = {0,0,0,0,0,0};
    float nx2 = 0.0f;
    #pragma unroll
    for (int j=0; j<3; j++){
        int c = tid + j*256;
        float xv = xr[c]; nx2 += xv*xv;
        ft[j] = outx[rb + c];
        #pragma unroll
        for (int v=0; v<NVIEW; v++){
            float p = b2f(pr[v][c]); pv[v][j] = p;
            dotv[v] += p*xv; np2[v] += p*p;
        }
    }
    __shared__ float part[4*13];
    __shared__ float ssim[NVIEW];
    float vals[13];
    vals[0] = nx2;
    #pragma unroll
    for (int v=0; v<NVIEW; v++){ vals[1+v] = dotv[v]; vals[7+v] = np2[v]; }
    int lane = tid & 63, wid = tid >> 6;
    #pragma unroll
    for (int k=0; k<13; k++){
        float w = vals[k];
        #pragma unroll
        for (int o=32;o;o>>=1) w += __shfl_down(w,o,64);
        if (!lane) part[wid*13 + k] = w;
    }
    __syncthreads();
    if (tid == 0){
        float tot[13];
        #pragma unroll
        for (int k=0; k<13; k++) tot[k] = part[k] + part[13+k] + part[26+k] + part[39+k];
        float nb = fmaxf(sqrtf(tot[0]), 1e-8f);
        float sv[NVIEW]; float ssumv = 0.0f;
        #pragma unroll
        for (int v=0; v<NVIEW; v++){
            float na = fmaxf(sqrtf(tot[7+v]), 1e-8f);
            float cs = tot[1+v] / (na*nb);
            sv[v] = (cs + 1.0f)*0.5f;
            ssumv += sv[v];
        }
        #pragma unroll
        for (int v=0; v<NVIEW; v++) ssim[v] = sv[v]/ssumv;
    }
    __syncthreads();
    #pragma unroll
    for (int j=0; j<3; j++){
        int c = tid + j*256;
        float xs = 0.0f;
        #pragma unroll
        for (int v=0; v<NVIEW; v++) xs += ssim[v]*pv[v][j];
        outx[rb + c] = ft[j] + 0.3f*xs;
    }
}

// ---------------- host launcher ----------------
extern "C" void kernel_launch(void* const* d_in, const int* in_sizes, int n_in,
                              void* d_out, int out_size, void* d_ws, size_t ws_size,
                              hipStream_t stream){
    const float* x     = (const float*)d_in[0];
    const float* ln1g  = (const float*)d_in[1];
    const float* ln1b  = (const float*)d_in[2];
    const float* ln2g  = (const float*)d_in[3];
    const float* ln2b  = (const float*)d_in[4];
    const float* Wqkv  = (const float*)d_in[5];
    const float* bqkv  = (const float*)d_in[6];
    const float* Wo    = (const float*)d_in[7];
    const float* bo    = (const float*)d_in[8];
    const float* Wfc   = (const float*)d_in[9];
    const float* bfc   = (const float*)d_in[10];
    const float* Wproj = (const float*)d_in[11];
    const float* bproj = (const float*)d_in[12];
    const float* Wa1   = (const float*)d_in[13];
    const float* ba1   = (const float*)d_in[14];
    const float* Wa2   = (const float*)d_in[15];
    const float* ba2   = (const float*)d_in[16];
    const float* bn3dg = (const float*)d_in[17];
    const float* bn3db = (const float*)d_in[18];
    const float* bn1dg = (const float*)d_in[19];
    const float* bn1db = (const float*)d_in[20];
    const float* n3g   = (const float*)d_in[21];
    const float* n3b   = (const float*)d_in[22];
    const float* aqw   = (const float*)d_in[23];
    const float* aqb   = (const float*)d_in[24];
    const float* apw   = (const float*)d_in[25];
    const float* apb   = (const float*)d_in[26];
    const int*   cluster = (const int*)d_in[27];
    const int*   fgi     = (const int*)d_in[28];
    const unsigned char* mask = (const unsigned char*)d_in[29];
    float* out = (float*)d_out;
    float* ws  = (float*)d_ws;

    bf16*  yb    = (bf16*)(ws + A_FS);
    bf16*  qkvb  = (bf16*)(ws + B_FS);
    bf16*  hb    = (bf16*)(ws + B_FS);          // FFN hidden chunk (8208 rows)
    bf16*  xffb  = (bf16*)(ws + B_FS + 12607488);
    float* qkv1a = ws + B_FS;                   // phase 2
    float* o1all = ws + B_FS + 3538944;
    float* svs   = ws + B_FS + 4718592;
    bf16*  x1b   = (bf16*)(ws + X1_FS);
    float* ah    = ws + AH_FS;
    int*   icnt  = (int*)(ws + DI_CNT);
    int*   ibase = (int*)(ws + DI_BASE);
    int*   icur  = (int*)(ws + DI_CUR);
    int*   iord  = (int*)(ws + DI_ORD);
    float* x3d   = ws + X3D_FS;
    bf16*  bnv   = (bf16*)(ws + BNV_FS);
    float* statm = ws + STATM_FS;
    float* statr = ws + STATR_FS;
    bf16* WqkvB  = (bf16*)(ws + DW_FS);
    bf16* WoB    = WqkvB + 2304*768;
    bf16* WfcB   = WoB   + 768*768;
    bf16* WprojB = WfcB  + 3072*768;
    bf16* WvB    = (bf16*)(ws + DWV_FS);        // 216x768
    float* bvP   = ws + DWV_FS + 82944;
    bf16* Wa1B   = (bf16*)(ws + DWV_FS + 83200);

    // 0. weight conversion / folding
    k_f2b<<<1024, 256, 0, stream>>>(Wqkv,  WqkvB,  2304*768);
    k_f2b<<<1024, 256, 0, stream>>>(Wo,    WoB,    768*768);
    k_f2b<<<1024, 256, 0, stream>>>(Wfc,   WfcB,   3072*768);
    k_f2b<<<1024, 256, 0, stream>>>(Wproj, WprojB, 768*3072);
    k_f2b<<<48, 256, 0, stream>>>(Wa1, Wa1B, 16*768);
    k_foldw<<<216, 256, 0, stream>>>(aqw, aqb, n3g, n3b, WvB, bvP);
    // 1. LN1
    k_ln<float><<<NT, 256, 0, stream>>>(x, yb, ln1g, ln1b);
    // 2. qkv GEMM
    k_gemm_mfma<bf16,0,0><<<(2304/128)*((NT+127)/128), 256, 0, stream>>>(yb, WqkvB, bqkv, nullptr, qkvb, NT, 2304, 768);
    // 3. flash attention (1D XCD-affine grid: 8 * 9 * 48 = 3456)
    k_attn_mfma<<<3456, 256, 0, stream>>>(qkvb, yb);
    // 4. o-proj + residual(x)
    k_gemm_mfma<bf16,0,1><<<(768/128)*((NT+127)/128), 256, 0, stream>>>(yb, WoB, bo, x, x1b, NT, 768, 768);
    // 5. LN2
    k_ln<bf16><<<NT, 256, 0, stream>>>(x1b, yb, ln2g, ln2b);
    // 6/7. FFN in 2 row-chunks
    for (int cch=0; cch<2; cch++){
        const bf16* a2 = yb + (size_t)cch*CHROWS*CDIM;
        bf16* xo = xffb + (size_t)cch*CHROWS*CDIM;
        k_gemm_mfma<bf16,1,0><<<(FFDIM/128)*((CHROWS+127)/128), 256, 0, stream>>>(a2, WfcB, bfc, nullptr, hb, CHROWS, FFDIM, 768);
        k_gemm_mfma<bf16,0,0><<<(768/128)*((CHROWS+127)/128), 256, 0, stream>>>(hb, WprojB, bproj, nullptr, xo, CHROWS, 768, FFDIM);
    }
    // 8. adapt hidden
    k_gemm_mfma<float,1,0><<<1*((NT+127)/128), 256, 0, stream>>>(xffb, Wa1B, ba1, nullptr, ah, NT, 16, 768);
    // 9. combine -> d_out
    k_comb<<<NT, 256, 0, stream>>>(x1b, xffb, ah, Wa2, ba2, out);
    // 10. cluster path
    k_zero<<<32, 256, 0, stream>>>((float*)icnt, NCLUST);
    k_icount<<<NR/256, 256, 0, stream>>>(cluster, icnt, NR);
    k_iscan<<<1, 256, 0, stream>>>(icnt, ibase, icur, NCLUST);
    k_iscatter<<<NR/256, 256, 0, stream>>>(cluster, icur, iord, NR);
    k_gather_seg<<<NCLUST, 256, 0, stream>>>(out, ibase, icnt, iord, x3d);
    k_zero<<<6, 256, 0, stream>>>(statm, 1536);
    k_colstats_part<<<dim3(3, 32), 256, 0, stream>>>(x3d, NCLUST, statm, statr);
    k_colfin<<<3, 256, 0, stream>>>(statm, statr, NCLUST);
    k_bngelu<float><<<(NCLUST*CDIM+255)/256, 256, 0, stream>>>(x3d, x3d, statm, statr, bn3dg, bn3db, NCLUST*CDIM);
    // 11. view shared prep
    k_lnn<<<NR, 256, 0, stream>>>(out, yb);
    k_gemm_mfma<float,0,0><<<2*(NR/128), 256, 0, stream>>>(yb, WvB, bvP, nullptr, qkv1a, NR, 216, 768);
    k_attnv<<<dim3(NB1, NVIEW), 256, 0, stream>>>(qkv1a, mask, o1all);
    // 12. per-view: index build + fused flat-gather + bn stats + gelu
    for (int v=0; v<NVIEW; v++){
        const int* fv = fgi + (size_t)v*NR;
        k_zero<<<32, 256, 0, stream>>>((float*)icnt, D1SEG);
        k_icount<<<NR/256, 256, 0, stream>>>(fv, icnt, NR);
        k_iscan<<<1, 256, 0, stream>>>(icnt, ibase, icur, D1SEG);
        k_iscatter<<<NR/256, 256, 0, stream>>>(fv, icur, iord, NR);
        k_gather_flat<<<D1SEG, 256, 0, stream>>>(out, o1all + (size_t)v*NR*MIDD,
                                                 apw + (size_t)v*CDIM*MIDD, apb + (size_t)v*CDIM,
                                                 ibase, icnt, iord, svs);
        k_zero<<<6, 256, 0, stream>>>(statm, 1536);
        k_colstats_part<<<dim3(3, 32), 256, 0, stream>>>(svs, D1SEG, statm, statr);
        k_colfin<<<3, 256, 0, stream>>>(statm, statr, D1SEG);
        k_bngelu<bf16><<<(D1SEG*CDIM+255)/256, 256, 0, stream>>>(svs, bnv + (size_t)v*D1SEG*CDIM, statm, statr,
                                                                 bn1dg + v*CDIM, bn1db + v*CDIM, D1SEG*CDIM);
    }
    // 13. final combine
    k_final<<<NR, 256, 0, stream>>>(out, x3d, bnv, cluster, fgi);
}

// Round 2
// 1733.662 us; speedup vs baseline: 1.0539x; 1.0385x over previous
//
#include <hip/hip_runtime.h>
#include <hip/hip_bf16.h>
#include <math.h>

typedef unsigned int u32;
typedef __hip_bfloat16 bf16;
typedef __attribute__((ext_vector_type(8))) short bh8;
typedef __attribute__((ext_vector_type(4))) float fx4;
typedef __attribute__((ext_vector_type(2))) unsigned int u32x2;
typedef __attribute__((ext_vector_type(4))) unsigned int u32x4;

#define CDIM   768
#define BATCH  32
#define SEQ    513
#define NT     (BATCH*SEQ)     // 16416 rows incl cls
#define NR     16384           // BG
#define NHEAD  12
#define HD     64
#define FFDIM  3072
#define NCLUST 2048
#define D1SEG  6272
#define NVIEW  6
#define MIDD   12
#define H1N    6
#define N1V    128
#define NB1    128
#define CHROWS 8208            // FFN row chunk (2 chunks)

// ---------------- workspace layout (float-slot offsets; ≈229.8 MB total) ----
#define A_FS      ((size_t)0)          // 6,303,744 fs : y / obuf / y2 / yv  (NT*768 bf16)
#define B_FS      ((size_t)6303744)    // 18,911,232 fs: qkv bf16 | h+xffn bf16 | qkv1a+o1all+svs
#define X1_FS     ((size_t)25214976)   // 6,303,744 fs : x1 bf16
#define AH_FS     ((size_t)31518720)   // 262,656 fs   : ah fp32
#define D_FS      ((size_t)31781376)   // 9,640,064 fs : index arrays | bf16 weights
#define DTOT_FS   9640064
#define X3D_FS    ((size_t)(D_FS + DTOT_FS))          // 1,572,864 fs x3d fp32
#define BNV_FS    (X3D_FS + 1572864)                  // 14,450,688 fs bnv bf16
#define STATM_FS  (BNV_FS + 14450688)                 // 768
#define STATR_FS  (STATM_FS + 768)                    // 768
#define DI_CNT    (D_FS)
#define DI_BASE   (D_FS + 6272)
#define DI_CUR    (D_FS + 12544)
#define DI_ORD    (D_FS + 18816)
#define DW_FS     (D_FS + 40960)
#define DWV_FS    (D_FS + 3600000)

__device__ inline float b2f(bf16 v){ return __bfloat162float(v); }
__device__ inline float ldv(const float* p, size_t i){ return p[i]; }
__device__ inline float ldv(const bf16*  p, size_t i){ return __bfloat162float(p[i]); }
__device__ inline void  stv(float* p, size_t i, float v){ p[i] = v; }
__device__ inline void  stv(bf16*  p, size_t i, float v){ p[i] = __float2bfloat16(v); }
__device__ inline short f2bs(float f){ bf16 h = __float2bfloat16(f); return *(short*)&h; }
__device__ inline void gload_lds16(const bf16* g, short* l){
    __builtin_amdgcn_global_load_lds((const __attribute__((address_space(1))) void*)g,
                                     (__attribute__((address_space(3))) void*)l, 16, 0, 0);
}
// gfx950 LDS transpose-read: per-lane address, 4 bf16 at +0/+32/+64/+96 bytes
__device__ inline u32x2 ds_tr16(unsigned a){
    u32x2 d;
    asm volatile("ds_read_b64_tr_b16 %0, %1" : "=v"(d) : "v"(a));
    return d;
}

// ---------------- utility ----------------

__global__ __launch_bounds__(256) void k_zero(float* p, int n){
    for (int i = blockIdx.x*256 + threadIdx.x; i < n; i += gridDim.x*256) p[i] = 0.0f;
}

__global__ __launch_bounds__(256) void k_f2b(const float* __restrict__ in, bf16* __restrict__ out, int n){
    for (int i = blockIdx.x*256 + threadIdx.x; i < n; i += gridDim.x*256)
        out[i] = __float2bfloat16(in[i]);
}

// LayerNorm over C=768, one block per row; out bf16
template<typename TI>
__global__ __launch_bounds__(256) void k_ln(const TI* __restrict__ in, bf16* __restrict__ out,
                                            const float* __restrict__ g, const float* __restrict__ b){
    int i = blockIdx.x;
    int tid = threadIdx.x;
    const TI* r = in + (size_t)i*CDIM;
    float v0 = ldv(r,(size_t)tid), v1 = ldv(r,(size_t)tid+256), v2 = ldv(r,(size_t)tid+512);
    float s  = v0+v1+v2;
    float s2 = v0*v0+v1*v1+v2*v2;
    __shared__ float t1[4], t2[4];
    #pragma unroll
    for (int o=32;o;o>>=1){ s += __shfl_down(s,o,64); s2 += __shfl_down(s2,o,64); }
    int lane = tid & 63, wid = tid >> 6;
    if (!lane){ t1[wid]=s; t2[wid]=s2; }
    __syncthreads();
    float S  = t1[0]+t1[1]+t1[2]+t1[3];
    float S2 = t2[0]+t2[1]+t2[2]+t2[3];
    float m  = S * (1.0f/CDIM);
    float var = S2 * (1.0f/CDIM) - m*m;
    float rstd = rsqrtf(var + 1e-5f);
    bf16* o_ = out + (size_t)i*CDIM;
    stv(o_,(size_t)tid,     (v0-m)*rstd*g[tid]     + b[tid]);
    stv(o_,(size_t)tid+256, (v1-m)*rstd*g[tid+256] + b[tid+256]);
    stv(o_,(size_t)tid+512, (v2-m)*rstd*g[tid+512] + b[tid+512]);
}

// normalize-only LN (affine folded into downstream weights), token-row map on input
__global__ __launch_bounds__(256) void k_lnn(const float* __restrict__ in, bf16* __restrict__ out){
    int i = blockIdx.x;
    size_t ri = (size_t)(i + (i>>9) + 1);
    int tid = threadIdx.x;
    const float* r = in + ri*CDIM;
    float v0 = r[tid], v1 = r[tid+256], v2 = r[tid+512];
    float s  = v0+v1+v2;
    float s2 = v0*v0+v1*v1+v2*v2;
    __shared__ float t1[4], t2[4];
    #pragma unroll
    for (int o=32;o;o>>=1){ s += __shfl_down(s,o,64); s2 += __shfl_down(s2,o,64); }
    int lane = tid & 63, wid = tid >> 6;
    if (!lane){ t1[wid]=s; t2[wid]=s2; }
    __syncthreads();
    float S  = t1[0]+t1[1]+t1[2]+t1[3];
    float S2 = t2[0]+t2[1]+t2[2]+t2[3];
    float m  = S * (1.0f/CDIM);
    float var = S2 * (1.0f/CDIM) - m*m;
    float rstd = rsqrtf(var + 1e-5f);
    bf16* o_ = out + (size_t)i*CDIM;
    stv(o_,(size_t)tid,     (v0-m)*rstd);
    stv(o_,(size_t)tid+256, (v1-m)*rstd);
    stv(o_,(size_t)tid+512, (v2-m)*rstd);
}

// fold per-view LN affine into view-qkv weights
__global__ __launch_bounds__(256) void k_foldw(const float* __restrict__ aqw, const float* __restrict__ aqb,
                                               const float* __restrict__ n3g, const float* __restrict__ n3b,
                                               bf16* __restrict__ Wv, float* __restrict__ bv){
    int row = blockIdx.x;                  // 0..215
    int v = row/36;
    const float* w = aqw + (size_t)row*768;
    const float* g = n3g + v*768;
    const float* b = n3b + v*768;
    int tid = threadIdx.x;
    float s = 0.0f;
    #pragma unroll
    for (int j=tid; j<768; j+=256){
        float wv = w[j];
        Wv[(size_t)row*768 + j] = __float2bfloat16(wv*g[j]);
        s += wv*b[j];
    }
    __shared__ float t1[4];
    #pragma unroll
    for (int o=32;o;o>>=1) s += __shfl_down(s,o,64);
    int lane = tid & 63, wid = tid >> 6;
    if (!lane) t1[wid]=s;
    __syncthreads();
    if (tid==0) bv[row] = aqb[row] + t1[0]+t1[1]+t1[2]+t1[3];
}

// ---------------- MFMA GEMM: 3-buffer depth-2 pipeline, counted vmcnt (T3+T4) ----
// out[M,N] = A[M,K](bf16) @ W[N,K]^T(bf16) + bias. 128x128 tile, BK=32, 4 waves of 64x64.
// Per K-step: s_waitcnt vmcnt(4) (tile t done, tile t+1 in flight) -> raw s_barrier ->
// ds_read frags -> STAGE(t+2) into 3rd buffer -> 16 MFMA. Never drains vmcnt to 0 in loop.
// Each wave stages only its own 32-row stripe; 3-buffer rotation + 1 barrier/iter is race-free
// (WAR on buf[t%3] separated by barrier(t+1)). XCD-chunked bijective block remap (m204).
template<typename TO, int ACT, int RES>
__global__ __launch_bounds__(256) void k_gemm_mfma(const bf16* __restrict__ A, const bf16* __restrict__ W,
                                                   const float* __restrict__ bias, const float* __restrict__ res,
                                                   TO* __restrict__ out, int M, int N, int K){
    __shared__ short As[3][128*32];
    __shared__ short Ws[3][128*32];
    int nbx = (N + 127) >> 7;
    int nwg = gridDim.x;
    int orig = blockIdx.x;
    int xcd = orig & 7, sl = orig >> 3;
    int q8 = nwg >> 3, r8 = nwg & 7;
    int wg = (xcd < r8 ? xcd*(q8+1) : r8*(q8+1) + (xcd - r8)*q8) + sl;
    int by = wg / nbx;
    int bm = by*128, bn = (wg - by*nbx)*128;
    int tid = threadIdx.x, wid = tid>>6, lane = tid&63, quad = lane>>4, l16 = lane&15;
    int wr = (wid>>1)*64, wc = (wid&1)*64;
    fx4 acc[4][4];
    #pragma unroll
    for (int i=0;i<4;i++)
        #pragma unroll
        for (int j=0;j<4;j++) acc[i][j] = (fx4){0.f,0.f,0.f,0.f};
    // staging: wave wid covers rows [wid*32, wid*32+32), 2 calls of 16 rows each
    int lrow = lane>>2;
    int gchunk = (lane&3) ^ ((lane>>3)&3);           // global k-chunk (XOR swizzle)
    int r0a0 = wid*32 + lrow,  r0a1 = wid*32 + 16 + lrow;
    int ra0 = bm + r0a0; if (ra0 > M-1) ra0 = M-1;
    int ra1 = bm + r0a1; if (ra1 > M-1) ra1 = M-1;
    int rw0 = bn + r0a0; if (rw0 > N-1) rw0 = N-1;
    int rw1 = bn + r0a1; if (rw1 > N-1) rw1 = N-1;
    const bf16* pa0 = A + (size_t)ra0*K + gchunk*8;
    const bf16* pa1 = A + (size_t)ra1*K + gchunk*8;
    const bf16* pw0 = W + (size_t)rw0*K + gchunk*8;
    const bf16* pw1 = W + (size_t)rw1*K + gchunk*8;
    int sL0 = (wid*32)*32;           // wave-uniform LDS stripe bases
    int sL1 = (wid*32 + 16)*32;
    int slotx = (l16>>1)&3;                          // read-side swizzle component
    int nt = K >> 5;
    #define STAGE4(bsel, t) do { int _k0 = (t) << 5;               \
        gload_lds16(pa0 + _k0, &As[(bsel)][sL0]);                  \
        gload_lds16(pa1 + _k0, &As[(bsel)][sL1]);                  \
        gload_lds16(pw0 + _k0, &Ws[(bsel)][sL0]);                  \
        gload_lds16(pw1 + _k0, &Ws[(bsel)][sL1]); } while(0)
    STAGE4(0, 0);
    STAGE4(1, 1);
    int cur = 0;
    for (int t = 0; t < nt; ++t){
        if (t + 1 < nt) asm volatile("s_waitcnt vmcnt(4)" ::: "memory");
        else            asm volatile("s_waitcnt vmcnt(0)" ::: "memory");
        __builtin_amdgcn_s_barrier();
        __builtin_amdgcn_sched_barrier(0);
        const short* Ab = &As[cur][0];
        const short* Wb = &Ws[cur][0];
        bh8 af[4], bf_[4];
        int sa = (quad ^ slotx)*8;
        #pragma unroll
        for (int i=0;i<4;i++) af[i]  = *(const bh8*)&Ab[(wr + i*16 + l16)*32 + sa];
        #pragma unroll
        for (int j=0;j<4;j++) bf_[j] = *(const bh8*)&Wb[(wc + j*16 + l16)*32 + sa];
        if (t + 2 < nt){
            int nb = cur + 2; if (nb >= 3) nb -= 3;
            STAGE4(nb, t + 2);
        }
        #pragma unroll
        for (int i=0;i<4;i++)
            #pragma unroll
            for (int j=0;j<4;j++)
                acc[i][j] = __builtin_amdgcn_mfma_f32_16x16x32_bf16(af[i], bf_[j], acc[i][j], 0,0,0);
        cur += 1; if (cur == 3) cur = 0;
    }
    #undef STAGE4
    #pragma unroll
    for (int i=0;i<4;i++){
        #pragma unroll
        for (int r=0;r<4;r++){
            int row = bm + wr + i*16 + quad*4 + r;
            if (row >= M) continue;
            #pragma unroll
            for (int j=0;j<4;j++){
                int col = bn + wc + j*16 + l16;
                if (col >= N) continue;
                float v = acc[i][j][r] + bias[col];
                if (ACT == 1) v = v / (1.0f + __expf(-1.702f*v));
                if (RES) v += res[(size_t)row*N + col];
                stv(out, (size_t)row*N + col, v);
            }
        }
    }
}

// ---------------- flash MFMA attention ----------------
// 1D grid 3456, XCD-affine: the 9 q-tiles of one (b,h) run back-to-back on ONE XCD
// (id%8 selects XCD) so K/V stay in that XCD's L2.
// V staged with vector stores into a tr-subtiled layout, consumed via ds_read_b64_tr_b16.
// Ps strip chunk-XOR-swizzled (2-way = free). Softmax scale folded into Q (exact).
#define KSTR 72
__global__ __launch_bounds__(256) void k_attn_mfma(const bf16* __restrict__ qkv, bf16* __restrict__ obuf){
    __shared__ short Ks[64*KSTR];      // [k][d] row-major, stride 72
    __shared__ short Vs[64*KSTR];      // subtiled: s=(k>>2)*4+(d>>4), S=s^(2*(s>>3)); elem=S*72+(k&3)*16+(d&15)
    __shared__ short Ps[4*16*KSTR];    // per-wave P strip [16 q][64 k], chunk-XOR swizzle
    int id = blockIdx.x;
    int qt = (id>>3) % 9;
    int bh = (id&7) + ((id/72)<<3);
    int h = bh % NHEAD, b = bh / NHEAD;
    int tid = threadIdx.x, wid = tid>>6, lane = tid&63, quad = lane>>4, l16 = lane&15;
    size_t base = (size_t)b*SEQ*2304;
    int q_own = qt*64 + wid*16 + l16;
    int q_cl  = q_own > 512 ? 512 : q_own;
    const bf16* qrow = qkv + base + (size_t)q_cl*2304 + h*HD;
    bh8 qa0 = *(const bh8*)(qrow + quad*8);
    bh8 qa1 = *(const bh8*)(qrow + 32 + quad*8);
    {   // fold softmax scale 1/8 into Q once (exact pow2 scale in bf16)
        union { bh8 v; short s[8]; } u0, u1;
        u0.v = qa0; u1.v = qa1;
        #pragma unroll
        for (int j=0;j<8;j++){
            bf16 a = *(bf16*)&u0.s[j]; u0.s[j] = f2bs(0.125f*b2f(a));
            bf16 c = *(bf16*)&u1.s[j]; u1.s[j] = f2bs(0.125f*b2f(c));
        }
        qa0 = u0.v; qa1 = u1.v;
    }
    fx4 o[4];
    #pragma unroll
    for (int d=0; d<4; d++) o[d] = (fx4){0.f,0.f,0.f,0.f};
    float mrow[4] = {-1e30f,-1e30f,-1e30f,-1e30f};
    float lrow[4] = {0.f,0.f,0.f,0.f};
    int srow = tid>>2, d0 = (tid&3)*16;
    // V store target (vector b128s, aggregate-optimal banks)
    int s_st = (srow>>2)*4 + (tid&3);
    int vsb  = (s_st ^ ((srow>>3)<<1))*KSTR + (srow&3)*16;
    // Ps store/read pointers with chunk-XOR swizzle ch' = ch ^ 2*((row>>2)&3)
    int h8 = l16>>3, l7 = l16&7;
    short* psw[4];
    #pragma unroll
    for (int nt=0;nt<4;nt++)
        psw[nt] = &Ps[(wid*16 + quad*4)*KSTR + (((nt<<1)|h8) ^ (quad<<1))*8 + l7];
    int swr = (l16>>2)<<1;
    const short* prd0 = &Ps[(wid*16+l16)*KSTR + ((quad ^ swr))*8];
    const short* prd1 = &Ps[(wid*16+l16)*KSTR + (((4|quad) ^ swr))*8];
    unsigned vls = (unsigned)(size_t)(__attribute__((address_space(3))) short*)Vs + 2u*l16;
    #define TRA(hf,c,dt) (vls + 144u*(unsigned)(((32*(hf) + 8*quad + 4*(c) + (dt)) ^ (8*(hf) + 2*quad))))
    for (int kt=0; kt<9; kt++){
        int kg = kt*64 + srow; if (kg > 512) kg = 512;   // clamp; last-tile mask zeroes P anyway
        const bf16* krow = qkv + base + 768 + (size_t)kg*2304 + h*HD + d0;
        bh8 kv0 = *(const bh8*)(krow);
        bh8 kv1 = *(const bh8*)(krow + 8);
        bh8 vv0 = *(const bh8*)(krow + 768);
        bh8 vv1 = *(const bh8*)(krow + 776);
        *(bh8*)&Ks[srow*KSTR + d0]     = kv0;
        *(bh8*)&Ks[srow*KSTR + d0 + 8] = kv1;
        *(bh8*)&Vs[vsb]     = vv0;
        *(bh8*)&Vs[vsb + 8] = vv1;
        __syncthreads();
        fx4 s[4];
        #pragma unroll
        for (int nt=0; nt<4; nt++){
            bh8 kb0 = *(const bh8*)&Ks[(nt*16+l16)*KSTR + quad*8];
            bh8 kb1 = *(const bh8*)&Ks[(nt*16+l16)*KSTR + 32 + quad*8];
            fx4 a = (fx4){0.f,0.f,0.f,0.f};
            a = __builtin_amdgcn_mfma_f32_16x16x32_bf16(qa0, kb0, a, 0,0,0);
            a = __builtin_amdgcn_mfma_f32_16x16x32_bf16(qa1, kb1, a, 0,0,0);
            s[nt] = a;
        }
        // issue V^T transpose-reads early; latency hides under softmax
        u32x2 tv[16];
        #pragma unroll
        for (int dt=0; dt<4; dt++){
            tv[dt*4+0] = ds_tr16(TRA(0,0,dt));
            tv[dt*4+1] = ds_tr16(TRA(0,1,dt));
            tv[dt*4+2] = ds_tr16(TRA(1,0,dt));
            tv[dt*4+3] = ds_tr16(TRA(1,1,dt));
        }
        float tmax[4] = {-1e30f,-1e30f,-1e30f,-1e30f};
        if (kt < 8){
            #pragma unroll
            for (int nt=0; nt<4; nt++)
                #pragma unroll
                for (int r=0;r<4;r++) tmax[r] = fmaxf(tmax[r], s[nt][r]);
        } else {
            #pragma unroll
            for (int nt=0; nt<4; nt++){
                bool ok = (nt==0) && (l16==0);          // only k==512 valid in last tile
                #pragma unroll
                for (int r=0;r<4;r++){
                    float v = ok ? s[nt][r] : -1e30f;
                    s[nt][r] = v;
                    tmax[r] = fmaxf(tmax[r], v);
                }
            }
        }
        #pragma unroll
        for (int msk=1; msk<16; msk<<=1)
            #pragma unroll
            for (int r=0;r<4;r++) tmax[r] = fmaxf(tmax[r], __shfl_xor(tmax[r], msk, 64));
        bool grow = (tmax[0]>mrow[0])|(tmax[1]>mrow[1])|(tmax[2]>mrow[2])|(tmax[3]>mrow[3]);
        if (__any(grow)){                                // exact: skipped only when al==1
            #pragma unroll
            for (int r=0;r<4;r++){
                float mn = fmaxf(mrow[r], tmax[r]);
                float al = __expf(mrow[r] - mn);
                mrow[r] = mn;
                lrow[r] *= al;
                #pragma unroll
                for (int d=0; d<4; d++) o[d][r] *= al;
            }
        }
        float ps[4] = {0.f,0.f,0.f,0.f};
        #pragma unroll
        for (int nt=0; nt<4; nt++)
            #pragma unroll
            for (int r=0;r<4;r++){
                float p = __expf(s[nt][r] - mrow[r]);
                s[nt][r] = p;
                ps[r] += p;
            }
        #pragma unroll
        for (int msk=1; msk<16; msk<<=1)
            #pragma unroll
            for (int r=0;r<4;r++) ps[r] += __shfl_xor(ps[r], msk, 64);
        #pragma unroll
        for (int r=0;r<4;r++) lrow[r] += ps[r];
        #pragma unroll
        for (int nt=0; nt<4; nt++)
            #pragma unroll
            for (int r=0;r<4;r++) psw[nt][r*KSTR] = f2bs(s[nt][r]);
        bh8 pa0 = *(const bh8*)prd0;
        bh8 pa1 = *(const bh8*)prd1;
        asm volatile("s_waitcnt lgkmcnt(0)" ::: "memory");
        __builtin_amdgcn_sched_barrier(0);
        #pragma unroll
        for (int dt=0; dt<4; dt++){
            union { u32x4 u; bh8 h; } v0, v1;
            v0.u = (u32x4){tv[dt*4+0][0], tv[dt*4+0][1], tv[dt*4+1][0], tv[dt*4+1][1]};
            v1.u = (u32x4){tv[dt*4+2][0], tv[dt*4+2][1], tv[dt*4+3][0], tv[dt*4+3][1]};
            o[dt] = __builtin_amdgcn_mfma_f32_16x16x32_bf16(pa0, v0.h, o[dt], 0,0,0);
            o[dt] = __builtin_amdgcn_mfma_f32_16x16x32_bf16(pa1, v1.h, o[dt], 0,0,0);
        }
        __syncthreads();
    }
    #undef TRA
    float inv[4];
    #pragma unroll
    for (int r=0;r<4;r++) inv[r] = 1.0f/lrow[r];
    #pragma unroll
    for (int r=0;r<4;r++){
        int q = qt*64 + wid*16 + quad*4 + r;
        if (q < SEQ){
            size_t ob = ((size_t)(b*SEQ+q))*CDIM + h*HD;
            #pragma unroll
            for (int dt=0; dt<4; dt++)
                obuf[ob + dt*16 + l16] = __float2bfloat16(o[dt][r]*inv[r]);
        }
    }
}

// x2 = x1 + xffn + 0.5*(ah @ Wa2^T + ba2) -> d_out (fp32); block per row
__global__ __launch_bounds__(256) void k_comb(const bf16* __restrict__ x1, const bf16* __restrict__ xffn,
                                              const float* __restrict__ ah, const float* __restrict__ Wa2,
                                              const float* __restrict__ ba2, float* __restrict__ x2){
    int i = blockIdx.x; int tid = threadIdx.x;
    __shared__ float ar[16];
    if (tid < 16) ar[tid] = ah[(size_t)i*16 + tid];
    __syncthreads();
    for (int c=tid; c<CDIM; c+=256){
        const float* w = Wa2 + (size_t)c*16;
        float a = ba2[c];
        #pragma unroll
        for (int mm=0; mm<16; mm++) a += ar[mm]*w[mm];
        size_t o = (size_t)i*CDIM + c;
        x2[o] = b2f(x1[o]) + b2f(xffn[o]) + 0.5f*a;
    }
}

// ---------------- segment index build ----------------
__global__ __launch_bounds__(256) void k_icount(const int* __restrict__ idx, int* __restrict__ cnt, int n){
    int i = blockIdx.x*256 + threadIdx.x;
    if (i < n) atomicAdd(&cnt[idx[i]], 1);
}

__global__ __launch_bounds__(256) void k_iscan(const int* __restrict__ cnt, int* __restrict__ base,
                                               int* __restrict__ cur, int nseg){
    __shared__ int part[256], off[256];
    int t = threadIdx.x;
    int chunk = (nseg + 255) >> 8;
    int j0 = t*chunk, j1 = j0 + chunk; if (j1 > nseg) j1 = nseg;
    int s = 0;
    for (int j=j0; j<j1; j++) s += cnt[j];
    part[t] = s; __syncthreads();
    if (t == 0){ int acc=0; for (int i=0;i<256;i++){ off[i]=acc; acc+=part[i]; } }
    __syncthreads();
    int acc = off[t];
    for (int j=j0; j<j1; j++){ base[j]=acc; cur[j]=acc; acc+=cnt[j]; }
}

__global__ __launch_bounds__(256) void k_iscatter(const int* __restrict__ idx, int* __restrict__ cur,
                                                  int* __restrict__ order, int n){
    int i = blockIdx.x*256 + threadIdx.x;
    if (i < n){
        int pos = atomicAdd(&cur[idx[i]], 1);
        order[pos] = i;
    }
}

// gather + segment max/mean for cluster path
__global__ __launch_bounds__(256) void k_gather_seg(const float* __restrict__ outx, const int* __restrict__ basep,
                                                    const int* __restrict__ cntp, const int* __restrict__ order,
                                                    float* __restrict__ dst){
    int sg = blockIdx.x; int tid = threadIdx.x;
    int n = cntp[sg], b0 = basep[sg];
    float mx[3] = {-1e30f,-1e30f,-1e30f};
    float sm[3] = {0.f,0.f,0.f};
    for (int r=0; r<n; r++){
        int i = order[b0+r];
        size_t rb = (size_t)(i + (i>>9) + 1)*CDIM;
        #pragma unroll
        for (int j=0;j<3;j++){
            float v = outx[rb + tid + j*256];
            mx[j] = fmaxf(mx[j], v); sm[j] += v;
        }
    }
    float den = (float)(n > 1 ? n : 1);
    size_t db = (size_t)sg*CDIM;
    #pragma unroll
    for (int j=0;j<3;j++)
        dst[db + tid + j*256] = (n > 0 ? mx[j] : 0.f) + sm[j]/den;
}

// per-view: flat = o1@Wp^T + bp + feat, then segment max/mean
__global__ __launch_bounds__(256) void k_gather_flat(const float* __restrict__ outx, const float* __restrict__ o1v,
                                                     const float* __restrict__ Wp, const float* __restrict__ bp,
                                                     const int* __restrict__ basep, const int* __restrict__ cntp,
                                                     const int* __restrict__ order, float* __restrict__ dst){
    int sg = blockIdx.x; int tid = threadIdx.x;
    int n = cntp[sg], b0 = basep[sg];
    float w[3][MIDD], bb[3];
    #pragma unroll
    for (int j=0;j<3;j++){
        int c = tid + j*256;
        bb[j] = bp[c];
        #pragma unroll
        for (int mm=0;mm<MIDD;mm++) w[j][mm] = Wp[(size_t)c*MIDD + mm];
    }
    float mx[3] = {-1e30f,-1e30f,-1e30f};
    float sm[3] = {0.f,0.f,0.f};
    for (int r=0; r<n; r++){
        int i = order[b0+r];
        const float* orow = o1v + (size_t)i*MIDD;
        float ov[MIDD];
        #pragma unroll
        for (int mm=0;mm<MIDD;mm++) ov[mm] = orow[mm];
        size_t rb = (size_t)(i + (i>>9) + 1)*CDIM;
        #pragma unroll
        for (int j=0;j<3;j++){
            float a = bb[j];
            #pragma unroll
            for (int mm=0;mm<MIDD;mm++) a += ov[mm]*w[j][mm];
            a += outx[rb + tid + j*256];
            mx[j] = fmaxf(mx[j], a); sm[j] += a;
        }
    }
    float den = (float)(n > 1 ? n : 1);
    size_t db = (size_t)sg*CDIM;
    #pragma unroll
    for (int j=0;j<3;j++)
        dst[db + tid + j*256] = (n > 0 ? mx[j] : 0.f) + sm[j]/den;
}

// two-stage column stats
__global__ __launch_bounds__(256) void k_colstats_part(const float* __restrict__ in, int rows,
                                                       float* __restrict__ sumv, float* __restrict__ sumsq){
    int c = blockIdx.x*256 + threadIdx.x;
    if (c >= CDIM) return;
    int chunk = (rows + 31) >> 5;
    int r0 = blockIdx.y*chunk;
    int r1 = r0 + chunk; if (r1 > rows) r1 = rows;
    float s = 0.0f, s2 = 0.0f;
    for (int r=r0; r<r1; r++){
        float v = in[(size_t)r*CDIM + c];
        s += v; s2 += v*v;
    }
    atomicAdd(&sumv[c], s);
    atomicAdd(&sumsq[c], s2);
}

__global__ __launch_bounds__(256) void k_colfin(float* __restrict__ sumv, float* __restrict__ sumsq, int rows){
    int c = blockIdx.x*256 + threadIdx.x;
    if (c >= CDIM) return;
    float m = sumv[c] / (float)rows;
    float var = sumsq[c] / (float)rows - m*m;
    sumv[c]  = m;
    sumsq[c] = rsqrtf(fmaxf(var, 0.0f) + 1e-5f);
}

template<typename TO>
__global__ __launch_bounds__(256) void k_bngelu(const float* __restrict__ in, TO* __restrict__ outp,
                                                const float* __restrict__ m, const float* __restrict__ r,
                                                const float* __restrict__ g, const float* __restrict__ b, int n){
    int i = blockIdx.x*256 + threadIdx.x;
    if (i >= n) return;
    int c = i - (i/CDIM)*CDIM;
    float y = (in[i]-m[c])*r[c]*g[c] + b[c];
    stv(outp, (size_t)i, 0.5f*y*(1.0f + erff(y*0.70710678118654752f)));
}

// per-view micro attention: block per (segblock, view); 256 threads = 2 head-groups x 128 rows.
// mask tile + Q/K/V staged in LDS once per block, shared by all 6 heads.
#define MSTR 33    // mask row stride in dwords (132 B)
__global__ __launch_bounds__(256) void k_attnv(const float* __restrict__ qkv1a,
                                               const unsigned char* __restrict__ mask,
                                               float* __restrict__ o1all){
    __shared__ float Qs[N1V][13], Ksv[N1V][13], Vsv[N1V][13];
    __shared__ int   Ms[N1V*MSTR];
    int blk = blockIdx.x, v = blockIdx.y;
    int tid = threadIdx.x;
    // stage Q/K/V: threads 0..127, one row each (9 float4 = 36 floats)
    if (tid < N1V){
        const float4* rp = (const float4*)(qkv1a + (size_t)(blk*N1V + tid)*216 + v*36);
        #pragma unroll
        for (int j=0;j<3;j++){
            float4 q4 = rp[j], k4 = rp[3+j], v4 = rp[6+j];
            Qs[tid][j*4+0]=q4.x; Qs[tid][j*4+1]=q4.y; Qs[tid][j*4+2]=q4.z; Qs[tid][j*4+3]=q4.w;
            Ksv[tid][j*4+0]=k4.x; Ksv[tid][j*4+1]=k4.y; Ksv[tid][j*4+2]=k4.z; Ksv[tid][j*4+3]=k4.w;
            Vsv[tid][j*4+0]=v4.x; Vsv[tid][j*4+1]=v4.y; Vsv[tid][j*4+2]=v4.z; Vsv[tid][j*4+3]=v4.w;
        }
    }
    // stage mask tile (16 KB) coalesced, write at stride 132 B
    {
        const int4* mp = (const int4*)(mask + ((size_t)v*NB1 + blk)*N1V*N1V);
        #pragma unroll
        for (int it=0; it<4; it++){
            int e = tid + it*256;            // 0..1023 int4s
            int4 m4 = mp[e];
            int row = e >> 3, c4 = (e & 7)*4;
            Ms[row*MSTR + c4 + 0] = m4.x;
            Ms[row*MSTR + c4 + 1] = m4.y;
            Ms[row*MSTR + c4 + 2] = m4.z;
            Ms[row*MSTR + c4 + 3] = m4.w;
        }
    }
    __syncthreads();
    int n = tid & 127, hg = tid >> 7;
    const float scale = 0.28867513459481287f; // 12^-0.5
    #pragma unroll
    for (int hh=0; hh<3; hh++){
        int h = hg*3 + hh;
        float q0 = Qs[n][h*2], q1 = Qs[n][h*2+1];
        float m = -1e30f;
        #pragma unroll 4
        for (int k4=0; k4<32; k4++){
            int mw = Ms[n*MSTR + k4];
            #pragma unroll
            for (int j=0;j<4;j++){
                int k = k4*4 + j;
                float s = (q0*Ksv[k][h*2] + q1*Ksv[k][h*2+1])*scale + (((mw>>(j*8))&0xFF) ? -100000.0f : 0.0f);
                m = fmaxf(m, s);
            }
        }
        float l = 0.f, o0 = 0.f, o1v = 0.f;
        #pragma unroll 4
        for (int k4=0; k4<32; k4++){
            int mw = Ms[n*MSTR + k4];
            #pragma unroll
            for (int j=0;j<4;j++){
                int k = k4*4 + j;
                float s = (q0*Ksv[k][h*2] + q1*Ksv[k][h*2+1])*scale + (((mw>>(j*8))&0xFF) ? -100000.0f : 0.0f);
                float p = __expf(s - m);
                l += p; o0 += p*Vsv[k][h*2]; o1v += p*Vsv[k][h*2+1];
            }
        }
        float inv = 1.0f/l;
        float* orow = o1all + ((size_t)v*NR + blk*N1V + n)*MIDD + h*2;
        orow[0] = o0*inv; orow[1] = o1v*inv;
    }
}

// cossim + sims-normalize + weighted sum + residual; block per token row; in-place on d_out
__global__ __launch_bounds__(256) void k_final(float* __restrict__ outx, const float* __restrict__ x3d,
                                               const bf16* __restrict__ bnv, const int* __restrict__ cluster,
                                               const int* __restrict__ fgi){
    int i = blockIdx.x; int tid = threadIdx.x;
    int cl = cluster[i];
    const float* xr = x3d + (size_t)cl*CDIM;
    const bf16* pr[NVIEW];
    #pragma unroll
    for (int v=0; v<NVIEW; v++)
        pr[v] = bnv + ((size_t)v*D1SEG + fgi[(size_t)v*NR + i])*CDIM;
    size_t rb = (size_t)(i + (i>>9) + 1)*CDIM;
    float pv[NVIEW][3], ft[3];
    float dotv[NVIEW] = {0,0,0,0,0,0};
    float np2[NVIEW]  = {0,0,0,0,0,0};
    float nx2 = 0.0f;
    #pragma unroll
    for (int j=0; j<3; j++){
        int c = tid + j*256;
        float xv = xr[c]; nx2 += xv*xv;
        ft[j] = outx[rb + c];
        #pragma unroll
        for (int v=0; v<NVIEW; v++){
            float p = b2f(pr[v][c]); pv[v][j] = p;
            dotv[v] += p*xv; np2[v] += p*p;
        }
    }
    __shared__ float part[4*13];
    __shared__ float ssim[NVIEW];
    float vals[13];
    vals[0] = nx2;
    #pragma unroll
    for (int v=0; v<NVIEW; v++){ vals[1+v] = dotv[v]; vals[7+v] = np2[v]; }
    int lane = tid & 63, wid = tid >> 6;
    #pragma unroll
    for (int k=0; k<13; k++){
        float w = vals[k];
        #pragma unroll
        for (int o=32;o;o>>=1) w += __shfl_down(w,o,64);
        if (!lane) part[wid*13 + k] = w;
    }
    __syncthreads();
    if (tid == 0){
        float tot[13];
        #pragma unroll
        for (int k=0; k<13; k++) tot[k] = part[k] + part[13+k] + part[26+k] + part[39+k];
        float nb = fmaxf(sqrtf(tot[0]), 1e-8f);
        float sv[NVIEW]; float ssumv = 0.0f;
        #pragma unroll
        for (int v=0; v<NVIEW; v++){
            float na = fmaxf(sqrtf(tot[7+v]), 1e-8f);
            float cs = tot[1+v] / (na*nb);
            sv[v] = (cs + 1.0f)*0.5f;
            ssumv += sv[v];
        }
        #pragma unroll
        for (int v=0; v<NVIEW; v++) ssim[v] = sv[v]/ssumv;
    }
    __syncthreads();
    #pragma unroll
    for (int j=0; j<3; j++){
        int c = tid + j*256;
        float xs = 0.0f;
        #pragma unroll
        for (int v=0; v<NVIEW; v++) xs += ssim[v]*pv[v][j];
        outx[rb + c] = ft[j] + 0.3f*xs;
    }
}

// ---------------- host launcher ----------------
extern "C" void kernel_launch(void* const* d_in, const int* in_sizes, int n_in,
                              void* d_out, int out_size, void* d_ws, size_t ws_size,
                              hipStream_t stream){
    const float* x     = (const float*)d_in[0];
    const float* ln1g  = (const float*)d_in[1];
    const float* ln1b  = (const float*)d_in[2];
    const float* ln2g  = (const float*)d_in[3];
    const float* ln2b  = (const float*)d_in[4];
    const float* Wqkv  = (const float*)d_in[5];
    const float* bqkv  = (const float*)d_in[6];
    const float* Wo    = (const float*)d_in[7];
    const float* bo    = (const float*)d_in[8];
    const float* Wfc   = (const float*)d_in[9];
    const float* bfc   = (const float*)d_in[10];
    const float* Wproj = (const float*)d_in[11];
    const float* bproj = (const float*)d_in[12];
    const float* Wa1   = (const float*)d_in[13];
    const float* ba1   = (const float*)d_in[14];
    const float* Wa2   = (const float*)d_in[15];
    const float* ba2   = (const float*)d_in[16];
    const float* bn3dg = (const float*)d_in[17];
    const float* bn3db = (const float*)d_in[18];
    const float* bn1dg = (const float*)d_in[19];
    const float* bn1db = (const float*)d_in[20];
    const float* n3g   = (const float*)d_in[21];
    const float* n3b   = (const float*)d_in[22];
    const float* aqw   = (const float*)d_in[23];
    const float* aqb   = (const float*)d_in[24];
    const float* apw   = (const float*)d_in[25];
    const float* apb   = (const float*)d_in[26];
    const int*   cluster = (const int*)d_in[27];
    const int*   fgi     = (const int*)d_in[28];
    const unsigned char* mask = (const unsigned char*)d_in[29];
    float* out = (float*)d_out;
    float* ws  = (float*)d_ws;

    bf16*  yb    = (bf16*)(ws + A_FS);
    bf16*  qkvb  = (bf16*)(ws + B_FS);
    bf16*  hb    = (bf16*)(ws + B_FS);          // FFN hidden chunk (8208 rows)
    bf16*  xffb  = (bf16*)(ws + B_FS + 12607488);
    float* qkv1a = ws + B_FS;                   // phase 2
    float* o1all = ws + B_FS + 3538944;
    float* svs   = ws + B_FS + 4718592;
    bf16*  x1b   = (bf16*)(ws + X1_FS);
    float* ah    = ws + AH_FS;
    int*   icnt  = (int*)(ws + DI_CNT);
    int*   ibase = (int*)(ws + DI_BASE);
    int*   icur  = (int*)(ws + DI_CUR);
    int*   iord  = (int*)(ws + DI_ORD);
    float* x3d   = ws + X3D_FS;
    bf16*  bnv   = (bf16*)(ws + BNV_FS);
    float* statm = ws + STATM_FS;
    float* statr = ws + STATR_FS;
    bf16* WqkvB  = (bf16*)(ws + DW_FS);
    bf16* WoB    = WqkvB + 2304*768;
    bf16* WfcB   = WoB   + 768*768;
    bf16* WprojB = WfcB  + 3072*768;
    bf16* WvB    = (bf16*)(ws + DWV_FS);        // 216x768
    float* bvP   = ws + DWV_FS + 82944;
    bf16* Wa1B   = (bf16*)(ws + DWV_FS + 83200);

    // 0. weight conversion / folding
    k_f2b<<<1024, 256, 0, stream>>>(Wqkv,  WqkvB,  2304*768);
    k_f2b<<<1024, 256, 0, stream>>>(Wo,    WoB,    768*768);
    k_f2b<<<1024, 256, 0, stream>>>(Wfc,   WfcB,   3072*768);
    k_f2b<<<1024, 256, 0, stream>>>(Wproj, WprojB, 768*3072);
    k_f2b<<<48, 256, 0, stream>>>(Wa1, Wa1B, 16*768);
    k_foldw<<<216, 256, 0, stream>>>(aqw, aqb, n3g, n3b, WvB, bvP);
    // 1. LN1
    k_ln<float><<<NT, 256, 0, stream>>>(x, yb, ln1g, ln1b);
    // 2. qkv GEMM
    k_gemm_mfma<bf16,0,0><<<(2304/128)*((NT+127)/128), 256, 0, stream>>>(yb, WqkvB, bqkv, nullptr, qkvb, NT, 2304, 768);
    // 3. flash attention (1D XCD-affine grid: 8 * 9 * 48 = 3456)
    k_attn_mfma<<<3456, 256, 0, stream>>>(qkvb, yb);
    // 4. o-proj + residual(x)
    k_gemm_mfma<bf16,0,1><<<(768/128)*((NT+127)/128), 256, 0, stream>>>(yb, WoB, bo, x, x1b, NT, 768, 768);
    // 5. LN2
    k_ln<bf16><<<NT, 256, 0, stream>>>(x1b, yb, ln2g, ln2b);
    // 6/7. FFN in 2 row-chunks
    for (int cch=0; cch<2; cch++){
        const bf16* a2 = yb + (size_t)cch*CHROWS*CDIM;
        bf16* xo = xffb + (size_t)cch*CHROWS*CDIM;
        k_gemm_mfma<bf16,1,0><<<(FFDIM/128)*((CHROWS+127)/128), 256, 0, stream>>>(a2, WfcB, bfc, nullptr, hb, CHROWS, FFDIM, 768);
        k_gemm_mfma<bf16,0,0><<<(768/128)*((CHROWS+127)/128), 256, 0, stream>>>(hb, WprojB, bproj, nullptr, xo, CHROWS, 768, FFDIM);
    }
    // 8. adapt hidden
    k_gemm_mfma<float,1,0><<<1*((NT+127)/128), 256, 0, stream>>>(xffb, Wa1B, ba1, nullptr, ah, NT, 16, 768);
    // 9. combine -> d_out
    k_comb<<<NT, 256, 0, stream>>>(x1b, xffb, ah, Wa2, ba2, out);
    // 10. cluster path
    k_zero<<<32, 256, 0, stream>>>((float*)icnt, NCLUST);
    k_icount<<<NR/256, 256, 0, stream>>>(cluster, icnt, NR);
    k_iscan<<<1, 256, 0, stream>>>(icnt, ibase, icur, NCLUST);
    k_iscatter<<<NR/256, 256, 0, stream>>>(cluster, icur, iord, NR);
    k_gather_seg<<<NCLUST, 256, 0, stream>>>(out, ibase, icnt, iord, x3d);
    k_zero<<<6, 256, 0, stream>>>(statm, 1536);
    k_colstats_part<<<dim3(3, 32), 256, 0, stream>>>(x3d, NCLUST, statm, statr);
    k_colfin<<<3, 256, 0, stream>>>(statm, statr, NCLUST);
    k_bngelu<float><<<(NCLUST*CDIM+255)/256, 256, 0, stream>>>(x3d, x3d, statm, statr, bn3dg, bn3db, NCLUST*CDIM);
    // 11. view shared prep
    k_lnn<<<NR, 256, 0, stream>>>(out, yb);
    k_gemm_mfma<float,0,0><<<2*(NR/128), 256, 0, stream>>>(yb, WvB, bvP, nullptr, qkv1a, NR, 216, 768);
    k_attnv<<<dim3(NB1, NVIEW), 256, 0, stream>>>(qkv1a, mask, o1all);
    // 12. per-view: index build + fused flat-gather + bn stats + gelu
    for (int v=0; v<NVIEW; v++){
        const int* fv = fgi + (size_t)v*NR;
        k_zero<<<32, 256, 0, stream>>>((float*)icnt, D1SEG);
        k_icount<<<NR/256, 256, 0, stream>>>(fv, icnt, NR);
        k_iscan<<<1, 256, 0, stream>>>(icnt, ibase, icur, D1SEG);
        k_iscatter<<<NR/256, 256, 0, stream>>>(fv, icur, iord, NR);
        k_gather_flat<<<D1SEG, 256, 0, stream>>>(out, o1all + (size_t)v*NR*MIDD,
                                                 apw + (size_t)v*CDIM*MIDD, apb + (size_t)v*CDIM,
                                                 ibase, icnt, iord, svs);
        k_zero<<<6, 256, 0, stream>>>(statm, 1536);
        k_colstats_part<<<dim3(3, 32), 256, 0, stream>>>(svs, D1SEG, statm, statr);
        k_colfin<<<3, 256, 0, stream>>>(statm, statr, D1SEG);
        k_bngelu<bf16><<<(D1SEG*CDIM+255)/256, 256, 0, stream>>>(svs, bnv + (size_t)v*D1SEG*CDIM, statm, statr,
                                                                 bn1dg + v*CDIM, bn1db + v*CDIM, D1SEG*CDIM);
    }
    // 13. final combine
    k_final<<<NR, 256, 0, stream>>>(out, x3d, bnv, cluster, fgi);
}

// Round 3
// 1596.673 us; speedup vs baseline: 1.1443x; 1.0858x over previous
//
#include <hip/hip_runtime.h>
#include <hip/hip_bf16.h>
#include <math.h>

typedef unsigned int u32;
typedef __hip_bfloat16 bf16;
typedef __attribute__((ext_vector_type(8))) short bh8;
typedef __attribute__((ext_vector_type(4))) float fx4;
typedef __attribute__((ext_vector_type(2))) unsigned int u32x2;
typedef __attribute__((ext_vector_type(4))) unsigned int u32x4;

#define CDIM   768
#define BATCH  32
#define SEQ    513
#define NT     (BATCH*SEQ)     // 16416 rows incl cls
#define NR     16384           // BG
#define NHEAD  12
#define HD     64
#define FFDIM  3072
#define NCLUST 2048
#define D1SEG  6272
#define NVIEW  6
#define MIDD   12
#define H1N    6
#define N1V    128
#define NB1    128
#define CHROWS 8208            // FFN row chunk (2 chunks)

// ---------------- workspace layout (float-slot offsets; ≈229.8 MB total) ----
#define A_FS      ((size_t)0)          // 6,303,744 fs : y / obuf / y2 / yv  (NT*768 bf16)
#define B_FS      ((size_t)6303744)    // 18,911,232 fs: qkv bf16 | h+xffn bf16 | qkv1a+o1all+svs
#define X1_FS     ((size_t)25214976)   // 6,303,744 fs : x1 bf16
#define AH_FS     ((size_t)31518720)   // 262,656 fs   : ah fp32 | (phase2) batched view idx + stats
#define D_FS      ((size_t)31781376)   // 9,640,064 fs : index arrays | bf16 weights
#define DTOT_FS   9640064
#define X3D_FS    ((size_t)(D_FS + DTOT_FS))          // 1,572,864 fs x3d fp32
#define BNV_FS    (X3D_FS + 1572864)                  // 14,450,688 fs bnv bf16
#define STATM_FS  (BNV_FS + 14450688)                 // 768
#define STATR_FS  (STATM_FS + 768)                    // 768
#define DI_CNT    (D_FS)
#define DI_BASE   (D_FS + 6272)
#define DI_CUR    (D_FS + 12544)
#define DI_ORD    (D_FS + 18816)
#define DW_FS     (D_FS + 40960)
#define DWV_FS    (D_FS + 3600000)

__device__ inline float b2f(bf16 v){ return __bfloat162float(v); }
__device__ inline float ldv(const float* p, size_t i){ return p[i]; }
__device__ inline float ldv(const bf16*  p, size_t i){ return __bfloat162float(p[i]); }
__device__ inline void  stv(float* p, size_t i, float v){ p[i] = v; }
__device__ inline void  stv(bf16*  p, size_t i, float v){ p[i] = __float2bfloat16(v); }
__device__ inline short f2bs(float f){ bf16 h = __float2bfloat16(f); return *(short*)&h; }
__device__ inline void gload_lds16(const bf16* g, short* l){
    __builtin_amdgcn_global_load_lds((const __attribute__((address_space(1))) void*)g,
                                     (__attribute__((address_space(3))) void*)l, 16, 0, 0);
}
// gfx950 LDS transpose-read: per-lane address, 4 bf16 at +0/+32/+64/+96 bytes
__device__ inline u32x2 ds_tr16(unsigned a){
    u32x2 d;
    asm volatile("ds_read_b64_tr_b16 %0, %1" : "=v"(d) : "v"(a));
    return d;
}

// ---------------- utility ----------------

__global__ __launch_bounds__(256) void k_zero(float* p, int n){
    for (int i = blockIdx.x*256 + threadIdx.x; i < n; i += gridDim.x*256) p[i] = 0.0f;
}

__global__ __launch_bounds__(256) void k_f2b(const float* __restrict__ in, bf16* __restrict__ out, int n){
    for (int i = blockIdx.x*256 + threadIdx.x; i < n; i += gridDim.x*256)
        out[i] = __float2bfloat16(in[i]);
}

// LayerNorm over C=768, one block per row; out bf16
template<typename TI>
__global__ __launch_bounds__(256) void k_ln(const TI* __restrict__ in, bf16* __restrict__ out,
                                            const float* __restrict__ g, const float* __restrict__ b){
    int i = blockIdx.x;
    int tid = threadIdx.x;
    const TI* r = in + (size_t)i*CDIM;
    float v0 = ldv(r,(size_t)tid), v1 = ldv(r,(size_t)tid+256), v2 = ldv(r,(size_t)tid+512);
    float s  = v0+v1+v2;
    float s2 = v0*v0+v1*v1+v2*v2;
    __shared__ float t1[4], t2[4];
    #pragma unroll
    for (int o=32;o;o>>=1){ s += __shfl_down(s,o,64); s2 += __shfl_down(s2,o,64); }
    int lane = tid & 63, wid = tid >> 6;
    if (!lane){ t1[wid]=s; t2[wid]=s2; }
    __syncthreads();
    float S  = t1[0]+t1[1]+t1[2]+t1[3];
    float S2 = t2[0]+t2[1]+t2[2]+t2[3];
    float m  = S * (1.0f/CDIM);
    float var = S2 * (1.0f/CDIM) - m*m;
    float rstd = rsqrtf(var + 1e-5f);
    bf16* o_ = out + (size_t)i*CDIM;
    stv(o_,(size_t)tid,     (v0-m)*rstd*g[tid]     + b[tid]);
    stv(o_,(size_t)tid+256, (v1-m)*rstd*g[tid+256] + b[tid+256]);
    stv(o_,(size_t)tid+512, (v2-m)*rstd*g[tid+512] + b[tid+512]);
}

// normalize-only LN (affine folded into downstream weights), token-row map on input
__global__ __launch_bounds__(256) void k_lnn(const float* __restrict__ in, bf16* __restrict__ out){
    int i = blockIdx.x;
    size_t ri = (size_t)(i + (i>>9) + 1);
    int tid = threadIdx.x;
    const float* r = in + ri*CDIM;
    float v0 = r[tid], v1 = r[tid+256], v2 = r[tid+512];
    float s  = v0+v1+v2;
    float s2 = v0*v0+v1*v1+v2*v2;
    __shared__ float t1[4], t2[4];
    #pragma unroll
    for (int o=32;o;o>>=1){ s += __shfl_down(s,o,64); s2 += __shfl_down(s2,o,64); }
    int lane = tid & 63, wid = tid >> 6;
    if (!lane){ t1[wid]=s; t2[wid]=s2; }
    __syncthreads();
    float S  = t1[0]+t1[1]+t1[2]+t1[3];
    float S2 = t2[0]+t2[1]+t2[2]+t2[3];
    float m  = S * (1.0f/CDIM);
    float var = S2 * (1.0f/CDIM) - m*m;
    float rstd = rsqrtf(var + 1e-5f);
    bf16* o_ = out + (size_t)i*CDIM;
    stv(o_,(size_t)tid,     (v0-m)*rstd);
    stv(o_,(size_t)tid+256, (v1-m)*rstd);
    stv(o_,(size_t)tid+512, (v2-m)*rstd);
}

// fold per-view LN affine into view-qkv weights
__global__ __launch_bounds__(256) void k_foldw(const float* __restrict__ aqw, const float* __restrict__ aqb,
                                               const float* __restrict__ n3g, const float* __restrict__ n3b,
                                               bf16* __restrict__ Wv, float* __restrict__ bv){
    int row = blockIdx.x;                  // 0..215
    int v = row/36;
    const float* w = aqw + (size_t)row*768;
    const float* g = n3g + v*768;
    const float* b = n3b + v*768;
    int tid = threadIdx.x;
    float s = 0.0f;
    #pragma unroll
    for (int j=tid; j<768; j+=256){
        float wv = w[j];
        Wv[(size_t)row*768 + j] = __float2bfloat16(wv*g[j]);
        s += wv*b[j];
    }
    __shared__ float t1[4];
    #pragma unroll
    for (int o=32;o;o>>=1) s += __shfl_down(s,o,64);
    int lane = tid & 63, wid = tid >> 6;
    if (!lane) t1[wid]=s;
    __syncthreads();
    if (tid==0) bv[row] = aqb[row] + t1[0]+t1[1]+t1[2]+t1[3];
}

// ---------------- MFMA GEMM: 3-buffer depth-2 pipeline, counted vmcnt (T3+T4) ----
// out[M,N] = A[M,K](bf16) @ W[N,K]^T(bf16) + bias. 128x128 tile, BK=32, 4 waves of 64x64.
// Per K-step: s_waitcnt vmcnt(4) (tile t done, tile t+1 in flight) -> raw s_barrier ->
// ds_read frags -> STAGE(t+2) into 3rd buffer -> 16 MFMA. Never drains vmcnt to 0 in loop.
template<typename TO, int ACT, int RES>
__global__ __launch_bounds__(256) void k_gemm_mfma(const bf16* __restrict__ A, const bf16* __restrict__ W,
                                                   const float* __restrict__ bias, const float* __restrict__ res,
                                                   TO* __restrict__ out, int M, int N, int K){
    __shared__ short As[3][128*32];
    __shared__ short Ws[3][128*32];
    int nbx = (N + 127) >> 7;
    int nwg = gridDim.x;
    int orig = blockIdx.x;
    int xcd = orig & 7, sl = orig >> 3;
    int q8 = nwg >> 3, r8 = nwg & 7;
    int wg = (xcd < r8 ? xcd*(q8+1) : r8*(q8+1) + (xcd - r8)*q8) + sl;
    int by = wg / nbx;
    int bm = by*128, bn = (wg - by*nbx)*128;
    int tid = threadIdx.x, wid = tid>>6, lane = tid&63, quad = lane>>4, l16 = lane&15;
    int wr = (wid>>1)*64, wc = (wid&1)*64;
    fx4 acc[4][4];
    #pragma unroll
    for (int i=0;i<4;i++)
        #pragma unroll
        for (int j=0;j<4;j++) acc[i][j] = (fx4){0.f,0.f,0.f,0.f};
    // staging: wave wid covers rows [wid*32, wid*32+32), 2 calls of 16 rows each
    int lrow = lane>>2;
    int gchunk = (lane&3) ^ ((lane>>3)&3);           // global k-chunk (XOR swizzle)
    int r0a0 = wid*32 + lrow,  r0a1 = wid*32 + 16 + lrow;
    int ra0 = bm + r0a0; if (ra0 > M-1) ra0 = M-1;
    int ra1 = bm + r0a1; if (ra1 > M-1) ra1 = M-1;
    int rw0 = bn + r0a0; if (rw0 > N-1) rw0 = N-1;
    int rw1 = bn + r0a1; if (rw1 > N-1) rw1 = N-1;
    const bf16* pa0 = A + (size_t)ra0*K + gchunk*8;
    const bf16* pa1 = A + (size_t)ra1*K + gchunk*8;
    const bf16* pw0 = W + (size_t)rw0*K + gchunk*8;
    const bf16* pw1 = W + (size_t)rw1*K + gchunk*8;
    int sL0 = (wid*32)*32;           // wave-uniform LDS stripe bases
    int sL1 = (wid*32 + 16)*32;
    int slotx = (l16>>1)&3;                          // read-side swizzle component
    int nt = K >> 5;
    #define STAGE4(bsel, t) do { int _k0 = (t) << 5;               \
        gload_lds16(pa0 + _k0, &As[(bsel)][sL0]);                  \
        gload_lds16(pa1 + _k0, &As[(bsel)][sL1]);                  \
        gload_lds16(pw0 + _k0, &Ws[(bsel)][sL0]);                  \
        gload_lds16(pw1 + _k0, &Ws[(bsel)][sL1]); } while(0)
    STAGE4(0, 0);
    STAGE4(1, 1);
    int cur = 0;
    for (int t = 0; t < nt; ++t){
        if (t + 1 < nt) asm volatile("s_waitcnt vmcnt(4)" ::: "memory");
        else            asm volatile("s_waitcnt vmcnt(0)" ::: "memory");
        __builtin_amdgcn_s_barrier();
        __builtin_amdgcn_sched_barrier(0);
        const short* Ab = &As[cur][0];
        const short* Wb = &Ws[cur][0];
        bh8 af[4], bf_[4];
        int sa = (quad ^ slotx)*8;
        #pragma unroll
        for (int i=0;i<4;i++) af[i]  = *(const bh8*)&Ab[(wr + i*16 + l16)*32 + sa];
        #pragma unroll
        for (int j=0;j<4;j++) bf_[j] = *(const bh8*)&Wb[(wc + j*16 + l16)*32 + sa];
        if (t + 2 < nt){
            int nb = cur + 2; if (nb >= 3) nb -= 3;
            STAGE4(nb, t + 2);
        }
        #pragma unroll
        for (int i=0;i<4;i++)
            #pragma unroll
            for (int j=0;j<4;j++)
                acc[i][j] = __builtin_amdgcn_mfma_f32_16x16x32_bf16(af[i], bf_[j], acc[i][j], 0,0,0);
        cur += 1; if (cur == 3) cur = 0;
    }
    #undef STAGE4
    #pragma unroll
    for (int i=0;i<4;i++){
        #pragma unroll
        for (int r=0;r<4;r++){
            int row = bm + wr + i*16 + quad*4 + r;
            if (row >= M) continue;
            #pragma unroll
            for (int j=0;j<4;j++){
                int col = bn + wc + j*16 + l16;
                if (col >= N) continue;
                float v = acc[i][j][r] + bias[col];
                if (ACT == 1) v = v / (1.0f + __expf(-1.702f*v));
                if (RES) v += res[(size_t)row*N + col];
                stv(out, (size_t)row*N + col, v);
            }
        }
    }
}

// ---------------- flash MFMA attention ----------------
// 1D grid 3456, XCD-affine (K/V of one (b,h) stay in one XCD's L2).
// T14 split: K/V tile t+1 prefetched into regs during tile t compute; regs -> LDS at top
// of next iter (vmcnt wait then free). Double-buffered K/V LDS -> ONE barrier per tile
// (reads of buf[q] in compute(t-1) happen-before sync(t) <= writes of buf[q] at t+1).
// V consumed via ds_read_b64_tr_b16; Ps per-wave (lgkmcnt-only). setprio around MFMA (T5).
#define KSTR 72
__global__ __launch_bounds__(256) void k_attn_mfma(const bf16* __restrict__ qkv, bf16* __restrict__ obuf){
    __shared__ short Ks[2][64*KSTR];   // [k][d] row-major, stride 72
    __shared__ short Vs[2][64*KSTR];   // subtiled for tr-read
    __shared__ short Ps[4*16*KSTR];    // per-wave P strip [16 q][64 k], chunk-XOR swizzle
    int id = blockIdx.x;
    int qt = (id>>3) % 9;
    int bh = (id&7) + ((id/72)<<3);
    int h = bh % NHEAD, b = bh / NHEAD;
    int tid = threadIdx.x, wid = tid>>6, lane = tid&63, quad = lane>>4, l16 = lane&15;
    size_t base = (size_t)b*SEQ*2304;
    int q_own = qt*64 + wid*16 + l16;
    int q_cl  = q_own > 512 ? 512 : q_own;
    const bf16* qrow = qkv + base + (size_t)q_cl*2304 + h*HD;
    bh8 qa0 = *(const bh8*)(qrow + quad*8);
    bh8 qa1 = *(const bh8*)(qrow + 32 + quad*8);
    {   // fold softmax scale 1/8 into Q once (exact pow2 scale in bf16)
        union { bh8 v; short s[8]; } u0, u1;
        u0.v = qa0; u1.v = qa1;
        #pragma unroll
        for (int j=0;j<8;j++){
            bf16 a = *(bf16*)&u0.s[j]; u0.s[j] = f2bs(0.125f*b2f(a));
            bf16 c = *(bf16*)&u1.s[j]; u1.s[j] = f2bs(0.125f*b2f(c));
        }
        qa0 = u0.v; qa1 = u1.v;
    }
    fx4 o[4];
    #pragma unroll
    for (int d=0; d<4; d++) o[d] = (fx4){0.f,0.f,0.f,0.f};
    float mrow[4] = {-1e30f,-1e30f,-1e30f,-1e30f};
    float lrow[4] = {0.f,0.f,0.f,0.f};
    int srow = tid>>2, d0 = (tid&3)*16;
    // V store target (vector b128s, aggregate-optimal banks)
    int s_st = (srow>>2)*4 + (tid&3);
    int vsb  = (s_st ^ ((srow>>3)<<1))*KSTR + (srow&3)*16;
    // Ps store/read pointers with chunk-XOR swizzle ch' = ch ^ 2*((row>>2)&3)
    int h8 = l16>>3, l7 = l16&7;
    short* psw[4];
    #pragma unroll
    for (int nt=0;nt<4;nt++)
        psw[nt] = &Ps[(wid*16 + quad*4)*KSTR + (((nt<<1)|h8) ^ (quad<<1))*8 + l7];
    int swr = (l16>>2)<<1;
    const short* prd0 = &Ps[(wid*16+l16)*KSTR + ((quad ^ swr))*8];
    const short* prd1 = &Ps[(wid*16+l16)*KSTR + (((4|quad) ^ swr))*8];
    unsigned vls = (unsigned)(size_t)(__attribute__((address_space(3))) short*)&Vs[0][0] + 2u*l16;
    #define TRA(vb,hf,c,dt) ((vb) + 144u*(unsigned)(((32*(hf) + 8*quad + 4*(c) + (dt)) ^ (8*(hf) + 2*quad))))
    // prefetch tile 0 into regs
    bh8 kv0, kv1, vv0, vv1;
    {
        const bf16* krow = qkv + base + 768 + (size_t)srow*2304 + h*HD + d0;
        kv0 = *(const bh8*)(krow);
        kv1 = *(const bh8*)(krow + 8);
        vv0 = *(const bh8*)(krow + 768);
        vv1 = *(const bh8*)(krow + 776);
    }
    int p = 0;
    for (int kt=0; kt<9; kt++){
        short* KsP = &Ks[p][0];
        short* VsP = &Vs[p][0];
        *(bh8*)&KsP[srow*KSTR + d0]     = kv0;   // implicit vmcnt wait; loads issued a full
        *(bh8*)&KsP[srow*KSTR + d0 + 8] = kv1;   // tile ago -> no stall
        *(bh8*)&VsP[vsb]     = vv0;
        *(bh8*)&VsP[vsb + 8] = vv1;
        __syncthreads();
        if (kt < 8){   // prefetch next tile; latency hides under softmax+PV
            int kg = (kt+1)*64 + srow; if (kg > 512) kg = 512;
            const bf16* krow = qkv + base + 768 + (size_t)kg*2304 + h*HD + d0;
            kv0 = *(const bh8*)(krow);
            kv1 = *(const bh8*)(krow + 8);
            vv0 = *(const bh8*)(krow + 768);
            vv1 = *(const bh8*)(krow + 776);
        }
        unsigned vb = vls + 9216u*(unsigned)p;
        fx4 s[4];
        __builtin_amdgcn_s_setprio(1);
        #pragma unroll
        for (int nt=0; nt<4; nt++){
            bh8 kb0 = *(const bh8*)&KsP[(nt*16+l16)*KSTR + quad*8];
            bh8 kb1 = *(const bh8*)&KsP[(nt*16+l16)*KSTR + 32 + quad*8];
            fx4 a = (fx4){0.f,0.f,0.f,0.f};
            a = __builtin_amdgcn_mfma_f32_16x16x32_bf16(qa0, kb0, a, 0,0,0);
            a = __builtin_amdgcn_mfma_f32_16x16x32_bf16(qa1, kb1, a, 0,0,0);
            s[nt] = a;
        }
        __builtin_amdgcn_s_setprio(0);
        // issue V^T transpose-reads early; latency hides under softmax
        u32x2 tv[16];
        #pragma unroll
        for (int dt=0; dt<4; dt++){
            tv[dt*4+0] = ds_tr16(TRA(vb,0,0,dt));
            tv[dt*4+1] = ds_tr16(TRA(vb,0,1,dt));
            tv[dt*4+2] = ds_tr16(TRA(vb,1,0,dt));
            tv[dt*4+3] = ds_tr16(TRA(vb,1,1,dt));
        }
        float tmax[4] = {-1e30f,-1e30f,-1e30f,-1e30f};
        if (kt < 8){
            #pragma unroll
            for (int nt=0; nt<4; nt++)
                #pragma unroll
                for (int r=0;r<4;r++) tmax[r] = fmaxf(tmax[r], s[nt][r]);
        } else {
            #pragma unroll
            for (int nt=0; nt<4; nt++){
                bool ok = (nt==0) && (l16==0);          // only k==512 valid in last tile
                #pragma unroll
                for (int r=0;r<4;r++){
                    float v = ok ? s[nt][r] : -1e30f;
                    s[nt][r] = v;
                    tmax[r] = fmaxf(tmax[r], v);
                }
            }
        }
        #pragma unroll
        for (int msk=1; msk<16; msk<<=1)
            #pragma unroll
            for (int r=0;r<4;r++) tmax[r] = fmaxf(tmax[r], __shfl_xor(tmax[r], msk, 64));
        bool grow = (tmax[0]>mrow[0])|(tmax[1]>mrow[1])|(tmax[2]>mrow[2])|(tmax[3]>mrow[3]);
        if (__any(grow)){                                // exact: skipped only when al==1
            #pragma unroll
            for (int r=0;r<4;r++){
                float mn = fmaxf(mrow[r], tmax[r]);
                float al = __expf(mrow[r] - mn);
                mrow[r] = mn;
                lrow[r] *= al;
                #pragma unroll
                for (int d=0; d<4; d++) o[d][r] *= al;
            }
        }
        float ps[4] = {0.f,0.f,0.f,0.f};
        #pragma unroll
        for (int nt=0; nt<4; nt++)
            #pragma unroll
            for (int r=0;r<4;r++){
                float pp = __expf(s[nt][r] - mrow[r]);
                s[nt][r] = pp;
                ps[r] += pp;
            }
        #pragma unroll
        for (int msk=1; msk<16; msk<<=1)
            #pragma unroll
            for (int r=0;r<4;r++) ps[r] += __shfl_xor(ps[r], msk, 64);
        #pragma unroll
        for (int r=0;r<4;r++) lrow[r] += ps[r];
        #pragma unroll
        for (int nt=0; nt<4; nt++)
            #pragma unroll
            for (int r=0;r<4;r++) psw[nt][r*KSTR] = f2bs(s[nt][r]);
        bh8 pa0 = *(const bh8*)prd0;
        bh8 pa1 = *(const bh8*)prd1;
        asm volatile("s_waitcnt lgkmcnt(0)" ::: "memory");
        __builtin_amdgcn_sched_barrier(0);
        __builtin_amdgcn_s_setprio(1);
        #pragma unroll
        for (int dt=0; dt<4; dt++){
            union { u32x4 u; bh8 h; } v0, v1;
            v0.u = (u32x4){tv[dt*4+0][0], tv[dt*4+0][1], tv[dt*4+1][0], tv[dt*4+1][1]};
            v1.u = (u32x4){tv[dt*4+2][0], tv[dt*4+2][1], tv[dt*4+3][0], tv[dt*4+3][1]};
            o[dt] = __builtin_amdgcn_mfma_f32_16x16x32_bf16(pa0, v0.h, o[dt], 0,0,0);
            o[dt] = __builtin_amdgcn_mfma_f32_16x16x32_bf16(pa1, v1.h, o[dt], 0,0,0);
        }
        __builtin_amdgcn_s_setprio(0);
        p ^= 1;
    }
    #undef TRA
    float inv[4];
    #pragma unroll
    for (int r=0;r<4;r++) inv[r] = 1.0f/lrow[r];
    #pragma unroll
    for (int r=0;r<4;r++){
        int q = qt*64 + wid*16 + quad*4 + r;
        if (q < SEQ){
            size_t ob = ((size_t)(b*SEQ+q))*CDIM + h*HD;
            #pragma unroll
            for (int dt=0; dt<4; dt++)
                obuf[ob + dt*16 + l16] = __float2bfloat16(o[dt][r]*inv[r]);
        }
    }
}

// x2 = x1 + xffn + 0.5*(ah @ Wa2^T + ba2) -> d_out (fp32); block per row
__global__ __launch_bounds__(256) void k_comb(const bf16* __restrict__ x1, const bf16* __restrict__ xffn,
                                              const float* __restrict__ ah, const float* __restrict__ Wa2,
                                              const float* __restrict__ ba2, float* __restrict__ x2){
    int i = blockIdx.x; int tid = threadIdx.x;
    __shared__ float ar[16];
    if (tid < 16) ar[tid] = ah[(size_t)i*16 + tid];
    __syncthreads();
    for (int c=tid; c<CDIM; c+=256){
        const float* w = Wa2 + (size_t)c*16;
        float a = ba2[c];
        #pragma unroll
        for (int mm=0; mm<16; mm++) a += ar[mm]*w[mm];
        size_t o = (size_t)i*CDIM + c;
        x2[o] = b2f(x1[o]) + b2f(xffn[o]) + 0.5f*a;
    }
}

// ---------------- segment index build (cluster path, single) ----------------
__global__ __launch_bounds__(256) void k_icount(const int* __restrict__ idx, int* __restrict__ cnt, int n){
    int i = blockIdx.x*256 + threadIdx.x;
    if (i < n) atomicAdd(&cnt[idx[i]], 1);
}

__global__ __launch_bounds__(256) void k_iscan(const int* __restrict__ cnt, int* __restrict__ base,
                                               int* __restrict__ cur, int nseg){
    __shared__ int part[256], off[256];
    int t = threadIdx.x;
    int chunk = (nseg + 255) >> 8;
    int j0 = t*chunk, j1 = j0 + chunk; if (j1 > nseg) j1 = nseg;
    int s = 0;
    for (int j=j0; j<j1; j++) s += cnt[j];
    part[t] = s; __syncthreads();
    if (t == 0){ int acc=0; for (int i=0;i<256;i++){ off[i]=acc; acc+=part[i]; } }
    __syncthreads();
    int acc = off[t];
    for (int j=j0; j<j1; j++){ base[j]=acc; cur[j]=acc; acc+=cnt[j]; }
}

__global__ __launch_bounds__(256) void k_iscatter(const int* __restrict__ idx, int* __restrict__ cur,
                                                  int* __restrict__ order, int n){
    int i = blockIdx.x*256 + threadIdx.x;
    if (i < n){
        int pos = atomicAdd(&cur[idx[i]], 1);
        order[pos] = i;
    }
}

// ---------------- batched 6-view index build ----------------
__global__ __launch_bounds__(256) void k_icount6(const int* __restrict__ fgi, int* __restrict__ cnt){
    int g = blockIdx.x*256 + threadIdx.x;            // 0..6*NR-1
    int v = g >> 14;                                 // NR = 16384
    atomicAdd(&cnt[v*D1SEG + fgi[g]], 1);
}

__global__ __launch_bounds__(256) void k_iscan6(const int* __restrict__ cnt, int* __restrict__ base,
                                                int* __restrict__ cur){
    __shared__ int part[256], off[256];
    int v = blockIdx.x;
    const int* c = cnt + v*D1SEG;
    int* bs = base + v*D1SEG;
    int* cu = cur + v*D1SEG;
    int t = threadIdx.x;
    int chunk = (D1SEG + 255) >> 8;
    int j0 = t*chunk, j1 = j0 + chunk; if (j1 > D1SEG) j1 = D1SEG;
    int s = 0;
    for (int j=j0; j<j1; j++) s += c[j];
    part[t] = s; __syncthreads();
    if (t == 0){ int acc=0; for (int i=0;i<256;i++){ off[i]=acc; acc+=part[i]; } }
    __syncthreads();
    int acc = off[t];
    for (int j=j0; j<j1; j++){ bs[j]=acc; cu[j]=acc; acc+=c[j]; }
}

__global__ __launch_bounds__(256) void k_iscatter6(const int* __restrict__ fgi, int* __restrict__ cur,
                                                   int* __restrict__ order){
    int g = blockIdx.x*256 + threadIdx.x;
    int v = g >> 14;
    int pos = atomicAdd(&cur[v*D1SEG + fgi[g]], 1);
    order[(size_t)v*NR + pos] = g & (NR-1);
}

// gather + segment max/mean for cluster path
__global__ __launch_bounds__(256) void k_gather_seg(const float* __restrict__ outx, const int* __restrict__ basep,
                                                    const int* __restrict__ cntp, const int* __restrict__ order,
                                                    float* __restrict__ dst){
    int sg = blockIdx.x; int tid = threadIdx.x;
    int n = cntp[sg], b0 = basep[sg];
    float mx[3] = {-1e30f,-1e30f,-1e30f};
    float sm[3] = {0.f,0.f,0.f};
    for (int r=0; r<n; r++){
        int i = order[b0+r];
        size_t rb = (size_t)(i + (i>>9) + 1)*CDIM;
        #pragma unroll
        for (int j=0;j<3;j++){
            float v = outx[rb + tid + j*256];
            mx[j] = fmaxf(mx[j], v); sm[j] += v;
        }
    }
    float den = (float)(n > 1 ? n : 1);
    size_t db = (size_t)sg*CDIM;
    #pragma unroll
    for (int j=0;j<3;j++)
        dst[db + tid + j*256] = (n > 0 ? mx[j] : 0.f) + sm[j]/den;
}

// per-view: flat = o1@Wp^T + bp + feat, then segment max/mean
__global__ __launch_bounds__(256) void k_gather_flat(const float* __restrict__ outx, const float* __restrict__ o1v,
                                                     const float* __restrict__ Wp, const float* __restrict__ bp,
                                                     const int* __restrict__ basep, const int* __restrict__ cntp,
                                                     const int* __restrict__ order, float* __restrict__ dst){
    int sg = blockIdx.x; int tid = threadIdx.x;
    int n = cntp[sg], b0 = basep[sg];
    float w[3][MIDD], bb[3];
    #pragma unroll
    for (int j=0;j<3;j++){
        int c = tid + j*256;
        bb[j] = bp[c];
        #pragma unroll
        for (int mm=0;mm<MIDD;mm++) w[j][mm] = Wp[(size_t)c*MIDD + mm];
    }
    float mx[3] = {-1e30f,-1e30f,-1e30f};
    float sm[3] = {0.f,0.f,0.f};
    for (int r=0; r<n; r++){
        int i = order[b0+r];
        const float* orow = o1v + (size_t)i*MIDD;
        float ov[MIDD];
        #pragma unroll
        for (int mm=0;mm<MIDD;mm++) ov[mm] = orow[mm];
        size_t rb = (size_t)(i + (i>>9) + 1)*CDIM;
        #pragma unroll
        for (int j=0;j<3;j++){
            float a = bb[j];
            #pragma unroll
            for (int mm=0;mm<MIDD;mm++) a += ov[mm]*w[j][mm];
            a += outx[rb + tid + j*256];
            mx[j] = fmaxf(mx[j], a); sm[j] += a;
        }
    }
    float den = (float)(n > 1 ? n : 1);
    size_t db = (size_t)sg*CDIM;
    #pragma unroll
    for (int j=0;j<3;j++)
        dst[db + tid + j*256] = (n > 0 ? mx[j] : 0.f) + sm[j]/den;
}

// two-stage column stats
__global__ __launch_bounds__(256) void k_colstats_part(const float* __restrict__ in, int rows,
                                                       float* __restrict__ sumv, float* __restrict__ sumsq){
    int c = blockIdx.x*256 + threadIdx.x;
    if (c >= CDIM) return;
    int chunk = (rows + 31) >> 5;
    int r0 = blockIdx.y*chunk;
    int r1 = r0 + chunk; if (r1 > rows) r1 = rows;
    float s = 0.0f, s2 = 0.0f;
    for (int r=r0; r<r1; r++){
        float v = in[(size_t)r*CDIM + c];
        s += v; s2 += v*v;
    }
    atomicAdd(&sumv[c], s);
    atomicAdd(&sumsq[c], s2);
}

// BN (stats finalized inline from raw sums; identical fp expressions to old colfin) + gelu
template<typename TO>
__global__ __launch_bounds__(256) void k_bngelu2(const float* __restrict__ in, TO* __restrict__ outp,
                                                 const float* __restrict__ sv, const float* __restrict__ sq,
                                                 const float* __restrict__ g, const float* __restrict__ b,
                                                 int n, float invn){
    int i = blockIdx.x*256 + threadIdx.x;
    if (i >= n) return;
    int c = i - (i/CDIM)*CDIM;
    float m = sv[c]*invn;
    float var = sq[c]*invn - m*m;
    float r = rsqrtf(fmaxf(var, 0.0f) + 1e-5f);
    float y = (in[i]-m)*r*g[c] + b[c];
    stv(outp, (size_t)i, 0.5f*y*(1.0f + erff(y*0.70710678118654752f)));
}

// per-view micro attention: block per (segblock, view); 256 threads = 2 head-groups x 128 rows.
// mask tile + Q/K/V staged in LDS once per block, shared by all 6 heads.
#define MSTR 33    // mask row stride in dwords (132 B)
__global__ __launch_bounds__(256) void k_attnv(const float* __restrict__ qkv1a,
                                               const unsigned char* __restrict__ mask,
                                               float* __restrict__ o1all){
    __shared__ float Qs[N1V][13], Ksv[N1V][13], Vsv[N1V][13];
    __shared__ int   Ms[N1V*MSTR];
    int blk = blockIdx.x, v = blockIdx.y;
    int tid = threadIdx.x;
    // stage Q/K/V: threads 0..127, one row each (9 float4 = 36 floats)
    if (tid < N1V){
        const float4* rp = (const float4*)(qkv1a + (size_t)(blk*N1V + tid)*216 + v*36);
        #pragma unroll
        for (int j=0;j<3;j++){
            float4 q4 = rp[j], k4 = rp[3+j], v4 = rp[6+j];
            Qs[tid][j*4+0]=q4.x; Qs[tid][j*4+1]=q4.y; Qs[tid][j*4+2]=q4.z; Qs[tid][j*4+3]=q4.w;
            Ksv[tid][j*4+0]=k4.x; Ksv[tid][j*4+1]=k4.y; Ksv[tid][j*4+2]=k4.z; Ksv[tid][j*4+3]=k4.w;
            Vsv[tid][j*4+0]=v4.x; Vsv[tid][j*4+1]=v4.y; Vsv[tid][j*4+2]=v4.z; Vsv[tid][j*4+3]=v4.w;
        }
    }
    // stage mask tile (16 KB) coalesced, write at stride 132 B
    {
        const int4* mp = (const int4*)(mask + ((size_t)v*NB1 + blk)*N1V*N1V);
        #pragma unroll
        for (int it=0; it<4; it++){
            int e = tid + it*256;            // 0..1023 int4s
            int4 m4 = mp[e];
            int row = e >> 3, c4 = (e & 7)*4;
            Ms[row*MSTR + c4 + 0] = m4.x;
            Ms[row*MSTR + c4 + 1] = m4.y;
            Ms[row*MSTR + c4 + 2] = m4.z;
            Ms[row*MSTR + c4 + 3] = m4.w;
        }
    }
    __syncthreads();
    int n = tid & 127, hg = tid >> 7;
    const float scale = 0.28867513459481287f; // 12^-0.5
    #pragma unroll
    for (int hh=0; hh<3; hh++){
        int h = hg*3 + hh;
        float q0 = Qs[n][h*2], q1 = Qs[n][h*2+1];
        float m = -1e30f;
        #pragma unroll 4
        for (int k4=0; k4<32; k4++){
            int mw = Ms[n*MSTR + k4];
            #pragma unroll
            for (int j=0;j<4;j++){
                int k = k4*4 + j;
                float s = (q0*Ksv[k][h*2] + q1*Ksv[k][h*2+1])*scale + (((mw>>(j*8))&0xFF) ? -100000.0f : 0.0f);
                m = fmaxf(m, s);
            }
        }
        float l = 0.f, o0 = 0.f, o1v = 0.f;
        #pragma unroll 4
        for (int k4=0; k4<32; k4++){
            int mw = Ms[n*MSTR + k4];
            #pragma unroll
            for (int j=0;j<4;j++){
                int k = k4*4 + j;
                float s = (q0*Ksv[k][h*2] + q1*Ksv[k][h*2+1])*scale + (((mw>>(j*8))&0xFF) ? -100000.0f : 0.0f);
                float p = __expf(s - m);
                l += p; o0 += p*Vsv[k][h*2]; o1v += p*Vsv[k][h*2+1];
            }
        }
        float inv = 1.0f/l;
        float* orow = o1all + ((size_t)v*NR + blk*N1V + n)*MIDD + h*2;
        orow[0] = o0*inv; orow[1] = o1v*inv;
    }
}

// cossim + sims-normalize + weighted sum + residual; block per token row; in-place on d_out
__global__ __launch_bounds__(256) void k_final(float* __restrict__ outx, const float* __restrict__ x3d,
                                               const bf16* __restrict__ bnv, const int* __restrict__ cluster,
                                               const int* __restrict__ fgi){
    int i = blockIdx.x; int tid = threadIdx.x;
    int cl = cluster[i];
    const float* xr = x3d + (size_t)cl*CDIM;
    const bf16* pr[NVIEW];
    #pragma unroll
    for (int v=0; v<NVIEW; v++)
        pr[v] = bnv + ((size_t)v*D1SEG + fgi[(size_t)v*NR + i])*CDIM;
    size_t rb = (size_t)(i + (i>>9) + 1)*CDIM;
    float pv[NVIEW][3], ft[3];
    float dotv[NVIEW] = {0,0,0,0,0,0};
    float np2[NVIEW]  = {0,0,0,0,0,0};
    float nx2 = 0.0f;
    #pragma unroll
    for (int j=0; j<3; j++){
        int c = tid + j*256;
        float xv = xr[c]; nx2 += xv*xv;
        ft[j] = outx[rb + c];
        #pragma unroll
        for (int v=0; v<NVIEW; v++){
            float p = b2f(pr[v][c]); pv[v][j] = p;
            dotv[v] += p*xv; np2[v] += p*p;
        }
    }
    __shared__ float part[4*13];
    __shared__ float ssim[NVIEW];
    float vals[13];
    vals[0] = nx2;
    #pragma unroll
    for (int v=0; v<NVIEW; v++){ vals[1+v] = dotv[v]; vals[7+v] = np2[v]; }
    int lane = tid & 63, wid = tid >> 6;
    #pragma unroll
    for (int k=0; k<13; k++){
        float w = vals[k];
        #pragma unroll
        for (int o=32;o;o>>=1) w += __shfl_down(w,o,64);
        if (!lane) part[wid*13 + k] = w;
    }
    __syncthreads();
    if (tid == 0){
        float tot[13];
        #pragma unroll
        for (int k=0; k<13; k++) tot[k] = part[k] + part[13+k] + part[26+k] + part[39+k];
        float nb = fmaxf(sqrtf(tot[0]), 1e-8f);
        float sv[NVIEW]; float ssumv = 0.0f;
        #pragma unroll
        for (int v=0; v<NVIEW; v++){
            float na = fmaxf(sqrtf(tot[7+v]), 1e-8f);
            float cs = tot[1+v] / (na*nb);
            sv[v] = (cs + 1.0f)*0.5f;
            ssumv += sv[v];
        }
        #pragma unroll
        for (int v=0; v<NVIEW; v++) ssim[v] = sv[v]/ssumv;
    }
    __syncthreads();
    #pragma unroll
    for (int j=0; j<3; j++){
        int c = tid + j*256;
        float xs = 0.0f;
        #pragma unroll
        for (int v=0; v<NVIEW; v++) xs += ssim[v]*pv[v][j];
        outx[rb + c] = ft[j] + 0.3f*xs;
    }
}

// ---------------- host launcher ----------------
extern "C" void kernel_launch(void* const* d_in, const int* in_sizes, int n_in,
                              void* d_out, int out_size, void* d_ws, size_t ws_size,
                              hipStream_t stream){
    const float* x     = (const float*)d_in[0];
    const float* ln1g  = (const float*)d_in[1];
    const float* ln1b  = (const float*)d_in[2];
    const float* ln2g  = (const float*)d_in[3];
    const float* ln2b  = (const float*)d_in[4];
    const float* Wqkv  = (const float*)d_in[5];
    const float* bqkv  = (const float*)d_in[6];
    const float* Wo    = (const float*)d_in[7];
    const float* bo    = (const float*)d_in[8];
    const float* Wfc   = (const float*)d_in[9];
    const float* bfc   = (const float*)d_in[10];
    const float* Wproj = (const float*)d_in[11];
    const float* bproj = (const float*)d_in[12];
    const float* Wa1   = (const float*)d_in[13];
    const float* ba1   = (const float*)d_in[14];
    const float* Wa2   = (const float*)d_in[15];
    const float* ba2   = (const float*)d_in[16];
    const float* bn3dg = (const float*)d_in[17];
    const float* bn3db = (const float*)d_in[18];
    const float* bn1dg = (const float*)d_in[19];
    const float* bn1db = (const float*)d_in[20];
    const float* n3g   = (const float*)d_in[21];
    const float* n3b   = (const float*)d_in[22];
    const float* aqw   = (const float*)d_in[23];
    const float* aqb   = (const float*)d_in[24];
    const float* apw   = (const float*)d_in[25];
    const float* apb   = (const float*)d_in[26];
    const int*   cluster = (const int*)d_in[27];
    const int*   fgi     = (const int*)d_in[28];
    const unsigned char* mask = (const unsigned char*)d_in[29];
    float* out = (float*)d_out;
    float* ws  = (float*)d_ws;

    bf16*  yb    = (bf16*)(ws + A_FS);
    bf16*  qkvb  = (bf16*)(ws + B_FS);
    bf16*  hb    = (bf16*)(ws + B_FS);          // FFN hidden chunk (8208 rows)
    bf16*  xffb  = (bf16*)(ws + B_FS + 12607488);
    float* qkv1a = ws + B_FS;                   // phase 2
    float* o1all = ws + B_FS + 3538944;
    float* svs   = ws + B_FS + 4718592;
    bf16*  x1b   = (bf16*)(ws + X1_FS);
    float* ah    = ws + AH_FS;
    int*   icnt  = (int*)(ws + DI_CNT);
    int*   ibase = (int*)(ws + DI_BASE);
    int*   icur  = (int*)(ws + DI_CUR);
    int*   iord  = (int*)(ws + DI_ORD);
    float* x3d   = ws + X3D_FS;
    bf16*  bnv   = (bf16*)(ws + BNV_FS);
    float* statm = ws + STATM_FS;
    float* statr = ws + STATR_FS;
    bf16* WqkvB  = (bf16*)(ws + DW_FS);
    bf16* WoB    = WqkvB + 2304*768;
    bf16* WfcB   = WoB   + 768*768;
    bf16* WprojB = WfcB  + 3072*768;
    bf16* WvB    = (bf16*)(ws + DWV_FS);        // 216x768
    float* bvP   = ws + DWV_FS + 82944;
    bf16* Wa1B   = (bf16*)(ws + DWV_FS + 83200);
    // phase-2 batched view index arrays + stats in the (dead) ah region:
    // 3*37632 + 98304 ints + 9216 floats = 220416 slots <= 262656
    int*   icnt6  = (int*)(ws + AH_FS);
    int*   ibase6 = icnt6 + 6*D1SEG;
    int*   icur6  = ibase6 + 6*D1SEG;
    int*   iord6  = icur6 + 6*D1SEG;
    float* stat6  = (float*)(iord6 + 6*NR);

    // 0. weight conversion / folding
    k_f2b<<<1024, 256, 0, stream>>>(Wqkv,  WqkvB,  2304*768);
    k_f2b<<<1024, 256, 0, stream>>>(Wo,    WoB,    768*768);
    k_f2b<<<1024, 256, 0, stream>>>(Wfc,   WfcB,   3072*768);
    k_f2b<<<1024, 256, 0, stream>>>(Wproj, WprojB, 768*3072);
    k_f2b<<<48, 256, 0, stream>>>(Wa1, Wa1B, 16*768);
    k_foldw<<<216, 256, 0, stream>>>(aqw, aqb, n3g, n3b, WvB, bvP);
    // 1. LN1
    k_ln<float><<<NT, 256, 0, stream>>>(x, yb, ln1g, ln1b);
    // 2. qkv GEMM
    k_gemm_mfma<bf16,0,0><<<(2304/128)*((NT+127)/128), 256, 0, stream>>>(yb, WqkvB, bqkv, nullptr, qkvb, NT, 2304, 768);
    // 3. flash attention (1D XCD-affine grid: 8 * 9 * 48 = 3456)
    k_attn_mfma<<<3456, 256, 0, stream>>>(qkvb, yb);
    // 4. o-proj + residual(x)
    k_gemm_mfma<bf16,0,1><<<(768/128)*((NT+127)/128), 256, 0, stream>>>(yb, WoB, bo, x, x1b, NT, 768, 768);
    // 5. LN2
    k_ln<bf16><<<NT, 256, 0, stream>>>(x1b, yb, ln2g, ln2b);
    // 6/7. FFN in 2 row-chunks
    for (int cch=0; cch<2; cch++){
        const bf16* a2 = yb + (size_t)cch*CHROWS*CDIM;
        bf16* xo = xffb + (size_t)cch*CHROWS*CDIM;
        k_gemm_mfma<bf16,1,0><<<(FFDIM/128)*((CHROWS+127)/128), 256, 0, stream>>>(a2, WfcB, bfc, nullptr, hb, CHROWS, FFDIM, 768);
        k_gemm_mfma<bf16,0,0><<<(768/128)*((CHROWS+127)/128), 256, 0, stream>>>(hb, WprojB, bproj, nullptr, xo, CHROWS, 768, FFDIM);
    }
    // 8. adapt hidden
    k_gemm_mfma<float,1,0><<<1*((NT+127)/128), 256, 0, stream>>>(xffb, Wa1B, ba1, nullptr, ah, NT, 16, 768);
    // 9. combine -> d_out
    k_comb<<<NT, 256, 0, stream>>>(x1b, xffb, ah, Wa2, ba2, out);
    // 10. cluster path
    k_zero<<<32, 256, 0, stream>>>((float*)icnt, NCLUST);
    k_icount<<<NR/256, 256, 0, stream>>>(cluster, icnt, NR);
    k_iscan<<<1, 256, 0, stream>>>(icnt, ibase, icur, NCLUST);
    k_iscatter<<<NR/256, 256, 0, stream>>>(cluster, icur, iord, NR);
    k_gather_seg<<<NCLUST, 256, 0, stream>>>(out, ibase, icnt, iord, x3d);
    k_zero<<<6, 256, 0, stream>>>(statm, 1536);
    k_colstats_part<<<dim3(3, 32), 256, 0, stream>>>(x3d, NCLUST, statm, statr);
    k_bngelu2<float><<<(NCLUST*CDIM+255)/256, 256, 0, stream>>>(x3d, x3d, statm, statr, bn3dg, bn3db,
                                                                NCLUST*CDIM, 1.0f/NCLUST);
    // 11. view shared prep
    k_lnn<<<NR, 256, 0, stream>>>(out, yb);
    k_gemm_mfma<float,0,0><<<2*(NR/128), 256, 0, stream>>>(yb, WvB, bvP, nullptr, qkv1a, NR, 216, 768);
    k_attnv<<<dim3(NB1, NVIEW), 256, 0, stream>>>(qkv1a, mask, o1all);
    // 12. batched 6-view index build, then per-view fused gather + stats + bn-gelu
    k_zero<<<(6*D1SEG+255)/256, 256, 0, stream>>>((float*)icnt6, 6*D1SEG);
    k_icount6<<<6*NR/256, 256, 0, stream>>>(fgi, icnt6);
    k_iscan6<<<6, 256, 0, stream>>>(icnt6, ibase6, icur6);
    k_iscatter6<<<6*NR/256, 256, 0, stream>>>(fgi, icur6, iord6);
    k_zero<<<(9216+255)/256, 256, 0, stream>>>(stat6, 9216);
    for (int v=0; v<NVIEW; v++){
        k_gather_flat<<<D1SEG, 256, 0, stream>>>(out, o1all + (size_t)v*NR*MIDD,
                                                 apw + (size_t)v*CDIM*MIDD, apb + (size_t)v*CDIM,
                                                 ibase6 + v*D1SEG, icnt6 + v*D1SEG, iord6 + (size_t)v*NR, svs);
        k_colstats_part<<<dim3(3, 32), 256, 0, stream>>>(svs, D1SEG, stat6 + v*1536, stat6 + v*1536 + 768);
        k_bngelu2<bf16><<<(D1SEG*CDIM+255)/256, 256, 0, stream>>>(svs, bnv + (size_t)v*D1SEG*CDIM,
                                                                  stat6 + v*1536, stat6 + v*1536 + 768,
                                                                  bn1dg + v*CDIM, bn1db + v*CDIM,
                                                                  D1SEG*CDIM, 1.0f/D1SEG);
    }
    // 13. final combine
    k_final<<<NR, 256, 0, stream>>>(out, x3d, bnv, cluster, fgi);
}

// Round 5
// 1591.773 us; speedup vs baseline: 1.1478x; 1.0031x over previous
//
#include <hip/hip_runtime.h>
#include <hip/hip_bf16.h>
#include <math.h>

typedef unsigned int u32;
typedef __hip_bfloat16 bf16;
typedef __attribute__((ext_vector_type(8))) short bh8;
typedef __attribute__((ext_vector_type(4))) float fx4;
typedef __attribute__((ext_vector_type(2))) unsigned int u32x2;
typedef __attribute__((ext_vector_type(4))) unsigned int u32x4;

#define CDIM   768
#define BATCH  32
#define SEQ    513
#define NT     (BATCH*SEQ)     // 16416 rows incl cls
#define NR     16384           // BG
#define NHEAD  12
#define HD     64
#define FFDIM  3072
#define NCLUST 2048
#define D1SEG  6272
#define NVIEW  6
#define MIDD   12
#define H1N    6
#define N1V    128
#define NB1    128
#define CHROWS 8208            // FFN row chunk (2 chunks)

// ---------------- workspace layout (float-slot offsets; ≈229.8 MB total) ----
#define A_FS      ((size_t)0)          // 6,303,744 fs : y / obuf / y2 / yv  (NT*768 bf16)
#define B_FS      ((size_t)6303744)    // 18,911,232 fs: qkv bf16 | h+xffn bf16 | qkv1a+o1all+svs
#define X1_FS     ((size_t)25214976)   // 6,303,744 fs : x1 bf16
#define AH_FS     ((size_t)31518720)   // 262,656 fs   : ah fp32 | (phase2) batched view idx + stats
#define D_FS      ((size_t)31781376)   // 9,640,064 fs : index arrays | bf16 weights
#define DTOT_FS   9640064
#define X3D_FS    ((size_t)(D_FS + DTOT_FS))          // 1,572,864 fs x3d fp32
#define BNV_FS    (X3D_FS + 1572864)                  // 14,450,688 fs bnv bf16
#define STATM_FS  (BNV_FS + 14450688)                 // 768
#define STATR_FS  (STATM_FS + 768)                    // 768
#define DI_CNT    (D_FS)
#define DI_BASE   (D_FS + 6272)
#define DI_CUR    (D_FS + 12544)
#define DI_ORD    (D_FS + 18816)
#define DW_FS     (D_FS + 40960)
#define DWV_FS    (D_FS + 3600000)

__device__ inline float b2f(bf16 v){ return __bfloat162float(v); }
__device__ inline float ldv(const float* p, size_t i){ return p[i]; }
__device__ inline float ldv(const bf16*  p, size_t i){ return __bfloat162float(p[i]); }
__device__ inline void  stv(float* p, size_t i, float v){ p[i] = v; }
__device__ inline void  stv(bf16*  p, size_t i, float v){ p[i] = __float2bfloat16(v); }
__device__ inline short f2bs(float f){ bf16 h = __float2bfloat16(f); return *(short*)&h; }
__device__ inline void gload_lds16(const bf16* g, short* l){
    __builtin_amdgcn_global_load_lds((const __attribute__((address_space(1))) void*)g,
                                     (__attribute__((address_space(3))) void*)l, 16, 0, 0);
}
// gfx950 LDS transpose-read: per-lane address, 4 bf16 at +0/+32/+64/+96 bytes
__device__ inline u32x2 ds_tr16(unsigned a){
    u32x2 d;
    asm volatile("ds_read_b64_tr_b16 %0, %1" : "=v"(d) : "v"(a));
    return d;
}
__device__ inline unsigned cvtpk_bf16(float lo, float hi){
    unsigned r;
    asm("v_cvt_pk_bf16_f32 %0, %1, %2" : "=v"(r) : "v"(lo), "v"(hi));
    return r;
}

// ---------------- utility ----------------

__global__ __launch_bounds__(256) void k_zero(float* p, int n){
    for (int i = blockIdx.x*256 + threadIdx.x; i < n; i += gridDim.x*256) p[i] = 0.0f;
}

// fused 5-way f32 -> bf16 weight conversion (one launch)
__global__ __launch_bounds__(256) void k_f2b5(const float* __restrict__ a0, bf16* __restrict__ b0, int n0,
                                              const float* __restrict__ a1, bf16* __restrict__ b1, int n1,
                                              const float* __restrict__ a2, bf16* __restrict__ b2, int n2,
                                              const float* __restrict__ a3, bf16* __restrict__ b3, int n3,
                                              const float* __restrict__ a4, bf16* __restrict__ b4, int n4){
    int i0 = blockIdx.x*256 + threadIdx.x, st = gridDim.x*256;
    for (int i=i0; i<n0; i+=st) b0[i] = __float2bfloat16(a0[i]);
    for (int i=i0; i<n1; i+=st) b1[i] = __float2bfloat16(a1[i]);
    for (int i=i0; i<n2; i+=st) b2[i] = __float2bfloat16(a2[i]);
    for (int i=i0; i<n3; i+=st) b3[i] = __float2bfloat16(a3[i]);
    for (int i=i0; i<n4; i+=st) b4[i] = __float2bfloat16(a4[i]);
}

// LayerNorm over C=768, one block per row; out bf16
template<typename TI>
__global__ __launch_bounds__(256) void k_ln(const TI* __restrict__ in, bf16* __restrict__ out,
                                            const float* __restrict__ g, const float* __restrict__ b){
    int i = blockIdx.x;
    int tid = threadIdx.x;
    const TI* r = in + (size_t)i*CDIM;
    float v0 = ldv(r,(size_t)tid), v1 = ldv(r,(size_t)tid+256), v2 = ldv(r,(size_t)tid+512);
    float s  = v0+v1+v2;
    float s2 = v0*v0+v1*v1+v2*v2;
    __shared__ float t1[4], t2[4];
    #pragma unroll
    for (int o=32;o;o>>=1){ s += __shfl_down(s,o,64); s2 += __shfl_down(s2,o,64); }
    int lane = tid & 63, wid = tid >> 6;
    if (!lane){ t1[wid]=s; t2[wid]=s2; }
    __syncthreads();
    float S  = t1[0]+t1[1]+t1[2]+t1[3];
    float S2 = t2[0]+t2[1]+t2[2]+t2[3];
    float m  = S * (1.0f/CDIM);
    float var = S2 * (1.0f/CDIM) - m*m;
    float rstd = rsqrtf(var + 1e-5f);
    bf16* o_ = out + (size_t)i*CDIM;
    stv(o_,(size_t)tid,     (v0-m)*rstd*g[tid]     + b[tid]);
    stv(o_,(size_t)tid+256, (v1-m)*rstd*g[tid+256] + b[tid+256]);
    stv(o_,(size_t)tid+512, (v2-m)*rstd*g[tid+512] + b[tid+512]);
}

// normalize-only LN (affine folded into downstream weights), token-row map on input
__global__ __launch_bounds__(256) void k_lnn(const float* __restrict__ in, bf16* __restrict__ out){
    int i = blockIdx.x;
    size_t ri = (size_t)(i + (i>>9) + 1);
    int tid = threadIdx.x;
    const float* r = in + ri*CDIM;
    float v0 = r[tid], v1 = r[tid+256], v2 = r[tid+512];
    float s  = v0+v1+v2;
    float s2 = v0*v0+v1*v1+v2*v2;
    __shared__ float t1[4], t2[4];
    #pragma unroll
    for (int o=32;o;o>>=1){ s += __shfl_down(s,o,64); s2 += __shfl_down(s2,o,64); }
    int lane = tid & 63, wid = tid >> 6;
    if (!lane){ t1[wid]=s; t2[wid]=s2; }
    __syncthreads();
    float S  = t1[0]+t1[1]+t1[2]+t1[3];
    float S2 = t2[0]+t2[1]+t2[2]+t2[3];
    float m  = S * (1.0f/CDIM);
    float var = S2 * (1.0f/CDIM) - m*m;
    float rstd = rsqrtf(var + 1e-5f);
    bf16* o_ = out + (size_t)i*CDIM;
    stv(o_,(size_t)tid,     (v0-m)*rstd);
    stv(o_,(size_t)tid+256, (v1-m)*rstd);
    stv(o_,(size_t)tid+512, (v2-m)*rstd);
}

// fold per-view LN affine into view-qkv weights
__global__ __launch_bounds__(256) void k_foldw(const float* __restrict__ aqw, const float* __restrict__ aqb,
                                               const float* __restrict__ n3g, const float* __restrict__ n3b,
                                               bf16* __restrict__ Wv, float* __restrict__ bv){
    int row = blockIdx.x;                  // 0..215
    int v = row/36;
    const float* w = aqw + (size_t)row*768;
    const float* g = n3g + v*768;
    const float* b = n3b + v*768;
    int tid = threadIdx.x;
    float s = 0.0f;
    #pragma unroll
    for (int j=tid; j<768; j+=256){
        float wv = w[j];
        Wv[(size_t)row*768 + j] = __float2bfloat16(wv*g[j]);
        s += wv*b[j];
    }
    __shared__ float t1[4];
    #pragma unroll
    for (int o=32;o;o>>=1) s += __shfl_down(s,o,64);
    int lane = tid & 63, wid = tid >> 6;
    if (!lane) t1[wid]=s;
    __syncthreads();
    if (tid==0) bv[row] = aqb[row] + t1[0]+t1[1]+t1[2]+t1[3];
}

// ---------------- MFMA GEMM: 3-buffer depth-2 pipeline, counted vmcnt (T3+T4) ----
// Per K-step: s_waitcnt vmcnt(4) -> raw s_barrier -> STAGE(t+2) (issued EARLY) ->
// ds_read frags -> 16 MFMA. Never drains vmcnt to 0 in loop.
template<typename TO, int ACT, int RES>
__global__ __launch_bounds__(256) void k_gemm_mfma(const bf16* __restrict__ A, const bf16* __restrict__ W,
                                                   const float* __restrict__ bias, const float* __restrict__ res,
                                                   TO* __restrict__ out, int M, int N, int K){
    __shared__ short As[3][128*32];
    __shared__ short Ws[3][128*32];
    int nbx = (N + 127) >> 7;
    int nwg = gridDim.x;
    int orig = blockIdx.x;
    int xcd = orig & 7, sl = orig >> 3;
    int q8 = nwg >> 3, r8 = nwg & 7;
    int wg = (xcd < r8 ? xcd*(q8+1) : r8*(q8+1) + (xcd - r8)*q8) + sl;
    int by = wg / nbx;
    int bm = by*128, bn = (wg - by*nbx)*128;
    int tid = threadIdx.x, wid = tid>>6, lane = tid&63, quad = lane>>4, l16 = lane&15;
    int wr = (wid>>1)*64, wc = (wid&1)*64;
    fx4 acc[4][4];
    #pragma unroll
    for (int i=0;i<4;i++)
        #pragma unroll
        for (int j=0;j<4;j++) acc[i][j] = (fx4){0.f,0.f,0.f,0.f};
    int lrow = lane>>2;
    int gchunk = (lane&3) ^ ((lane>>3)&3);           // global k-chunk (XOR swizzle)
    int r0a0 = wid*32 + lrow,  r0a1 = wid*32 + 16 + lrow;
    int ra0 = bm + r0a0; if (ra0 > M-1) ra0 = M-1;
    int ra1 = bm + r0a1; if (ra1 > M-1) ra1 = M-1;
    int rw0 = bn + r0a0; if (rw0 > N-1) rw0 = N-1;
    int rw1 = bn + r0a1; if (rw1 > N-1) rw1 = N-1;
    const bf16* pa0 = A + (size_t)ra0*K + gchunk*8;
    const bf16* pa1 = A + (size_t)ra1*K + gchunk*8;
    const bf16* pw0 = W + (size_t)rw0*K + gchunk*8;
    const bf16* pw1 = W + (size_t)rw1*K + gchunk*8;
    int sL0 = (wid*32)*32;           // wave-uniform LDS stripe bases
    int sL1 = (wid*32 + 16)*32;
    int slotx = (l16>>1)&3;                          // read-side swizzle component
    int nt = K >> 5;
    #define STAGE4(bsel, t) do { int _k0 = (t) << 5;               \
        gload_lds16(pa0 + _k0, &As[(bsel)][sL0]);                  \
        gload_lds16(pa1 + _k0, &As[(bsel)][sL1]);                  \
        gload_lds16(pw0 + _k0, &Ws[(bsel)][sL0]);                  \
        gload_lds16(pw1 + _k0, &Ws[(bsel)][sL1]); } while(0)
    STAGE4(0, 0);
    STAGE4(1, 1);
    int cur = 0;
    for (int t = 0; t < nt; ++t){
        if (t + 1 < nt) asm volatile("s_waitcnt vmcnt(4)" ::: "memory");
        else            asm volatile("s_waitcnt vmcnt(0)" ::: "memory");
        __builtin_amdgcn_s_barrier();
        __builtin_amdgcn_sched_barrier(0);
        if (t + 2 < nt){                 // issue next-next tile loads EARLY
            int nb = cur + 2; if (nb >= 3) nb -= 3;
            STAGE4(nb, t + 2);
        }
        const short* Ab = &As[cur][0];
        const short* Wb = &Ws[cur][0];
        bh8 af[4], bf_[4];
        int sa = (quad ^ slotx)*8;
        #pragma unroll
        for (int i=0;i<4;i++) af[i]  = *(const bh8*)&Ab[(wr + i*16 + l16)*32 + sa];
        #pragma unroll
        for (int j=0;j<4;j++) bf_[j] = *(const bh8*)&Wb[(wc + j*16 + l16)*32 + sa];
        #pragma unroll
        for (int i=0;i<4;i++)
            #pragma unroll
            for (int j=0;j<4;j++)
                acc[i][j] = __builtin_amdgcn_mfma_f32_16x16x32_bf16(af[i], bf_[j], acc[i][j], 0,0,0);
        cur += 1; if (cur == 3) cur = 0;
    }
    #undef STAGE4
    #pragma unroll
    for (int i=0;i<4;i++){
        #pragma unroll
        for (int r=0;r<4;r++){
            int row = bm + wr + i*16 + quad*4 + r;
            if (row >= M) continue;
            #pragma unroll
            for (int j=0;j<4;j++){
                int col = bn + wc + j*16 + l16;
                if (col >= N) continue;
                float v = acc[i][j][r] + bias[col];
                if (ACT == 1) v = v / (1.0f + __expf(-1.702f*v));
                if (RES) v += res[(size_t)row*N + col];
                stv(out, (size_t)row*N + col, v);
            }
        }
    }
}

// ---------------- flash MFMA attention (semi-swapped: S^T QK^T, LDS P, original PV) ----
// 1D grid 3456, XCD-affine. QK^T computed SWAPPED: S^T = mfma(K_frag, Q_frag) so each
// lane holds 16 k-values of ONE q (=l16): softmax = 15 in-lane ops + 2 shfl_xor; m,l are
// per-lane scalars. P^T (4 consecutive k per nt) packed via cvt_pk_bf16 -> ONE b64 store
// per nt into straight Ps[q][k] (bank-uniform). PV + epilogue identical to the verified
// round-3 path (pa=A, v=B); per-q rescale/1/l redistributed via __shfl(.., quad*4+r, 16).
#define KSTR 72
__global__ __launch_bounds__(256) void k_attn_mfma(const bf16* __restrict__ qkv, bf16* __restrict__ obuf){
    __shared__ short Ks[2][64*KSTR];   // [k][d] row-major, stride 72
    __shared__ short Vs[2][64*KSTR];   // subtiled for tr-read
    __shared__ short Ps[4*16*KSTR];    // per-wave P strip [16 q][64 k] straight layout
    int id = blockIdx.x;
    int qt = (id>>3) % 9;
    int bh = (id&7) + ((id/72)<<3);
    int h = bh % NHEAD, b = bh / NHEAD;
    int tid = threadIdx.x, wid = tid>>6, lane = tid&63, quad = lane>>4, l16 = lane&15;
    size_t base = (size_t)b*SEQ*2304;
    int q_own = qt*64 + wid*16 + l16;
    int q_cl  = q_own > 512 ? 512 : q_own;
    const bf16* qrow = qkv + base + (size_t)q_cl*2304 + h*HD;
    bh8 qa0 = *(const bh8*)(qrow + quad*8);
    bh8 qa1 = *(const bh8*)(qrow + 32 + quad*8);
    {   // fold softmax scale 1/8 into Q once (exact pow2 scale in bf16)
        union { bh8 v; short s[8]; } u0, u1;
        u0.v = qa0; u1.v = qa1;
        #pragma unroll
        for (int j=0;j<8;j++){
            bf16 a = *(bf16*)&u0.s[j]; u0.s[j] = f2bs(0.125f*b2f(a));
            bf16 c = *(bf16*)&u1.s[j]; u1.s[j] = f2bs(0.125f*b2f(c));
        }
        qa0 = u0.v; qa1 = u1.v;
    }
    fx4 o[4];                      // o[dt][r] = O[q = wid*16+quad*4+r][d = dt*16+l16]
    #pragma unroll
    for (int d=0; d<4; d++) o[d] = (fx4){0.f,0.f,0.f,0.f};
    float mrow = -1e30f, lrow = 0.f;   // per-lane scalars for q(local) = l16
    int srow = tid>>2, d0 = (tid&3)*16;
    int s_st = (srow>>2)*4 + (tid&3);
    int vsb  = (s_st ^ ((srow>>3)<<1))*KSTR + (srow&3)*16;
    short* pw = &Ps[(wid*16 + l16)*KSTR];      // this lane's q row
    const short* prd0 = &Ps[(wid*16+l16)*KSTR + quad*8];
    const short* prd1 = &Ps[(wid*16+l16)*KSTR + 32 + quad*8];
    unsigned vls = (unsigned)(size_t)(__attribute__((address_space(3))) short*)&Vs[0][0] + 2u*l16;
    #define TRA(vb,hf,c,dt) ((vb) + 144u*(unsigned)(((32*(hf) + 8*quad + 4*(c) + (dt)) ^ (8*(hf) + 2*quad))))
    bh8 kv0, kv1, vv0, vv1;
    {
        const bf16* krow = qkv + base + 768 + (size_t)srow*2304 + h*HD + d0;
        kv0 = *(const bh8*)(krow);
        kv1 = *(const bh8*)(krow + 8);
        vv0 = *(const bh8*)(krow + 768);
        vv1 = *(const bh8*)(krow + 776);
    }
    int p = 0;
    for (int kt=0; kt<9; kt++){
        short* KsP = &Ks[p][0];
        short* VsP = &Vs[p][0];
        *(bh8*)&KsP[srow*KSTR + d0]     = kv0;
        *(bh8*)&KsP[srow*KSTR + d0 + 8] = kv1;
        *(bh8*)&VsP[vsb]     = vv0;
        *(bh8*)&VsP[vsb + 8] = vv1;
        __syncthreads();
        if (kt < 8){   // prefetch next tile; latency hides under softmax+PV
            int kg = (kt+1)*64 + srow; if (kg > 512) kg = 512;
            const bf16* krow = qkv + base + 768 + (size_t)kg*2304 + h*HD + d0;
            kv0 = *(const bh8*)(krow);
            kv1 = *(const bh8*)(krow + 8);
            vv0 = *(const bh8*)(krow + 768);
            vv1 = *(const bh8*)(krow + 776);
        }
        unsigned vb = vls + 9216u*(unsigned)p;
        fx4 s[4];    // s[nt][r] = S^T[k = nt*16+quad*4+r][q = l16]
        __builtin_amdgcn_s_setprio(1);
        #pragma unroll
        for (int nt=0; nt<4; nt++){
            bh8 kb0 = *(const bh8*)&KsP[(nt*16+l16)*KSTR + quad*8];
            bh8 kb1 = *(const bh8*)&KsP[(nt*16+l16)*KSTR + 32 + quad*8];
            fx4 a = (fx4){0.f,0.f,0.f,0.f};
            a = __builtin_amdgcn_mfma_f32_16x16x32_bf16(kb0, qa0, a, 0,0,0);
            a = __builtin_amdgcn_mfma_f32_16x16x32_bf16(kb1, qa1, a, 0,0,0);
            s[nt] = a;
        }
        __builtin_amdgcn_s_setprio(0);
        // issue V^T transpose-reads early; latency hides under softmax
        u32x2 tv[16];
        #pragma unroll
        for (int dt=0; dt<4; dt++){
            tv[dt*4+0] = ds_tr16(TRA(vb,0,0,dt));
            tv[dt*4+1] = ds_tr16(TRA(vb,0,1,dt));
            tv[dt*4+2] = ds_tr16(TRA(vb,1,0,dt));
            tv[dt*4+3] = ds_tr16(TRA(vb,1,1,dt));
        }
        if (kt == 8){   // only k==512 valid in last tile: k_local = nt*16+quad*4+r == 0
            #pragma unroll
            for (int nt=0; nt<4; nt++)
                #pragma unroll
                for (int r=0;r<4;r++){
                    bool ok = (nt==0) && (r==0) && (quad==0);
                    s[nt][r] = ok ? s[nt][r] : -1e30f;
                }
        }
        // column (q=l16) max: 15 in-lane + 2 cross-quad rounds
        float ml = s[0][0];
        #pragma unroll
        for (int nt=0; nt<4; nt++)
            #pragma unroll
            for (int r=0;r<4;r++) if (nt|r) ml = fmaxf(ml, s[nt][r]);
        ml = fmaxf(ml, __shfl_xor(ml, 16, 64));
        ml = fmaxf(ml, __shfl_xor(ml, 32, 64));
        if (__any(ml > mrow)){           // exact: skipped only when al==1
            float mn = fmaxf(mrow, ml);
            float al = __expf(mrow - mn);
            mrow = mn;
            lrow *= al;
            // redistribute al to the output-layout q = quad*4+r
            float alr[4];
            #pragma unroll
            for (int r=0;r<4;r++) alr[r] = __shfl(al, quad*4 + r, 16);
            #pragma unroll
            for (int d=0; d<4; d++)
                #pragma unroll
                for (int r=0;r<4;r++) o[d][r] *= alr[r];
        }
        float ps = 0.f;
        #pragma unroll
        for (int nt=0; nt<4; nt++)
            #pragma unroll
            for (int r=0;r<4;r++){
                float pp = __expf(s[nt][r] - mrow);
                s[nt][r] = pp;
                ps += pp;
            }
        ps += __shfl_xor(ps, 16, 64);
        ps += __shfl_xor(ps, 32, 64);
        lrow += ps;
        // pack 4 consecutive k per nt -> one b64 store into Ps[q][k] (straight layout)
        #pragma unroll
        for (int nt=0; nt<4; nt++){
            u32x2 w;
            w[0] = cvtpk_bf16(s[nt][0], s[nt][1]);
            w[1] = cvtpk_bf16(s[nt][2], s[nt][3]);
            *(u32x2*)&pw[nt*16 + quad*4] = w;
        }
        bh8 pa0 = *(const bh8*)prd0;
        bh8 pa1 = *(const bh8*)prd1;
        asm volatile("s_waitcnt lgkmcnt(0)" ::: "memory");
        __builtin_amdgcn_sched_barrier(0);
        __builtin_amdgcn_s_setprio(1);
        #pragma unroll
        for (int dt=0; dt<4; dt++){
            union { u32x4 u; bh8 h; } v0, v1;
            v0.u = (u32x4){tv[dt*4+0][0], tv[dt*4+0][1], tv[dt*4+1][0], tv[dt*4+1][1]};
            v1.u = (u32x4){tv[dt*4+2][0], tv[dt*4+2][1], tv[dt*4+3][0], tv[dt*4+3][1]};
            o[dt] = __builtin_amdgcn_mfma_f32_16x16x32_bf16(pa0, v0.h, o[dt], 0,0,0);
            o[dt] = __builtin_amdgcn_mfma_f32_16x16x32_bf16(pa1, v1.h, o[dt], 0,0,0);
        }
        __builtin_amdgcn_s_setprio(0);
        p ^= 1;
    }
    #undef TRA
    // epilogue: redistribute 1/l to output-layout q = quad*4+r, coalesced global write
    float linv[4];
    #pragma unroll
    for (int r=0;r<4;r++) linv[r] = 1.0f / __shfl(lrow, quad*4 + r, 16);
    #pragma unroll
    for (int r=0;r<4;r++){
        int q = qt*64 + wid*16 + quad*4 + r;
        if (q < SEQ){
            size_t ob = ((size_t)(b*SEQ+q))*CDIM + h*HD;
            #pragma unroll
            for (int dt=0; dt<4; dt++)
                obuf[ob + dt*16 + l16] = __float2bfloat16(o[dt][r]*linv[r]);
        }
    }
}

// x2 = x1 + xffn + 0.5*(ah @ Wa2^T + ba2) -> d_out (fp32); block per row
__global__ __launch_bounds__(256) void k_comb(const bf16* __restrict__ x1, const bf16* __restrict__ xffn,
                                              const float* __restrict__ ah, const float* __restrict__ Wa2,
                                              const float* __restrict__ ba2, float* __restrict__ x2){
    int i = blockIdx.x; int tid = threadIdx.x;
    __shared__ float ar[16];
    if (tid < 16) ar[tid] = ah[(size_t)i*16 + tid];
    __syncthreads();
    for (int c=tid; c<CDIM; c+=256){
        const float* w = Wa2 + (size_t)c*16;
        float a = ba2[c];
        #pragma unroll
        for (int mm=0; mm<16; mm++) a += ar[mm]*w[mm];
        size_t o = (size_t)i*CDIM + c;
        x2[o] = b2f(x1[o]) + b2f(xffn[o]) + 0.5f*a;
    }
}

// ---------------- segment index build (cluster path, single) ----------------
__global__ __launch_bounds__(256) void k_icount(const int* __restrict__ idx, int* __restrict__ cnt, int n){
    int i = blockIdx.x*256 + threadIdx.x;
    if (i < n) atomicAdd(&cnt[idx[i]], 1);
}

__global__ __launch_bounds__(256) void k_iscan(const int* __restrict__ cnt, int* __restrict__ base,
                                               int* __restrict__ cur, int nseg){
    __shared__ int part[256], off[256];
    int t = threadIdx.x;
    int chunk = (nseg + 255) >> 8;
    int j0 = t*chunk, j1 = j0 + chunk; if (j1 > nseg) j1 = nseg;
    int s = 0;
    for (int j=j0; j<j1; j++) s += cnt[j];
    part[t] = s; __syncthreads();
    if (t == 0){ int acc=0; for (int i=0;i<256;i++){ off[i]=acc; acc+=part[i]; } }
    __syncthreads();
    int acc = off[t];
    for (int j=j0; j<j1; j++){ base[j]=acc; cur[j]=acc; acc+=cnt[j]; }
}

__global__ __launch_bounds__(256) void k_iscatter(const int* __restrict__ idx, int* __restrict__ cur,
                                                  int* __restrict__ order, int n){
    int i = blockIdx.x*256 + threadIdx.x;
    if (i < n){
        int pos = atomicAdd(&cur[idx[i]], 1);
        order[pos] = i;
    }
}

// ---------------- batched 6-view index build ----------------
__global__ __launch_bounds__(256) void k_icount6(const int* __restrict__ fgi, int* __restrict__ cnt){
    int g = blockIdx.x*256 + threadIdx.x;            // 0..6*NR-1
    int v = g >> 14;                                 // NR = 16384
    atomicAdd(&cnt[v*D1SEG + fgi[g]], 1);
}

__global__ __launch_bounds__(256) void k_iscan6(const int* __restrict__ cnt, int* __restrict__ base,
                                                int* __restrict__ cur){
    __shared__ int part[256], off[256];
    int v = blockIdx.x;
    const int* c = cnt + v*D1SEG;
    int* bs = base + v*D1SEG;
    int* cu = cur + v*D1SEG;
    int t = threadIdx.x;
    int chunk = (D1SEG + 255) >> 8;
    int j0 = t*chunk, j1 = j0 + chunk; if (j1 > D1SEG) j1 = D1SEG;
    int s = 0;
    for (int j=j0; j<j1; j++) s += c[j];
    part[t] = s; __syncthreads();
    if (t == 0){ int acc=0; for (int i=0;i<256;i++){ off[i]=acc; acc+=part[i]; } }
    __syncthreads();
    int acc = off[t];
    for (int j=j0; j<j1; j++){ bs[j]=acc; cu[j]=acc; acc+=c[j]; }
}

__global__ __launch_bounds__(256) void k_iscatter6(const int* __restrict__ fgi, int* __restrict__ cur,
                                                   int* __restrict__ order){
    int g = blockIdx.x*256 + threadIdx.x;
    int v = g >> 14;
    int pos = atomicAdd(&cur[v*D1SEG + fgi[g]], 1);
    order[(size_t)v*NR + pos] = g & (NR-1);
}

// gather + segment max/mean for cluster path
__global__ __launch_bounds__(256) void k_gather_seg(const float* __restrict__ outx, const int* __restrict__ basep,
                                                    const int* __restrict__ cntp, const int* __restrict__ order,
                                                    float* __restrict__ dst){
    int sg = blockIdx.x; int tid = threadIdx.x;
    int n = cntp[sg], b0 = basep[sg];
    float mx[3] = {-1e30f,-1e30f,-1e30f};
    float sm[3] = {0.f,0.f,0.f};
    for (int r=0; r<n; r++){
        int i = order[b0+r];
        size_t rb = (size_t)(i + (i>>9) + 1)*CDIM;
        #pragma unroll
        for (int j=0;j<3;j++){
            float v = outx[rb + tid + j*256];
            mx[j] = fmaxf(mx[j], v); sm[j] += v;
        }
    }
    float den = (float)(n > 1 ? n : 1);
    size_t db = (size_t)sg*CDIM;
    #pragma unroll
    for (int j=0;j<3;j++)
        dst[db + tid + j*256] = (n > 0 ? mx[j] : 0.f) + sm[j]/den;
}

// per-view: flat = o1@Wp^T + bp + feat, then segment max/mean
__global__ __launch_bounds__(256) void k_gather_flat(const float* __restrict__ outx, const float* __restrict__ o1v,
                                                     const float* __restrict__ Wp, const float* __restrict__ bp,
                                                     const int* __restrict__ basep, const int* __restrict__ cntp,
                                                     const int* __restrict__ order, float* __restrict__ dst){
    int sg = blockIdx.x; int tid = threadIdx.x;
    int n = cntp[sg], b0 = basep[sg];
    float w[3][MIDD], bb[3];
    #pragma unroll
    for (int j=0;j<3;j++){
        int c = tid + j*256;
        bb[j] = bp[c];
        #pragma unroll
        for (int mm=0;mm<MIDD;mm++) w[j][mm] = Wp[(size_t)c*MIDD + mm];
    }
    float mx[3] = {-1e30f,-1e30f,-1e30f};
    float sm[3] = {0.f,0.f,0.f};
    for (int r=0; r<n; r++){
        int i = order[b0+r];
        const float* orow = o1v + (size_t)i*MIDD;
        float ov[MIDD];
        #pragma unroll
        for (int mm=0;mm<MIDD;mm++) ov[mm] = orow[mm];
        size_t rb = (size_t)(i + (i>>9) + 1)*CDIM;
        #pragma unroll
        for (int j=0;j<3;j++){
            float a = bb[j];
            #pragma unroll
            for (int mm=0;mm<MIDD;mm++) a += ov[mm]*w[j][mm];
            a += outx[rb + tid + j*256];
            mx[j] = fmaxf(mx[j], a); sm[j] += a;
        }
    }
    float den = (float)(n > 1 ? n : 1);
    size_t db = (size_t)sg*CDIM;
    #pragma unroll
    for (int j=0;j<3;j++)
        dst[db + tid + j*256] = (n > 0 ? mx[j] : 0.f) + sm[j]/den;
}

// two-stage column stats
__global__ __launch_bounds__(256) void k_colstats_part(const float* __restrict__ in, int rows,
                                                       float* __restrict__ sumv, float* __restrict__ sumsq){
    int c = blockIdx.x*256 + threadIdx.x;
    if (c >= CDIM) return;
    int chunk = (rows + 31) >> 5;
    int r0 = blockIdx.y*chunk;
    int r1 = r0 + chunk; if (r1 > rows) r1 = rows;
    float s = 0.0f, s2 = 0.0f;
    for (int r=r0; r<r1; r++){
        float v = in[(size_t)r*CDIM + c];
        s += v; s2 += v*v;
    }
    atomicAdd(&sumv[c], s);
    atomicAdd(&sumsq[c], s2);
}

// BN (stats finalized inline from raw sums; identical fp expressions to old colfin) + gelu
template<typename TO>
__global__ __launch_bounds__(256) void k_bngelu2(const float* __restrict__ in, TO* __restrict__ outp,
                                                 const float* __restrict__ sv, const float* __restrict__ sq,
                                                 const float* __restrict__ g, const float* __restrict__ b,
                                                 int n, float invn){
    int i = blockIdx.x*256 + threadIdx.x;
    if (i >= n) return;
    int c = i - (i/CDIM)*CDIM;
    float m = sv[c]*invn;
    float var = sq[c]*invn - m*m;
    float r = rsqrtf(fmaxf(var, 0.0f) + 1e-5f);
    float y = (in[i]-m)*r*g[c] + b[c];
    stv(outp, (size_t)i, 0.5f*y*(1.0f + erff(y*0.70710678118654752f)));
}

// per-view micro attention: block per (segblock, view); 256 threads = 2 head-groups x 128 rows.
// mask tile + Q/K/V staged in LDS once per block, shared by all 6 heads.
#define MSTR 33    // mask row stride in dwords (132 B)
__global__ __launch_bounds__(256) void k_attnv(const float* __restrict__ qkv1a,
                                               const unsigned char* __restrict__ mask,
                                               float* __restrict__ o1all){
    __shared__ float Qs[N1V][13], Ksv[N1V][13], Vsv[N1V][13];
    __shared__ int   Ms[N1V*MSTR];
    int blk = blockIdx.x, v = blockIdx.y;
    int tid = threadIdx.x;
    // stage Q/K/V: threads 0..127, one row each (9 float4 = 36 floats)
    if (tid < N1V){
        const float4* rp = (const float4*)(qkv1a + (size_t)(blk*N1V + tid)*216 + v*36);
        #pragma unroll
        for (int j=0;j<3;j++){
            float4 q4 = rp[j], k4 = rp[3+j], v4 = rp[6+j];
            Qs[tid][j*4+0]=q4.x; Qs[tid][j*4+1]=q4.y; Qs[tid][j*4+2]=q4.z; Qs[tid][j*4+3]=q4.w;
            Ksv[tid][j*4+0]=k4.x; Ksv[tid][j*4+1]=k4.y; Ksv[tid][j*4+2]=k4.z; Ksv[tid][j*4+3]=k4.w;
            Vsv[tid][j*4+0]=v4.x; Vsv[tid][j*4+1]=v4.y; Vsv[tid][j*4+2]=v4.z; Vsv[tid][j*4+3]=v4.w;
        }
    }
    // stage mask tile (16 KB) coalesced, write at stride 132 B
    {
        const int4* mp = (const int4*)(mask + ((size_t)v*NB1 + blk)*N1V*N1V);
        #pragma unroll
        for (int it=0; it<4; it++){
            int e = tid + it*256;            // 0..1023 int4s
            int4 m4 = mp[e];
            int row = e >> 3, c4 = (e & 7)*4;
            Ms[row*MSTR + c4 + 0] = m4.x;
            Ms[row*MSTR + c4 + 1] = m4.y;
            Ms[row*MSTR + c4 + 2] = m4.z;
            Ms[row*MSTR + c4 + 3] = m4.w;
        }
    }
    __syncthreads();
    int n = tid & 127, hg = tid >> 7;
    const float scale = 0.28867513459481287f; // 12^-0.5
    #pragma unroll
    for (int hh=0; hh<3; hh++){
        int h = hg*3 + hh;
        float q0 = Qs[n][h*2], q1 = Qs[n][h*2+1];
        float m = -1e30f;
        #pragma unroll 4
        for (int k4=0; k4<32; k4++){
            int mw = Ms[n*MSTR + k4];
            #pragma unroll
            for (int j=0;j<4;j++){
                int k = k4*4 + j;
                float s = (q0*Ksv[k][h*2] + q1*Ksv[k][h*2+1])*scale + (((mw>>(j*8))&0xFF) ? -100000.0f : 0.0f);
                m = fmaxf(m, s);
            }
        }
        float l = 0.f, o0 = 0.f, o1v = 0.f;
        #pragma unroll 4
        for (int k4=0; k4<32; k4++){
            int mw = Ms[n*MSTR + k4];
            #pragma unroll
            for (int j=0;j<4;j++){
                int k = k4*4 + j;
                float s = (q0*Ksv[k][h*2] + q1*Ksv[k][h*2+1])*scale + (((mw>>(j*8))&0xFF) ? -100000.0f : 0.0f);
                float p = __expf(s - m);
                l += p; o0 += p*Vsv[k][h*2]; o1v += p*Vsv[k][h*2+1];
            }
        }
        float inv = 1.0f/l;
        float* orow = o1all + ((size_t)v*NR + blk*N1V + n)*MIDD + h*2;
        orow[0] = o0*inv; orow[1] = o1v*inv;
    }
}

// cossim + sims-normalize + weighted sum + residual; block per token row; in-place on d_out
__global__ __launch_bounds__(256) void k_final(float* __restrict__ outx, const float* __restrict__ x3d,
                                               const bf16* __restrict__ bnv, const int* __restrict__ cluster,
                                               const int* __restrict__ fgi){
    int i = blockIdx.x; int tid = threadIdx.x;
    int cl = cluster[i];
    const float* xr = x3d + (size_t)cl*CDIM;
    const bf16* pr[NVIEW];
    #pragma unroll
    for (int v=0; v<NVIEW; v++)
        pr[v] = bnv + ((size_t)v*D1SEG + fgi[(size_t)v*NR + i])*CDIM;
    size_t rb = (size_t)(i + (i>>9) + 1)*CDIM;
    float pv[NVIEW][3], ft[3];
    float dotv[NVIEW] = {0,0,0,0,0,0};
    float np2[NVIEW]  = {0,0,0,0,0,0};
    float nx2 = 0.0f;
    #pragma unroll
    for (int j=0; j<3; j++){
        int c = tid + j*256;
        float xv = xr[c]; nx2 += xv*xv;
        ft[j] = outx[rb + c];
        #pragma unroll
        for (int v=0; v<NVIEW; v++){
            float p = b2f(pr[v][c]); pv[v][j] = p;
            dotv[v] += p*xv; np2[v] += p*p;
        }
    }
    __shared__ float part[4*13];
    __shared__ float ssim[NVIEW];
    float vals[13];
    vals[0] = nx2;
    #pragma unroll
    for (int v=0; v<NVIEW; v++){ vals[1+v] = dotv[v]; vals[7+v] = np2[v]; }
    int lane = tid & 63, wid = tid >> 6;
    #pragma unroll
    for (int k=0; k<13; k++){
        float w = vals[k];
        #pragma unroll
        for (int o=32;o;o>>=1) w += __shfl_down(w,o,64);
        if (!lane) part[wid*13 + k] = w;
    }
    __syncthreads();
    if (tid == 0){
        float tot[13];
        #pragma unroll
        for (int k=0; k<13; k++) tot[k] = part[k] + part[13+k] + part[26+k] + part[39+k];
        float nb = fmaxf(sqrtf(tot[0]), 1e-8f);
        float sv[NVIEW]; float ssumv = 0.0f;
        #pragma unroll
        for (int v=0; v<NVIEW; v++){
            float na = fmaxf(sqrtf(tot[7+v]), 1e-8f);
            float cs = tot[1+v] / (na*nb);
            sv[v] = (cs + 1.0f)*0.5f;
            ssumv += sv[v];
        }
        #pragma unroll
        for (int v=0; v<NVIEW; v++) ssim[v] = sv[v]/ssumv;
    }
    __syncthreads();
    #pragma unroll
    for (int j=0; j<3; j++){
        int c = tid + j*256;
        float xs = 0.0f;
        #pragma unroll
        for (int v=0; v<NVIEW; v++) xs += ssim[v]*pv[v][j];
        outx[rb + c] = ft[j] + 0.3f*xs;
    }
}

// ---------------- host launcher ----------------
extern "C" void kernel_launch(void* const* d_in, const int* in_sizes, int n_in,
                              void* d_out, int out_size, void* d_ws, size_t ws_size,
                              hipStream_t stream){
    const float* x     = (const float*)d_in[0];
    const float* ln1g  = (const float*)d_in[1];
    const float* ln1b  = (const float*)d_in[2];
    const float* ln2g  = (const float*)d_in[3];
    const float* ln2b  = (const float*)d_in[4];
    const float* Wqkv  = (const float*)d_in[5];
    const float* bqkv  = (const float*)d_in[6];
    const float* Wo    = (const float*)d_in[7];
    const float* bo    = (const float*)d_in[8];
    const float* Wfc   = (const float*)d_in[9];
    const float* bfc   = (const float*)d_in[10];
    const float* Wproj = (const float*)d_in[11];
    const float* bproj = (const float*)d_in[12];
    const float* Wa1   = (const float*)d_in[13];
    const float* ba1   = (const float*)d_in[14];
    const float* Wa2   = (const float*)d_in[15];
    const float* ba2   = (const float*)d_in[16];
    const float* bn3dg = (const float*)d_in[17];
    const float* bn3db = (const float*)d_in[18];
    const float* bn1dg = (const float*)d_in[19];
    const float* bn1db = (const float*)d_in[20];
    const float* n3g   = (const float*)d_in[21];
    const float* n3b   = (const float*)d_in[22];
    const float* aqw   = (const float*)d_in[23];
    const float* aqb   = (const float*)d_in[24];
    const float* apw   = (const float*)d_in[25];
    const float* apb   = (const float*)d_in[26];
    const int*   cluster = (const int*)d_in[27];
    const int*   fgi     = (const int*)d_in[28];
    const unsigned char* mask = (const unsigned char*)d_in[29];
    float* out = (float*)d_out;
    float* ws  = (float*)d_ws;

    bf16*  yb    = (bf16*)(ws + A_FS);
    bf16*  qkvb  = (bf16*)(ws + B_FS);
    bf16*  hb    = (bf16*)(ws + B_FS);          // FFN hidden chunk (8208 rows)
    bf16*  xffb  = (bf16*)(ws + B_FS + 12607488);
    float* qkv1a = ws + B_FS;                   // phase 2
    float* o1all = ws + B_FS + 3538944;
    float* svs   = ws + B_FS + 4718592;
    bf16*  x1b   = (bf16*)(ws + X1_FS);
    float* ah    = ws + AH_FS;
    int*   icnt  = (int*)(ws + DI_CNT);
    int*   ibase = (int*)(ws + DI_BASE);
    int*   icur  = (int*)(ws + DI_CUR);
    int*   iord  = (int*)(ws + DI_ORD);
    float* x3d   = ws + X3D_FS;
    bf16*  bnv   = (bf16*)(ws + BNV_FS);
    float* statm = ws + STATM_FS;
    float* statr = ws + STATR_FS;
    bf16* WqkvB  = (bf16*)(ws + DW_FS);
    bf16* WoB    = WqkvB + 2304*768;
    bf16* WfcB   = WoB   + 768*768;
    bf16* WprojB = WfcB  + 3072*768;
    bf16* WvB    = (bf16*)(ws + DWV_FS);        // 216x768
    float* bvP   = ws + DWV_FS + 82944;
    bf16* Wa1B   = (bf16*)(ws + DWV_FS + 83200);
    // phase-2 batched view index arrays + stats in the (dead) ah region:
    // 3*37632 + 98304 ints + 9216 floats = 220416 slots <= 262656
    int*   icnt6  = (int*)(ws + AH_FS);
    int*   ibase6 = icnt6 + 6*D1SEG;
    int*   icur6  = ibase6 + 6*D1SEG;
    int*   iord6  = icur6 + 6*D1SEG;
    float* stat6  = (float*)(iord6 + 6*NR);

    // 0. weight conversion / folding (single fused launch + foldw)
    k_f2b5<<<2048, 256, 0, stream>>>(Wqkv, WqkvB, 2304*768,  Wo, WoB, 768*768,
                                     Wfc, WfcB, 3072*768,    Wproj, WprojB, 768*3072,
                                     Wa1, Wa1B, 16*768);
    k_foldw<<<216, 256, 0, stream>>>(aqw, aqb, n3g, n3b, WvB, bvP);
    // 1. LN1
    k_ln<float><<<NT, 256, 0, stream>>>(x, yb, ln1g, ln1b);
    // 2. qkv GEMM
    k_gemm_mfma<bf16,0,0><<<(2304/128)*((NT+127)/128), 256, 0, stream>>>(yb, WqkvB, bqkv, nullptr, qkvb, NT, 2304, 768);
    // 3. flash attention (1D XCD-affine grid: 8 * 9 * 48 = 3456)
    k_attn_mfma<<<3456, 256, 0, stream>>>(qkvb, yb);
    // 4. o-proj + residual(x)
    k_gemm_mfma<bf16,0,1><<<(768/128)*((NT+127)/128), 256, 0, stream>>>(yb, WoB, bo, x, x1b, NT, 768, 768);
    // 5. LN2
    k_ln<bf16><<<NT, 256, 0, stream>>>(x1b, yb, ln2g, ln2b);
    // 6/7. FFN in 2 row-chunks
    for (int cch=0; cch<2; cch++){
        const bf16* a2 = yb + (size_t)cch*CHROWS*CDIM;
        bf16* xo = xffb + (size_t)cch*CHROWS*CDIM;
        k_gemm_mfma<bf16,1,0><<<(FFDIM/128)*((CHROWS+127)/128), 256, 0, stream>>>(a2, WfcB, bfc, nullptr, hb, CHROWS, FFDIM, 768);
        k_gemm_mfma<bf16,0,0><<<(768/128)*((CHROWS+127)/128), 256, 0, stream>>>(hb, WprojB, bproj, nullptr, xo, CHROWS, 768, FFDIM);
    }
    // 8. adapt hidden
    k_gemm_mfma<float,1,0><<<1*((NT+127)/128), 256, 0, stream>>>(xffb, Wa1B, ba1, nullptr, ah, NT, 16, 768);
    // 9. combine -> d_out
    k_comb<<<NT, 256, 0, stream>>>(x1b, xffb, ah, Wa2, ba2, out);
    // 10. cluster path
    k_zero<<<32, 256, 0, stream>>>((float*)icnt, NCLUST);
    k_icount<<<NR/256, 256, 0, stream>>>(cluster, icnt, NR);
    k_iscan<<<1, 256, 0, stream>>>(icnt, ibase, icur, NCLUST);
    k_iscatter<<<NR/256, 256, 0, stream>>>(cluster, icur, iord, NR);
    k_gather_seg<<<NCLUST, 256, 0, stream>>>(out, ibase, icnt, iord, x3d);
    k_zero<<<6, 256, 0, stream>>>(statm, 1536);
    k_colstats_part<<<dim3(3, 32), 256, 0, stream>>>(x3d, NCLUST, statm, statr);
    k_bngelu2<float><<<(NCLUST*CDIM+255)/256, 256, 0, stream>>>(x3d, x3d, statm, statr, bn3dg, bn3db,
                                                                NCLUST*CDIM, 1.0f/NCLUST);
    // 11. view shared prep
    k_lnn<<<NR, 256, 0, stream>>>(out, yb);
    k_gemm_mfma<float,0,0><<<2*(NR/128), 256, 0, stream>>>(yb, WvB, bvP, nullptr, qkv1a, NR, 216, 768);
    k_attnv<<<dim3(NB1, NVIEW), 256, 0, stream>>>(qkv1a, mask, o1all);
    // 12. batched 6-view index build (one zero covers idx arrays + stat6), then per-view
    k_zero<<<(220416+255)/256, 256, 0, stream>>>((float*)icnt6, 220416);
    k_icount6<<<6*NR/256, 256, 0, stream>>>(fgi, icnt6);
    k_iscan6<<<6, 256, 0, stream>>>(icnt6, ibase6, icur6);
    k_iscatter6<<<6*NR/256, 256, 0, stream>>>(fgi, icur6, iord6);
    for (int v=0; v<NVIEW; v++){
        k_gather_flat<<<D1SEG, 256, 0, stream>>>(out, o1all + (size_t)v*NR*MIDD,
                                                 apw + (size_t)v*CDIM*MIDD, apb + (size_t)v*CDIM,
                                                 ibase6 + v*D1SEG, icnt6 + v*D1SEG, iord6 + (size_t)v*NR, svs);
        k_colstats_part<<<dim3(3, 32), 256, 0, stream>>>(svs, D1SEG, stat6 + v*1536, stat6 + v*1536 + 768);
        k_bngelu2<bf16><<<(D1SEG*CDIM+255)/256, 256, 0, stream>>>(svs, bnv + (size_t)v*D1SEG*CDIM,
                                                                  stat6 + v*1536, stat6 + v*1536 + 768,
                                                                  bn1dg + v*CDIM, bn1db + v*CDIM,
                                                                  D1SEG*CDIM, 1.0f/D1SEG);
    }
    // 13. final combine
    k_final<<<NR, 256, 0, stream>>>(out, x3d, bnv, cluster, fgi);
}

// Round 6
// 1363.548 us; speedup vs baseline: 1.3399x; 1.1674x over previous
//
#include <hip/hip_runtime.h>
#include <hip/hip_bf16.h>
#include <math.h>

typedef unsigned int u32;
typedef __hip_bfloat16 bf16;
typedef __attribute__((ext_vector_type(8))) short bh8;
typedef __attribute__((ext_vector_type(4))) float fx4;
typedef __attribute__((ext_vector_type(2))) unsigned int u32x2;
typedef __attribute__((ext_vector_type(4))) unsigned int u32x4;

#define CDIM   768
#define BATCH  32
#define SEQ    513
#define NT     (BATCH*SEQ)     // 16416 rows incl cls
#define NR     16384           // BG
#define NHEAD  12
#define HD     64
#define FFDIM  3072
#define NCLUST 2048
#define D1SEG  6272
#define NVIEW  6
#define MIDD   12
#define H1N    6
#define N1V    128
#define NB1    128
#define CHROWS 8208            // FFN row chunk (2 chunks)

// ---------------- workspace layout (float-slot offsets; ≈229.8 MB total) ----
#define A_FS      ((size_t)0)          // 6,303,744 fs : y / obuf / y2 / yv  (NT*768 bf16)
#define B_FS      ((size_t)6303744)    // 18,911,232 fs: qkv bf16 | h+xffn bf16 | qkv1a+o1all+svs
#define X1_FS     ((size_t)25214976)   // 6,303,744 fs : x1 bf16
#define AH_FS     ((size_t)31518720)   // 262,656 fs   : ah fp32 | (phase2) batched view idx + stats
#define D_FS      ((size_t)31781376)   // 9,640,064 fs : index arrays | bf16 weights
#define DTOT_FS   9640064
#define X3D_FS    ((size_t)(D_FS + DTOT_FS))          // 1,572,864 fs x3d fp32
#define BNV_FS    (X3D_FS + 1572864)                  // 14,450,688 fs bnv bf16
#define STATM_FS  (BNV_FS + 14450688)                 // 768
#define STATR_FS  (STATM_FS + 768)                    // 768
#define DI_CNT    (D_FS)
#define DI_BASE   (D_FS + 6272)
#define DI_CUR    (D_FS + 12544)
#define DI_ORD    (D_FS + 18816)
#define DW_FS     (D_FS + 40960)
#define DWV_FS    (D_FS + 3600000)

__device__ inline float b2f(bf16 v){ return __bfloat162float(v); }
__device__ inline float ldv(const float* p, size_t i){ return p[i]; }
__device__ inline float ldv(const bf16*  p, size_t i){ return __bfloat162float(p[i]); }
__device__ inline void  stv(float* p, size_t i, float v){ p[i] = v; }
__device__ inline void  stv(bf16*  p, size_t i, float v){ p[i] = __float2bfloat16(v); }
__device__ inline short f2bs(float f){ bf16 h = __float2bfloat16(f); return *(short*)&h; }
__device__ inline void gload_lds16(const bf16* g, short* l){
    __builtin_amdgcn_global_load_lds((const __attribute__((address_space(1))) void*)g,
                                     (__attribute__((address_space(3))) void*)l, 16, 0, 0);
}
// gfx950 LDS transpose-read: per-lane address, 4 bf16 at +0/+32/+64/+96 bytes
__device__ inline u32x2 ds_tr16(unsigned a){
    u32x2 d;
    asm volatile("ds_read_b64_tr_b16 %0, %1" : "=v"(d) : "v"(a));
    return d;
}
__device__ inline unsigned cvtpk_bf16(float lo, float hi){
    unsigned r;
    asm("v_cvt_pk_bf16_f32 %0, %1, %2" : "=v"(r) : "v"(lo), "v"(hi));
    return r;
}

// ---------------- utility ----------------

__global__ __launch_bounds__(256) void k_zero(float* p, int n){
    for (int i = blockIdx.x*256 + threadIdx.x; i < n; i += gridDim.x*256) p[i] = 0.0f;
}

// fused 5-way f32 -> bf16 weight conversion (one launch)
__global__ __launch_bounds__(256) void k_f2b5(const float* __restrict__ a0, bf16* __restrict__ b0, int n0,
                                              const float* __restrict__ a1, bf16* __restrict__ b1, int n1,
                                              const float* __restrict__ a2, bf16* __restrict__ b2, int n2,
                                              const float* __restrict__ a3, bf16* __restrict__ b3, int n3,
                                              const float* __restrict__ a4, bf16* __restrict__ b4, int n4){
    int i0 = blockIdx.x*256 + threadIdx.x, st = gridDim.x*256;
    for (int i=i0; i<n0; i+=st) b0[i] = __float2bfloat16(a0[i]);
    for (int i=i0; i<n1; i+=st) b1[i] = __float2bfloat16(a1[i]);
    for (int i=i0; i<n2; i+=st) b2[i] = __float2bfloat16(a2[i]);
    for (int i=i0; i<n3; i+=st) b3[i] = __float2bfloat16(a3[i]);
    for (int i=i0; i<n4; i+=st) b4[i] = __float2bfloat16(a4[i]);
}

// LayerNorm over C=768, one block per row; out bf16
template<typename TI>
__global__ __launch_bounds__(256) void k_ln(const TI* __restrict__ in, bf16* __restrict__ out,
                                            const float* __restrict__ g, const float* __restrict__ b){
    int i = blockIdx.x;
    int tid = threadIdx.x;
    const TI* r = in + (size_t)i*CDIM;
    float v0 = ldv(r,(size_t)tid), v1 = ldv(r,(size_t)tid+256), v2 = ldv(r,(size_t)tid+512);
    float s  = v0+v1+v2;
    float s2 = v0*v0+v1*v1+v2*v2;
    __shared__ float t1[4], t2[4];
    #pragma unroll
    for (int o=32;o;o>>=1){ s += __shfl_down(s,o,64); s2 += __shfl_down(s2,o,64); }
    int lane = tid & 63, wid = tid >> 6;
    if (!lane){ t1[wid]=s; t2[wid]=s2; }
    __syncthreads();
    float S  = t1[0]+t1[1]+t1[2]+t1[3];
    float S2 = t2[0]+t2[1]+t2[2]+t2[3];
    float m  = S * (1.0f/CDIM);
    float var = S2 * (1.0f/CDIM) - m*m;
    float rstd = rsqrtf(var + 1e-5f);
    bf16* o_ = out + (size_t)i*CDIM;
    stv(o_,(size_t)tid,     (v0-m)*rstd*g[tid]     + b[tid]);
    stv(o_,(size_t)tid+256, (v1-m)*rstd*g[tid+256] + b[tid+256]);
    stv(o_,(size_t)tid+512, (v2-m)*rstd*g[tid+512] + b[tid+512]);
}

// normalize-only LN (affine folded into downstream weights), token-row map on input
__global__ __launch_bounds__(256) void k_lnn(const float* __restrict__ in, bf16* __restrict__ out){
    int i = blockIdx.x;
    size_t ri = (size_t)(i + (i>>9) + 1);
    int tid = threadIdx.x;
    const float* r = in + ri*CDIM;
    float v0 = r[tid], v1 = r[tid+256], v2 = r[tid+512];
    float s  = v0+v1+v2;
    float s2 = v0*v0+v1*v1+v2*v2;
    __shared__ float t1[4], t2[4];
    #pragma unroll
    for (int o=32;o;o>>=1){ s += __shfl_down(s,o,64); s2 += __shfl_down(s2,o,64); }
    int lane = tid & 63, wid = tid >> 6;
    if (!lane){ t1[wid]=s; t2[wid]=s2; }
    __syncthreads();
    float S  = t1[0]+t1[1]+t1[2]+t1[3];
    float S2 = t2[0]+t2[1]+t2[2]+t2[3];
    float m  = S * (1.0f/CDIM);
    float var = S2 * (1.0f/CDIM) - m*m;
    float rstd = rsqrtf(var + 1e-5f);
    bf16* o_ = out + (size_t)i*CDIM;
    stv(o_,(size_t)tid,     (v0-m)*rstd);
    stv(o_,(size_t)tid+256, (v1-m)*rstd);
    stv(o_,(size_t)tid+512, (v2-m)*rstd);
}

// fold per-view LN affine into view-qkv weights
__global__ __launch_bounds__(256) void k_foldw(const float* __restrict__ aqw, const float* __restrict__ aqb,
                                               const float* __restrict__ n3g, const float* __restrict__ n3b,
                                               bf16* __restrict__ Wv, float* __restrict__ bv){
    int row = blockIdx.x;                  // 0..215
    int v = row/36;
    const float* w = aqw + (size_t)row*768;
    const float* g = n3g + v*768;
    const float* b = n3b + v*768;
    int tid = threadIdx.x;
    float s = 0.0f;
    #pragma unroll
    for (int j=tid; j<768; j+=256){
        float wv = w[j];
        Wv[(size_t)row*768 + j] = __float2bfloat16(wv*g[j]);
        s += wv*b[j];
    }
    __shared__ float t1[4];
    #pragma unroll
    for (int o=32;o;o>>=1) s += __shfl_down(s,o,64);
    int lane = tid & 63, wid = tid >> 6;
    if (!lane) t1[wid]=s;
    __syncthreads();
    if (tid==0) bv[row] = aqb[row] + t1[0]+t1[1]+t1[2]+t1[3];
}

// ---------------- MFMA GEMM (small-N): 128x128, 4 waves, 3-buffer counted vmcnt ----
template<typename TO, int ACT, int RES>
__global__ __launch_bounds__(256) void k_gemm_mfma(const bf16* __restrict__ A, const bf16* __restrict__ W,
                                                   const float* __restrict__ bias, const float* __restrict__ res,
                                                   TO* __restrict__ out, int M, int N, int K){
    __shared__ short As[3][128*32];
    __shared__ short Ws[3][128*32];
    int nbx = (N + 127) >> 7;
    int nwg = gridDim.x;
    int orig = blockIdx.x;
    int xcd = orig & 7, sl = orig >> 3;
    int q8 = nwg >> 3, r8 = nwg & 7;
    int wg = (xcd < r8 ? xcd*(q8+1) : r8*(q8+1) + (xcd - r8)*q8) + sl;
    int by = wg / nbx;
    int bm = by*128, bn = (wg - by*nbx)*128;
    int tid = threadIdx.x, wid = tid>>6, lane = tid&63, quad = lane>>4, l16 = lane&15;
    int wr = (wid>>1)*64, wc = (wid&1)*64;
    fx4 acc[4][4];
    #pragma unroll
    for (int i=0;i<4;i++)
        #pragma unroll
        for (int j=0;j<4;j++) acc[i][j] = (fx4){0.f,0.f,0.f,0.f};
    int lrow = lane>>2;
    int gchunk = (lane&3) ^ ((lane>>3)&3);           // global k-chunk (XOR swizzle)
    int r0a0 = wid*32 + lrow,  r0a1 = wid*32 + 16 + lrow;
    int ra0 = bm + r0a0; if (ra0 > M-1) ra0 = M-1;
    int ra1 = bm + r0a1; if (ra1 > M-1) ra1 = M-1;
    int rw0 = bn + r0a0; if (rw0 > N-1) rw0 = N-1;
    int rw1 = bn + r0a1; if (rw1 > N-1) rw1 = N-1;
    const bf16* pa0 = A + (size_t)ra0*K + gchunk*8;
    const bf16* pa1 = A + (size_t)ra1*K + gchunk*8;
    const bf16* pw0 = W + (size_t)rw0*K + gchunk*8;
    const bf16* pw1 = W + (size_t)rw1*K + gchunk*8;
    int sL0 = (wid*32)*32;           // wave-uniform LDS stripe bases
    int sL1 = (wid*32 + 16)*32;
    int slotx = (l16>>1)&3;                          // read-side swizzle component
    int nt = K >> 5;
    #define STAGE4(bsel, t) do { int _k0 = (t) << 5;               \
        gload_lds16(pa0 + _k0, &As[(bsel)][sL0]);                  \
        gload_lds16(pa1 + _k0, &As[(bsel)][sL1]);                  \
        gload_lds16(pw0 + _k0, &Ws[(bsel)][sL0]);                  \
        gload_lds16(pw1 + _k0, &Ws[(bsel)][sL1]); } while(0)
    STAGE4(0, 0);
    STAGE4(1, 1);
    int cur = 0;
    for (int t = 0; t < nt; ++t){
        if (t + 1 < nt) asm volatile("s_waitcnt vmcnt(4)" ::: "memory");
        else            asm volatile("s_waitcnt vmcnt(0)" ::: "memory");
        __builtin_amdgcn_s_barrier();
        __builtin_amdgcn_sched_barrier(0);
        if (t + 2 < nt){                 // issue next-next tile loads EARLY
            int nb = cur + 2; if (nb >= 3) nb -= 3;
            STAGE4(nb, t + 2);
        }
        const short* Ab = &As[cur][0];
        const short* Wb = &Ws[cur][0];
        bh8 af[4], bf_[4];
        int sa = (quad ^ slotx)*8;
        #pragma unroll
        for (int i=0;i<4;i++) af[i]  = *(const bh8*)&Ab[(wr + i*16 + l16)*32 + sa];
        #pragma unroll
        for (int j=0;j<4;j++) bf_[j] = *(const bh8*)&Wb[(wc + j*16 + l16)*32 + sa];
        #pragma unroll
        for (int i=0;i<4;i++)
            #pragma unroll
            for (int j=0;j<4;j++)
                acc[i][j] = __builtin_amdgcn_mfma_f32_16x16x32_bf16(af[i], bf_[j], acc[i][j], 0,0,0);
        cur += 1; if (cur == 3) cur = 0;
    }
    #undef STAGE4
    #pragma unroll
    for (int i=0;i<4;i++){
        #pragma unroll
        for (int r=0;r<4;r++){
            int row = bm + wr + i*16 + quad*4 + r;
            if (row >= M) continue;
            #pragma unroll
            for (int j=0;j<4;j++){
                int col = bn + wc + j*16 + l16;
                if (col >= N) continue;
                float v = acc[i][j][r] + bias[col];
                if (ACT == 1) v = v / (1.0f + __expf(-1.702f*v));
                if (RES) v += res[(size_t)row*N + col];
                stv(out, (size_t)row*N + col, v);
            }
        }
    }
}

// ---------------- MFMA GEMM (big-N): 128x256, 8 waves (512 thr), same 3-buffer pipeline ----
// Wave grid 2(M)x4(N), per-wave output 64x64 -- fragment/epilogue math identical to the
// 4-wave kernel. Staging per wave: 1 A-gload (16 rows) + 2 B-gloads (32 rows) -> vmcnt(3).
// LDS 72KB -> 2 blocks/CU (16 waves). A-panel traffic halved vs BN=128.
template<typename TO, int ACT, int RES>
__global__ __launch_bounds__(512) void k_gemm_mfma2(const bf16* __restrict__ A, const bf16* __restrict__ W,
                                                    const float* __restrict__ bias, const float* __restrict__ res,
                                                    TO* __restrict__ out, int M, int N, int K){
    __shared__ short As[3][128*32];
    __shared__ short Ws[3][256*32];
    int nbx = (N + 255) >> 8;
    int nwg = gridDim.x;
    int orig = blockIdx.x;
    int xcd = orig & 7, sl = orig >> 3;
    int q8 = nwg >> 3, r8 = nwg & 7;
    int wg = (xcd < r8 ? xcd*(q8+1) : r8*(q8+1) + (xcd - r8)*q8) + sl;
    int by = wg / nbx;
    int bm = by*128, bn = (wg - by*nbx)*256;
    int tid = threadIdx.x, wid = tid>>6, lane = tid&63, quad = lane>>4, l16 = lane&15;
    int wr = (wid>>2)*64, wc = (wid&3)*64;
    fx4 acc[4][4];
    #pragma unroll
    for (int i=0;i<4;i++)
        #pragma unroll
        for (int j=0;j<4;j++) acc[i][j] = (fx4){0.f,0.f,0.f,0.f};
    int lrow = lane>>2;
    int gchunk = (lane&3) ^ ((lane>>3)&3);           // global k-chunk (XOR swizzle)
    // A: wave stages rows [wid*16, +16); B: rows [wid*32, +32)
    int ra0 = bm + wid*16 + lrow;      if (ra0 > M-1) ra0 = M-1;
    int rw0 = bn + wid*32 + lrow;      if (rw0 > N-1) rw0 = N-1;
    int rw1 = bn + wid*32 + 16 + lrow; if (rw1 > N-1) rw1 = N-1;
    const bf16* pa0 = A + (size_t)ra0*K + gchunk*8;
    const bf16* pw0 = W + (size_t)rw0*K + gchunk*8;
    const bf16* pw1 = W + (size_t)rw1*K + gchunk*8;
    int sA  = (wid*16)*32;
    int sB0 = (wid*32)*32;
    int sB1 = (wid*32 + 16)*32;
    int slotx = (l16>>1)&3;                          // read-side swizzle component
    int nt = K >> 5;
    #define STAGE3(bsel, t) do { int _k0 = (t) << 5;               \
        gload_lds16(pa0 + _k0, &As[(bsel)][sA]);                   \
        gload_lds16(pw0 + _k0, &Ws[(bsel)][sB0]);                  \
        gload_lds16(pw1 + _k0, &Ws[(bsel)][sB1]); } while(0)
    STAGE3(0, 0);
    STAGE3(1, 1);
    int cur = 0;
    for (int t = 0; t < nt; ++t){
        if (t + 1 < nt) asm volatile("s_waitcnt vmcnt(3)" ::: "memory");
        else            asm volatile("s_waitcnt vmcnt(0)" ::: "memory");
        __builtin_amdgcn_s_barrier();
        __builtin_amdgcn_sched_barrier(0);
        if (t + 2 < nt){                 // issue next-next tile loads EARLY
            int nb = cur + 2; if (nb >= 3) nb -= 3;
            STAGE3(nb, t + 2);
        }
        const short* Ab = &As[cur][0];
        const short* Wb = &Ws[cur][0];
        bh8 af[4], bf_[4];
        int sa = (quad ^ slotx)*8;
        #pragma unroll
        for (int i=0;i<4;i++) af[i]  = *(const bh8*)&Ab[(wr + i*16 + l16)*32 + sa];
        #pragma unroll
        for (int j=0;j<4;j++) bf_[j] = *(const bh8*)&Wb[(wc + j*16 + l16)*32 + sa];
        #pragma unroll
        for (int i=0;i<4;i++)
            #pragma unroll
            for (int j=0;j<4;j++)
                acc[i][j] = __builtin_amdgcn_mfma_f32_16x16x32_bf16(af[i], bf_[j], acc[i][j], 0,0,0);
        cur += 1; if (cur == 3) cur = 0;
    }
    #undef STAGE3
    #pragma unroll
    for (int i=0;i<4;i++){
        #pragma unroll
        for (int r=0;r<4;r++){
            int row = bm + wr + i*16 + quad*4 + r;
            if (row >= M) continue;
            #pragma unroll
            for (int j=0;j<4;j++){
                int col = bn + wc + j*16 + l16;
                if (col >= N) continue;
                float v = acc[i][j][r] + bias[col];
                if (ACT == 1) v = v / (1.0f + __expf(-1.702f*v));
                if (RES) v += res[(size_t)row*N + col];
                stv(out, (size_t)row*N + col, v);
            }
        }
    }
}

// ---------------- flash MFMA attention (semi-swapped: S^T QK^T, LDS P, original PV) ----
#define KSTR 72
__global__ __launch_bounds__(256) void k_attn_mfma(const bf16* __restrict__ qkv, bf16* __restrict__ obuf){
    __shared__ short Ks[2][64*KSTR];   // [k][d] row-major, stride 72
    __shared__ short Vs[2][64*KSTR];   // subtiled for tr-read
    __shared__ short Ps[4*16*KSTR];    // per-wave P strip [16 q][64 k] straight layout
    int id = blockIdx.x;
    int qt = (id>>3) % 9;
    int bh = (id&7) + ((id/72)<<3);
    int h = bh % NHEAD, b = bh / NHEAD;
    int tid = threadIdx.x, wid = tid>>6, lane = tid&63, quad = lane>>4, l16 = lane&15;
    size_t base = (size_t)b*SEQ*2304;
    int q_own = qt*64 + wid*16 + l16;
    int q_cl  = q_own > 512 ? 512 : q_own;
    const bf16* qrow = qkv + base + (size_t)q_cl*2304 + h*HD;
    bh8 qa0 = *(const bh8*)(qrow + quad*8);
    bh8 qa1 = *(const bh8*)(qrow + 32 + quad*8);
    {   // fold softmax scale 1/8 into Q once (exact pow2 scale in bf16)
        union { bh8 v; short s[8]; } u0, u1;
        u0.v = qa0; u1.v = qa1;
        #pragma unroll
        for (int j=0;j<8;j++){
            bf16 a = *(bf16*)&u0.s[j]; u0.s[j] = f2bs(0.125f*b2f(a));
            bf16 c = *(bf16*)&u1.s[j]; u1.s[j] = f2bs(0.125f*b2f(c));
        }
        qa0 = u0.v; qa1 = u1.v;
    }
    fx4 o[4];                      // o[dt][r] = O[q = wid*16+quad*4+r][d = dt*16+l16]
    #pragma unroll
    for (int d=0; d<4; d++) o[d] = (fx4){0.f,0.f,0.f,0.f};
    float mrow = -1e30f, lrow = 0.f;   // per-lane scalars for q(local) = l16
    int srow = tid>>2, d0 = (tid&3)*16;
    int s_st = (srow>>2)*4 + (tid&3);
    int vsb  = (s_st ^ ((srow>>3)<<1))*KSTR + (srow&3)*16;
    short* pw = &Ps[(wid*16 + l16)*KSTR];      // this lane's q row
    const short* prd0 = &Ps[(wid*16+l16)*KSTR + quad*8];
    const short* prd1 = &Ps[(wid*16+l16)*KSTR + 32 + quad*8];
    unsigned vls = (unsigned)(size_t)(__attribute__((address_space(3))) short*)&Vs[0][0] + 2u*l16;
    #define TRA(vb,hf,c,dt) ((vb) + 144u*(unsigned)(((32*(hf) + 8*quad + 4*(c) + (dt)) ^ (8*(hf) + 2*quad))))
    bh8 kv0, kv1, vv0, vv1;
    {
        const bf16* krow = qkv + base + 768 + (size_t)srow*2304 + h*HD + d0;
        kv0 = *(const bh8*)(krow);
        kv1 = *(const bh8*)(krow + 8);
        vv0 = *(const bh8*)(krow + 768);
        vv1 = *(const bh8*)(krow + 776);
    }
    int p = 0;
    for (int kt=0; kt<9; kt++){
        short* KsP = &Ks[p][0];
        short* VsP = &Vs[p][0];
        *(bh8*)&KsP[srow*KSTR + d0]     = kv0;
        *(bh8*)&KsP[srow*KSTR + d0 + 8] = kv1;
        *(bh8*)&VsP[vsb]     = vv0;
        *(bh8*)&VsP[vsb + 8] = vv1;
        __syncthreads();
        if (kt < 8){   // prefetch next tile; latency hides under softmax+PV
            int kg = (kt+1)*64 + srow; if (kg > 512) kg = 512;
            const bf16* krow = qkv + base + 768 + (size_t)kg*2304 + h*HD + d0;
            kv0 = *(const bh8*)(krow);
            kv1 = *(const bh8*)(krow + 8);
            vv0 = *(const bh8*)(krow + 768);
            vv1 = *(const bh8*)(krow + 776);
        }
        unsigned vb = vls + 9216u*(unsigned)p;
        fx4 s[4];    // s[nt][r] = S^T[k = nt*16+quad*4+r][q = l16]
        __builtin_amdgcn_s_setprio(1);
        #pragma unroll
        for (int nt=0; nt<4; nt++){
            bh8 kb0 = *(const bh8*)&KsP[(nt*16+l16)*KSTR + quad*8];
            bh8 kb1 = *(const bh8*)&KsP[(nt*16+l16)*KSTR + 32 + quad*8];
            fx4 a = (fx4){0.f,0.f,0.f,0.f};
            a = __builtin_amdgcn_mfma_f32_16x16x32_bf16(kb0, qa0, a, 0,0,0);
            a = __builtin_amdgcn_mfma_f32_16x16x32_bf16(kb1, qa1, a, 0,0,0);
            s[nt] = a;
        }
        __builtin_amdgcn_s_setprio(0);
        // issue V^T transpose-reads early; latency hides under softmax
        u32x2 tv[16];
        #pragma unroll
        for (int dt=0; dt<4; dt++){
            tv[dt*4+0] = ds_tr16(TRA(vb,0,0,dt));
            tv[dt*4+1] = ds_tr16(TRA(vb,0,1,dt));
            tv[dt*4+2] = ds_tr16(TRA(vb,1,0,dt));
            tv[dt*4+3] = ds_tr16(TRA(vb,1,1,dt));
        }
        if (kt == 8){   // only k==512 valid in last tile: k_local = nt*16+quad*4+r == 0
            #pragma unroll
            for (int nt=0; nt<4; nt++)
                #pragma unroll
                for (int r=0;r<4;r++){
                    bool ok = (nt==0) && (r==0) && (quad==0);
                    s[nt][r] = ok ? s[nt][r] : -1e30f;
                }
        }
        // column (q=l16) max: 15 in-lane + 2 cross-quad rounds
        float ml = s[0][0];
        #pragma unroll
        for (int nt=0; nt<4; nt++)
            #pragma unroll
            for (int r=0;r<4;r++) if (nt|r) ml = fmaxf(ml, s[nt][r]);
        ml = fmaxf(ml, __shfl_xor(ml, 16, 64));
        ml = fmaxf(ml, __shfl_xor(ml, 32, 64));
        if (__any(ml > mrow)){           // exact: skipped only when al==1
            float mn = fmaxf(mrow, ml);
            float al = __expf(mrow - mn);
            mrow = mn;
            lrow *= al;
            // redistribute al to the output-layout q = quad*4+r
            float alr[4];
            #pragma unroll
            for (int r=0;r<4;r++) alr[r] = __shfl(al, quad*4 + r, 16);
            #pragma unroll
            for (int d=0; d<4; d++)
                #pragma unroll
                for (int r=0;r<4;r++) o[d][r] *= alr[r];
        }
        float ps = 0.f;
        #pragma unroll
        for (int nt=0; nt<4; nt++)
            #pragma unroll
            for (int r=0;r<4;r++){
                float pp = __expf(s[nt][r] - mrow);
                s[nt][r] = pp;
                ps += pp;
            }
        ps += __shfl_xor(ps, 16, 64);
        ps += __shfl_xor(ps, 32, 64);
        lrow += ps;
        // pack 4 consecutive k per nt -> one b64 store into Ps[q][k] (straight layout)
        #pragma unroll
        for (int nt=0; nt<4; nt++){
            u32x2 w;
            w[0] = cvtpk_bf16(s[nt][0], s[nt][1]);
            w[1] = cvtpk_bf16(s[nt][2], s[nt][3]);
            *(u32x2*)&pw[nt*16 + quad*4] = w;
        }
        bh8 pa0 = *(const bh8*)prd0;
        bh8 pa1 = *(const bh8*)prd1;
        asm volatile("s_waitcnt lgkmcnt(0)" ::: "memory");
        __builtin_amdgcn_sched_barrier(0);
        __builtin_amdgcn_s_setprio(1);
        #pragma unroll
        for (int dt=0; dt<4; dt++){
            union { u32x4 u; bh8 h; } v0, v1;
            v0.u = (u32x4){tv[dt*4+0][0], tv[dt*4+0][1], tv[dt*4+1][0], tv[dt*4+1][1]};
            v1.u = (u32x4){tv[dt*4+2][0], tv[dt*4+2][1], tv[dt*4+3][0], tv[dt*4+3][1]};
            o[dt] = __builtin_amdgcn_mfma_f32_16x16x32_bf16(pa0, v0.h, o[dt], 0,0,0);
            o[dt] = __builtin_amdgcn_mfma_f32_16x16x32_bf16(pa1, v1.h, o[dt], 0,0,0);
        }
        __builtin_amdgcn_s_setprio(0);
        p ^= 1;
    }
    #undef TRA
    // epilogue: redistribute 1/l to output-layout q = quad*4+r, coalesced global write
    float linv[4];
    #pragma unroll
    for (int r=0;r<4;r++) linv[r] = 1.0f / __shfl(lrow, quad*4 + r, 16);
    #pragma unroll
    for (int r=0;r<4;r++){
        int q = qt*64 + wid*16 + quad*4 + r;
        if (q < SEQ){
            size_t ob = ((size_t)(b*SEQ+q))*CDIM + h*HD;
            #pragma unroll
            for (int dt=0; dt<4; dt++)
                obuf[ob + dt*16 + l16] = __float2bfloat16(o[dt][r]*linv[r]);
        }
    }
}

// x2 = x1 + xffn + 0.5*(ah @ Wa2^T + ba2) -> d_out (fp32); block per row
__global__ __launch_bounds__(256) void k_comb(const bf16* __restrict__ x1, const bf16* __restrict__ xffn,
                                              const float* __restrict__ ah, const float* __restrict__ Wa2,
                                              const float* __restrict__ ba2, float* __restrict__ x2){
    int i = blockIdx.x; int tid = threadIdx.x;
    __shared__ float ar[16];
    if (tid < 16) ar[tid] = ah[(size_t)i*16 + tid];
    __syncthreads();
    for (int c=tid; c<CDIM; c+=256){
        const float* w = Wa2 + (size_t)c*16;
        float a = ba2[c];
        #pragma unroll
        for (int mm=0; mm<16; mm++) a += ar[mm]*w[mm];
        size_t o = (size_t)i*CDIM + c;
        x2[o] = b2f(x1[o]) + b2f(xffn[o]) + 0.5f*a;
    }
}

// ---------------- segment index build (cluster path, single) ----------------
__global__ __launch_bounds__(256) void k_icount(const int* __restrict__ idx, int* __restrict__ cnt, int n){
    int i = blockIdx.x*256 + threadIdx.x;
    if (i < n) atomicAdd(&cnt[idx[i]], 1);
}

__global__ __launch_bounds__(256) void k_iscan(const int* __restrict__ cnt, int* __restrict__ base,
                                               int* __restrict__ cur, int nseg){
    __shared__ int part[256], off[256];
    int t = threadIdx.x;
    int chunk = (nseg + 255) >> 8;
    int j0 = t*chunk, j1 = j0 + chunk; if (j1 > nseg) j1 = nseg;
    int s = 0;
    for (int j=j0; j<j1; j++) s += cnt[j];
    part[t] = s; __syncthreads();
    if (t == 0){ int acc=0; for (int i=0;i<256;i++){ off[i]=acc; acc+=part[i]; } }
    __syncthreads();
    int acc = off[t];
    for (int j=j0; j<j1; j++){ base[j]=acc; cur[j]=acc; acc+=cnt[j]; }
}

__global__ __launch_bounds__(256) void k_iscatter(const int* __restrict__ idx, int* __restrict__ cur,
                                                  int* __restrict__ order, int n){
    int i = blockIdx.x*256 + threadIdx.x;
    if (i < n){
        int pos = atomicAdd(&cur[idx[i]], 1);
        order[pos] = i;
    }
}

// ---------------- batched 6-view index build ----------------
__global__ __launch_bounds__(256) void k_icount6(const int* __restrict__ fgi, int* __restrict__ cnt){
    int g = blockIdx.x*256 + threadIdx.x;            // 0..6*NR-1
    int v = g >> 14;                                 // NR = 16384
    atomicAdd(&cnt[v*D1SEG + fgi[g]], 1);
}

__global__ __launch_bounds__(256) void k_iscan6(const int* __restrict__ cnt, int* __restrict__ base,
                                                int* __restrict__ cur){
    __shared__ int part[256], off[256];
    int v = blockIdx.x;
    const int* c = cnt + v*D1SEG;
    int* bs = base + v*D1SEG;
    int* cu = cur + v*D1SEG;
    int t = threadIdx.x;
    int chunk = (D1SEG + 255) >> 8;
    int j0 = t*chunk, j1 = j0 + chunk; if (j1 > D1SEG) j1 = D1SEG;
    int s = 0;
    for (int j=j0; j<j1; j++) s += c[j];
    part[t] = s; __syncthreads();
    if (t == 0){ int acc=0; for (int i=0;i<256;i++){ off[i]=acc; acc+=part[i]; } }
    __syncthreads();
    int acc = off[t];
    for (int j=j0; j<j1; j++){ bs[j]=acc; cu[j]=acc; acc+=c[j]; }
}

__global__ __launch_bounds__(256) void k_iscatter6(const int* __restrict__ fgi, int* __restrict__ cur,
                                                   int* __restrict__ order){
    int g = blockIdx.x*256 + threadIdx.x;
    int v = g >> 14;
    int pos = atomicAdd(&cur[v*D1SEG + fgi[g]], 1);
    order[(size_t)v*NR + pos] = g & (NR-1);
}

// gather + segment max/mean for cluster path
__global__ __launch_bounds__(256) void k_gather_seg(const float* __restrict__ outx, const int* __restrict__ basep,
                                                    const int* __restrict__ cntp, const int* __restrict__ order,
                                                    float* __restrict__ dst){
    int sg = blockIdx.x; int tid = threadIdx.x;
    int n = cntp[sg], b0 = basep[sg];
    float mx[3] = {-1e30f,-1e30f,-1e30f};
    float sm[3] = {0.f,0.f,0.f};
    for (int r=0; r<n; r++){
        int i = order[b0+r];
        size_t rb = (size_t)(i + (i>>9) + 1)*CDIM;
        #pragma unroll
        for (int j=0;j<3;j++){
            float v = outx[rb + tid + j*256];
            mx[j] = fmaxf(mx[j], v); sm[j] += v;
        }
    }
    float den = (float)(n > 1 ? n : 1);
    size_t db = (size_t)sg*CDIM;
    #pragma unroll
    for (int j=0;j<3;j++)
        dst[db + tid + j*256] = (n > 0 ? mx[j] : 0.f) + sm[j]/den;
}

// per-view: flat = o1@Wp^T + bp + feat, then segment max/mean
__global__ __launch_bounds__(256) void k_gather_flat(const float* __restrict__ outx, const float* __restrict__ o1v,
                                                     const float* __restrict__ Wp, const float* __restrict__ bp,
                                                     const int* __restrict__ basep, const int* __restrict__ cntp,
                                                     const int* __restrict__ order, float* __restrict__ dst){
    int sg = blockIdx.x; int tid = threadIdx.x;
    int n = cntp[sg], b0 = basep[sg];
    float w[3][MIDD], bb[3];
    #pragma unroll
    for (int j=0;j<3;j++){
        int c = tid + j*256;
        bb[j] = bp[c];
        #pragma unroll
        for (int mm=0;mm<MIDD;mm++) w[j][mm] = Wp[(size_t)c*MIDD + mm];
    }
    float mx[3] = {-1e30f,-1e30f,-1e30f};
    float sm[3] = {0.f,0.f,0.f};
    for (int r=0; r<n; r++){
        int i = order[b0+r];
        const float* orow = o1v + (size_t)i*MIDD;
        float ov[MIDD];
        #pragma unroll
        for (int mm=0;mm<MIDD;mm++) ov[mm] = orow[mm];
        size_t rb = (size_t)(i + (i>>9) + 1)*CDIM;
        #pragma unroll
        for (int j=0;j<3;j++){
            float a = bb[j];
            #pragma unroll
            for (int mm=0;mm<MIDD;mm++) a += ov[mm]*w[j][mm];
            a += outx[rb + tid + j*256];
            mx[j] = fmaxf(mx[j], a); sm[j] += a;
        }
    }
    float den = (float)(n > 1 ? n : 1);
    size_t db = (size_t)sg*CDIM;
    #pragma unroll
    for (int j=0;j<3;j++)
        dst[db + tid + j*256] = (n > 0 ? mx[j] : 0.f) + sm[j]/den;
}

// two-stage column stats (widened: 85 row-chunks -> 255 blocks)
__global__ __launch_bounds__(256) void k_colstats_part(const float* __restrict__ in, int rows,
                                                       float* __restrict__ sumv, float* __restrict__ sumsq){
    int c = blockIdx.x*256 + threadIdx.x;
    if (c >= CDIM) return;
    int chunk = (rows + 84) / 85;
    int r0 = blockIdx.y*chunk;
    int r1 = r0 + chunk; if (r1 > rows) r1 = rows;
    float s = 0.0f, s2 = 0.0f;
    for (int r=r0; r<r1; r++){
        float v = in[(size_t)r*CDIM + c];
        s += v; s2 += v*v;
    }
    atomicAdd(&sumv[c], s);
    atomicAdd(&sumsq[c], s2);
}

// BN (stats finalized inline from raw sums) + gelu
template<typename TO>
__global__ __launch_bounds__(256) void k_bngelu2(const float* __restrict__ in, TO* __restrict__ outp,
                                                 const float* __restrict__ sv, const float* __restrict__ sq,
                                                 const float* __restrict__ g, const float* __restrict__ b,
                                                 int n, float invn){
    int i = blockIdx.x*256 + threadIdx.x;
    if (i >= n) return;
    int c = i - (i/CDIM)*CDIM;
    float m = sv[c]*invn;
    float var = sq[c]*invn - m*m;
    float r = rsqrtf(fmaxf(var, 0.0f) + 1e-5f);
    float y = (in[i]-m)*r*g[c] + b[c];
    stv(outp, (size_t)i, 0.5f*y*(1.0f + erff(y*0.70710678118654752f)));
}

// per-view micro attention: block per (segblock, view); 256 threads = 2 head-groups x 128 rows.
#define MSTR 33    // mask row stride in dwords (132 B)
__global__ __launch_bounds__(256) void k_attnv(const float* __restrict__ qkv1a,
                                               const unsigned char* __restrict__ mask,
                                               float* __restrict__ o1all){
    __shared__ float Qs[N1V][13], Ksv[N1V][13], Vsv[N1V][13];
    __shared__ int   Ms[N1V*MSTR];
    int blk = blockIdx.x, v = blockIdx.y;
    int tid = threadIdx.x;
    // stage Q/K/V: threads 0..127, one row each (9 float4 = 36 floats)
    if (tid < N1V){
        const float4* rp = (const float4*)(qkv1a + (size_t)(blk*N1V + tid)*216 + v*36);
        #pragma unroll
        for (int j=0;j<3;j++){
            float4 q4 = rp[j], k4 = rp[3+j], v4 = rp[6+j];
            Qs[tid][j*4+0]=q4.x; Qs[tid][j*4+1]=q4.y; Qs[tid][j*4+2]=q4.z; Qs[tid][j*4+3]=q4.w;
            Ksv[tid][j*4+0]=k4.x; Ksv[tid][j*4+1]=k4.y; Ksv[tid][j*4+2]=k4.z; Ksv[tid][j*4+3]=k4.w;
            Vsv[tid][j*4+0]=v4.x; Vsv[tid][j*4+1]=v4.y; Vsv[tid][j*4+2]=v4.z; Vsv[tid][j*4+3]=v4.w;
        }
    }
    // stage mask tile (16 KB) coalesced, write at stride 132 B
    {
        const int4* mp = (const int4*)(mask + ((size_t)v*NB1 + blk)*N1V*N1V);
        #pragma unroll
        for (int it=0; it<4; it++){
            int e = tid + it*256;            // 0..1023 int4s
            int4 m4 = mp[e];
            int row = e >> 3, c4 = (e & 7)*4;
            Ms[row*MSTR + c4 + 0] = m4.x;
            Ms[row*MSTR + c4 + 1] = m4.y;
            Ms[row*MSTR + c4 + 2] = m4.z;
            Ms[row*MSTR + c4 + 3] = m4.w;
        }
    }
    __syncthreads();
    int n = tid & 127, hg = tid >> 7;
    const float scale = 0.28867513459481287f; // 12^-0.5
    #pragma unroll
    for (int hh=0; hh<3; hh++){
        int h = hg*3 + hh;
        float q0 = Qs[n][h*2], q1 = Qs[n][h*2+1];
        float m = -1e30f;
        #pragma unroll 4
        for (int k4=0; k4<32; k4++){
            int mw = Ms[n*MSTR + k4];
            #pragma unroll
            for (int j=0;j<4;j++){
                int k = k4*4 + j;
                float s = (q0*Ksv[k][h*2] + q1*Ksv[k][h*2+1])*scale + (((mw>>(j*8))&0xFF) ? -100000.0f : 0.0f);
                m = fmaxf(m, s);
            }
        }
        float l = 0.f, o0 = 0.f, o1v = 0.f;
        #pragma unroll 4
        for (int k4=0; k4<32; k4++){
            int mw = Ms[n*MSTR + k4];
            #pragma unroll
            for (int j=0;j<4;j++){
                int k = k4*4 + j;
                float s = (q0*Ksv[k][h*2] + q1*Ksv[k][h*2+1])*scale + (((mw>>(j*8))&0xFF) ? -100000.0f : 0.0f);
                float p = __expf(s - m);
                l += p; o0 += p*Vsv[k][h*2]; o1v += p*Vsv[k][h*2+1];
            }
        }
        float inv = 1.0f/l;
        float* orow = o1all + ((size_t)v*NR + blk*N1V + n)*MIDD + h*2;
        orow[0] = o0*inv; orow[1] = o1v*inv;
    }
}

// cossim + sims-normalize + weighted sum + residual; block per token row; in-place on d_out
__global__ __launch_bounds__(256) void k_final(float* __restrict__ outx, const float* __restrict__ x3d,
                                               const bf16* __restrict__ bnv, const int* __restrict__ cluster,
                                               const int* __restrict__ fgi){
    int i = blockIdx.x; int tid = threadIdx.x;
    int cl = cluster[i];
    const float* xr = x3d + (size_t)cl*CDIM;
    const bf16* pr[NVIEW];
    #pragma unroll
    for (int v=0; v<NVIEW; v++)
        pr[v] = bnv + ((size_t)v*D1SEG + fgi[(size_t)v*NR + i])*CDIM;
    size_t rb = (size_t)(i + (i>>9) + 1)*CDIM;
    float pv[NVIEW][3], ft[3];
    float dotv[NVIEW] = {0,0,0,0,0,0};
    float np2[NVIEW]  = {0,0,0,0,0,0};
    float nx2 = 0.0f;
    #pragma unroll
    for (int j=0; j<3; j++){
        int c = tid + j*256;
        float xv = xr[c]; nx2 += xv*xv;
        ft[j] = outx[rb + c];
        #pragma unroll
        for (int v=0; v<NVIEW; v++){
            float p = b2f(pr[v][c]); pv[v][j] = p;
            dotv[v] += p*xv; np2[v] += p*p;
        }
    }
    __shared__ float part[4*13];
    __shared__ float ssim[NVIEW];
    float vals[13];
    vals[0] = nx2;
    #pragma unroll
    for (int v=0; v<NVIEW; v++){ vals[1+v] = dotv[v]; vals[7+v] = np2[v]; }
    int lane = tid & 63, wid = tid >> 6;
    #pragma unroll
    for (int k=0; k<13; k++){
        float w = vals[k];
        #pragma unroll
        for (int o=32;o;o>>=1) w += __shfl_down(w,o,64);
        if (!lane) part[wid*13 + k] = w;
    }
    __syncthreads();
    if (tid == 0){
        float tot[13];
        #pragma unroll
        for (int k=0; k<13; k++) tot[k] = part[k] + part[13+k] + part[26+k] + part[39+k];
        float nb = fmaxf(sqrtf(tot[0]), 1e-8f);
        float sv[NVIEW]; float ssumv = 0.0f;
        #pragma unroll
        for (int v=0; v<NVIEW; v++){
            float na = fmaxf(sqrtf(tot[7+v]), 1e-8f);
            float cs = tot[1+v] / (na*nb);
            sv[v] = (cs + 1.0f)*0.5f;
            ssumv += sv[v];
        }
        #pragma unroll
        for (int v=0; v<NVIEW; v++) ssim[v] = sv[v]/ssumv;
    }
    __syncthreads();
    #pragma unroll
    for (int j=0; j<3; j++){
        int c = tid + j*256;
        float xs = 0.0f;
        #pragma unroll
        for (int v=0; v<NVIEW; v++) xs += ssim[v]*pv[v][j];
        outx[rb + c] = ft[j] + 0.3f*xs;
    }
}

// ---------------- host launcher ----------------
extern "C" void kernel_launch(void* const* d_in, const int* in_sizes, int n_in,
                              void* d_out, int out_size, void* d_ws, size_t ws_size,
                              hipStream_t stream){
    const float* x     = (const float*)d_in[0];
    const float* ln1g  = (const float*)d_in[1];
    const float* ln1b  = (const float*)d_in[2];
    const float* ln2g  = (const float*)d_in[3];
    const float* ln2b  = (const float*)d_in[4];
    const float* Wqkv  = (const float*)d_in[5];
    const float* bqkv  = (const float*)d_in[6];
    const float* Wo    = (const float*)d_in[7];
    const float* bo    = (const float*)d_in[8];
    const float* Wfc   = (const float*)d_in[9];
    const float* bfc   = (const float*)d_in[10];
    const float* Wproj = (const float*)d_in[11];
    const float* bproj = (const float*)d_in[12];
    const float* Wa1   = (const float*)d_in[13];
    const float* ba1   = (const float*)d_in[14];
    const float* Wa2   = (const float*)d_in[15];
    const float* ba2   = (const float*)d_in[16];
    const float* bn3dg = (const float*)d_in[17];
    const float* bn3db = (const float*)d_in[18];
    const float* bn1dg = (const float*)d_in[19];
    const float* bn1db = (const float*)d_in[20];
    const float* n3g   = (const float*)d_in[21];
    const float* n3b   = (const float*)d_in[22];
    const float* aqw   = (const float*)d_in[23];
    const float* aqb   = (const float*)d_in[24];
    const float* apw   = (const float*)d_in[25];
    const float* apb   = (const float*)d_in[26];
    const int*   cluster = (const int*)d_in[27];
    const int*   fgi     = (const int*)d_in[28];
    const unsigned char* mask = (const unsigned char*)d_in[29];
    float* out = (float*)d_out;
    float* ws  = (float*)d_ws;

    bf16*  yb    = (bf16*)(ws + A_FS);
    bf16*  qkvb  = (bf16*)(ws + B_FS);
    bf16*  hb    = (bf16*)(ws + B_FS);          // FFN hidden chunk (8208 rows)
    bf16*  xffb  = (bf16*)(ws + B_FS + 12607488);
    float* qkv1a = ws + B_FS;                   // phase 2
    float* o1all = ws + B_FS + 3538944;
    float* svs   = ws + B_FS + 4718592;
    bf16*  x1b   = (bf16*)(ws + X1_FS);
    float* ah    = ws + AH_FS;
    int*   icnt  = (int*)(ws + DI_CNT);
    int*   ibase = (int*)(ws + DI_BASE);
    int*   icur  = (int*)(ws + DI_CUR);
    int*   iord  = (int*)(ws + DI_ORD);
    float* x3d   = ws + X3D_FS;
    bf16*  bnv   = (bf16*)(ws + BNV_FS);
    float* statm = ws + STATM_FS;
    float* statr = ws + STATR_FS;
    bf16* WqkvB  = (bf16*)(ws + DW_FS);
    bf16* WoB    = WqkvB + 2304*768;
    bf16* WfcB   = WoB   + 768*768;
    bf16* WprojB = WfcB  + 3072*768;
    bf16* WvB    = (bf16*)(ws + DWV_FS);        // 216x768
    float* bvP   = ws + DWV_FS + 82944;
    bf16* Wa1B   = (bf16*)(ws + DWV_FS + 83200);
    // phase-2 batched view index arrays + stats in the (dead) ah region:
    int*   icnt6  = (int*)(ws + AH_FS);
    int*   ibase6 = icnt6 + 6*D1SEG;
    int*   icur6  = ibase6 + 6*D1SEG;
    int*   iord6  = icur6 + 6*D1SEG;
    float* stat6  = (float*)(iord6 + 6*NR);

    // 0. weight conversion / folding (single fused launch + foldw)
    k_f2b5<<<2048, 256, 0, stream>>>(Wqkv, WqkvB, 2304*768,  Wo, WoB, 768*768,
                                     Wfc, WfcB, 3072*768,    Wproj, WprojB, 768*3072,
                                     Wa1, Wa1B, 16*768);
    k_foldw<<<216, 256, 0, stream>>>(aqw, aqb, n3g, n3b, WvB, bvP);
    // 1. LN1
    k_ln<float><<<NT, 256, 0, stream>>>(x, yb, ln1g, ln1b);
    // 2. qkv GEMM (128x256 8-wave)
    k_gemm_mfma2<bf16,0,0><<<(2304/256)*((NT+127)/128), 512, 0, stream>>>(yb, WqkvB, bqkv, nullptr, qkvb, NT, 2304, 768);
    // 3. flash attention (1D XCD-affine grid: 8 * 9 * 48 = 3456)
    k_attn_mfma<<<3456, 256, 0, stream>>>(qkvb, yb);
    // 4. o-proj + residual(x)
    k_gemm_mfma2<bf16,0,1><<<(768/256)*((NT+127)/128), 512, 0, stream>>>(yb, WoB, bo, x, x1b, NT, 768, 768);
    // 5. LN2
    k_ln<bf16><<<NT, 256, 0, stream>>>(x1b, yb, ln2g, ln2b);
    // 6/7. FFN in 2 row-chunks
    for (int cch=0; cch<2; cch++){
        const bf16* a2 = yb + (size_t)cch*CHROWS*CDIM;
        bf16* xo = xffb + (size_t)cch*CHROWS*CDIM;
        k_gemm_mfma2<bf16,1,0><<<(FFDIM/256)*((CHROWS+127)/128), 512, 0, stream>>>(a2, WfcB, bfc, nullptr, hb, CHROWS, FFDIM, 768);
        k_gemm_mfma2<bf16,0,0><<<(768/256)*((CHROWS+127)/128), 512, 0, stream>>>(hb, WprojB, bproj, nullptr, xo, CHROWS, 768, FFDIM);
    }
    // 8. adapt hidden (tiny N: keep 4-wave kernel)
    k_gemm_mfma<float,1,0><<<1*((NT+127)/128), 256, 0, stream>>>(xffb, Wa1B, ba1, nullptr, ah, NT, 16, 768);
    // 9. combine -> d_out
    k_comb<<<NT, 256, 0, stream>>>(x1b, xffb, ah, Wa2, ba2, out);
    // 10. cluster path
    k_zero<<<32, 256, 0, stream>>>((float*)icnt, NCLUST);
    k_icount<<<NR/256, 256, 0, stream>>>(cluster, icnt, NR);
    k_iscan<<<1, 256, 0, stream>>>(icnt, ibase, icur, NCLUST);
    k_iscatter<<<NR/256, 256, 0, stream>>>(cluster, icur, iord, NR);
    k_gather_seg<<<NCLUST, 256, 0, stream>>>(out, ibase, icnt, iord, x3d);
    k_zero<<<6, 256, 0, stream>>>(statm, 1536);
    k_colstats_part<<<dim3(3, 85), 256, 0, stream>>>(x3d, NCLUST, statm, statr);
    k_bngelu2<float><<<(NCLUST*CDIM+255)/256, 256, 0, stream>>>(x3d, x3d, statm, statr, bn3dg, bn3db,
                                                                NCLUST*CDIM, 1.0f/NCLUST);
    // 11. view shared prep
    k_lnn<<<NR, 256, 0, stream>>>(out, yb);
    k_gemm_mfma<float,0,0><<<2*(NR/128), 256, 0, stream>>>(yb, WvB, bvP, nullptr, qkv1a, NR, 216, 768);
    k_attnv<<<dim3(NB1, NVIEW), 256, 0, stream>>>(qkv1a, mask, o1all);
    // 12. batched 6-view index build (one zero covers idx arrays + stat6), then per-view
    k_zero<<<(220416+255)/256, 256, 0, stream>>>((float*)icnt6, 220416);
    k_icount6<<<6*NR/256, 256, 0, stream>>>(fgi, icnt6);
    k_iscan6<<<6, 256, 0, stream>>>(icnt6, ibase6, icur6);
    k_iscatter6<<<6*NR/256, 256, 0, stream>>>(fgi, icur6, iord6);
    for (int v=0; v<NVIEW; v++){
        k_gather_flat<<<D1SEG, 256, 0, stream>>>(out, o1all + (size_t)v*NR*MIDD,
                                                 apw + (size_t)v*CDIM*MIDD, apb + (size_t)v*CDIM,
                                                 ibase6 + v*D1SEG, icnt6 + v*D1SEG, iord6 + (size_t)v*NR, svs);
        k_colstats_part<<<dim3(3, 85), 256, 0, stream>>>(svs, D1SEG, stat6 + v*1536, stat6 + v*1536 + 768);
        k_bngelu2<bf16><<<(D1SEG*CDIM+255)/256, 256, 0, stream>>>(svs, bnv + (size_t)v*D1SEG*CDIM,
                                                                  stat6 + v*1536, stat6 + v*1536 + 768,
                                                                  bn1dg + v*CDIM, bn1db + v*CDIM,
                                                                  D1SEG*CDIM, 1.0f/D1SEG);
    }
    // 13. final combine
    k_final<<<NR, 256, 0, stream>>>(out, x3d, bnv, cluster, fgi);
}

// Round 8
// 1350.104 us; speedup vs baseline: 1.3533x; 1.0100x over previous
//
#include <hip/hip_runtime.h>
#include <hip/hip_bf16.h>
#include <math.h>

typedef unsigned int u32;
typedef __hip_bfloat16 bf16;
typedef __attribute__((ext_vector_type(8))) short bh8;
typedef __attribute__((ext_vector_type(4))) float fx4;
typedef __attribute__((ext_vector_type(2))) unsigned int u32x2;
typedef __attribute__((ext_vector_type(4))) unsigned int u32x4;

#define CDIM   768
#define BATCH  32
#define SEQ    513
#define NT     (BATCH*SEQ)     // 16416 rows incl cls
#define NR     16384           // BG
#define NHEAD  12
#define HD     64
#define FFDIM  3072
#define NCLUST 2048
#define D1SEG  6272
#define NVIEW  6
#define MIDD   12
#define H1N    6
#define N1V    128
#define NB1    128
#define CHROWS 8208            // FFN row chunk (2 chunks)

// ---------------- workspace layout (float-slot offsets; ≈229.8 MB total) ----
#define A_FS      ((size_t)0)          // 6,303,744 fs : y / obuf / y2 / yv  (NT*768 bf16)
#define B_FS      ((size_t)6303744)    // 18,911,232 fs: qkv bf16 | h+xffn bf16 | qkv1a+o1all+svs
#define X1_FS     ((size_t)25214976)   // 6,303,744 fs : x1 bf16
#define AH_FS     ((size_t)31518720)   // 262,656 fs   : ah fp32 | (phase2) batched view idx + stats
#define D_FS      ((size_t)31781376)   // 9,640,064 fs : index arrays | bf16 weights
#define DTOT_FS   9640064
#define X3D_FS    ((size_t)(D_FS + DTOT_FS))          // 1,572,864 fs x3d fp32
#define BNV_FS    (X3D_FS + 1572864)                  // 14,450,688 fs bnv bf16
#define STATM_FS  (BNV_FS + 14450688)                 // 768
#define STATR_FS  (STATM_FS + 768)                    // 768
#define DI_CNT    (D_FS)
#define DI_BASE   (D_FS + 6272)
#define DI_CUR    (D_FS + 12544)
#define DI_ORD    (D_FS + 18816)
#define DW_FS     (D_FS + 40960)
#define DWV_FS    (D_FS + 3600000)

__device__ inline float b2f(bf16 v){ return __bfloat162float(v); }
__device__ inline float ldv(const float* p, size_t i){ return p[i]; }
__device__ inline float ldv(const bf16*  p, size_t i){ return __bfloat162float(p[i]); }
__device__ inline void  stv(float* p, size_t i, float v){ p[i] = v; }
__device__ inline void  stv(bf16*  p, size_t i, float v){ p[i] = __float2bfloat16(v); }
__device__ inline short f2bs(float f){ bf16 h = __float2bfloat16(f); return *(short*)&h; }
__device__ inline void gload_lds16(const bf16* g, short* l){
    __builtin_amdgcn_global_load_lds((const __attribute__((address_space(1))) void*)g,
                                     (__attribute__((address_space(3))) void*)l, 16, 0, 0);
}
// gfx950 LDS transpose-read: per-lane address, 4 bf16 at +0/+32/+64/+96 bytes
__device__ inline u32x2 ds_tr16(unsigned a){
    u32x2 d;
    asm volatile("ds_read_b64_tr_b16 %0, %1" : "=v"(d) : "v"(a));
    return d;
}
__device__ inline unsigned cvtpk_bf16(float lo, float hi){
    unsigned r;
    asm("v_cvt_pk_bf16_f32 %0, %1, %2" : "=v"(r) : "v"(lo), "v"(hi));
    return r;
}

// ---------------- utility ----------------

__global__ __launch_bounds__(256) void k_zero(float* p, int n){
    for (int i = blockIdx.x*256 + threadIdx.x; i < n; i += gridDim.x*256) p[i] = 0.0f;
}

// fused 5-way f32 -> bf16 weight conversion (one launch)
__global__ __launch_bounds__(256) void k_f2b5(const float* __restrict__ a0, bf16* __restrict__ b0, int n0,
                                              const float* __restrict__ a1, bf16* __restrict__ b1, int n1,
                                              const float* __restrict__ a2, bf16* __restrict__ b2, int n2,
                                              const float* __restrict__ a3, bf16* __restrict__ b3, int n3,
                                              const float* __restrict__ a4, bf16* __restrict__ b4, int n4){
    int i0 = blockIdx.x*256 + threadIdx.x, st = gridDim.x*256;
    for (int i=i0; i<n0; i+=st) b0[i] = __float2bfloat16(a0[i]);
    for (int i=i0; i<n1; i+=st) b1[i] = __float2bfloat16(a1[i]);
    for (int i=i0; i<n2; i+=st) b2[i] = __float2bfloat16(a2[i]);
    for (int i=i0; i<n3; i+=st) b3[i] = __float2bfloat16(a3[i]);
    for (int i=i0; i<n4; i+=st) b4[i] = __float2bfloat16(a4[i]);
}

// LayerNorm over C=768, one block per row; out bf16
template<typename TI>
__global__ __launch_bounds__(256) void k_ln(const TI* __restrict__ in, bf16* __restrict__ out,
                                            const float* __restrict__ g, const float* __restrict__ b){
    int i = blockIdx.x;
    int tid = threadIdx.x;
    const TI* r = in + (size_t)i*CDIM;
    float v0 = ldv(r,(size_t)tid), v1 = ldv(r,(size_t)tid+256), v2 = ldv(r,(size_t)tid+512);
    float s  = v0+v1+v2;
    float s2 = v0*v0+v1*v1+v2*v2;
    __shared__ float t1[4], t2[4];
    #pragma unroll
    for (int o=32;o;o>>=1){ s += __shfl_down(s,o,64); s2 += __shfl_down(s2,o,64); }
    int lane = tid & 63, wid = tid >> 6;
    if (!lane){ t1[wid]=s; t2[wid]=s2; }
    __syncthreads();
    float S  = t1[0]+t1[1]+t1[2]+t1[3];
    float S2 = t2[0]+t2[1]+t2[2]+t2[3];
    float m  = S * (1.0f/CDIM);
    float var = S2 * (1.0f/CDIM) - m*m;
    float rstd = rsqrtf(var + 1e-5f);
    bf16* o_ = out + (size_t)i*CDIM;
    stv(o_,(size_t)tid,     (v0-m)*rstd*g[tid]     + b[tid]);
    stv(o_,(size_t)tid+256, (v1-m)*rstd*g[tid+256] + b[tid+256]);
    stv(o_,(size_t)tid+512, (v2-m)*rstd*g[tid+512] + b[tid+512]);
}

// normalize-only LN (affine folded into downstream weights), token-row map on input
__global__ __launch_bounds__(256) void k_lnn(const float* __restrict__ in, bf16* __restrict__ out){
    int i = blockIdx.x;
    size_t ri = (size_t)(i + (i>>9) + 1);
    int tid = threadIdx.x;
    const float* r = in + ri*CDIM;
    float v0 = r[tid], v1 = r[tid+256], v2 = r[tid+512];
    float s  = v0+v1+v2;
    float s2 = v0*v0+v1*v1+v2*v2;
    __shared__ float t1[4], t2[4];
    #pragma unroll
    for (int o=32;o;o>>=1){ s += __shfl_down(s,o,64); s2 += __shfl_down(s2,o,64); }
    int lane = tid & 63, wid = tid >> 6;
    if (!lane){ t1[wid]=s; t2[wid]=s2; }
    __syncthreads();
    float S  = t1[0]+t1[1]+t1[2]+t1[3];
    float S2 = t2[0]+t2[1]+t2[2]+t2[3];
    float m  = S * (1.0f/CDIM);
    float var = S2 * (1.0f/CDIM) - m*m;
    float rstd = rsqrtf(var + 1e-5f);
    bf16* o_ = out + (size_t)i*CDIM;
    stv(o_,(size_t)tid,     (v0-m)*rstd);
    stv(o_,(size_t)tid+256, (v1-m)*rstd);
    stv(o_,(size_t)tid+512, (v2-m)*rstd);
}

// fold per-view LN affine into view-qkv weights
__global__ __launch_bounds__(256) void k_foldw(const float* __restrict__ aqw, const float* __restrict__ aqb,
                                               const float* __restrict__ n3g, const float* __restrict__ n3b,
                                               bf16* __restrict__ Wv, float* __restrict__ bv){
    int row = blockIdx.x;                  // 0..215
    int v = row/36;
    const float* w = aqw + (size_t)row*768;
    const float* g = n3g + v*768;
    const float* b = n3b + v*768;
    int tid = threadIdx.x;
    float s = 0.0f;
    #pragma unroll
    for (int j=tid; j<768; j+=256){
        float wv = w[j];
        Wv[(size_t)row*768 + j] = __float2bfloat16(wv*g[j]);
        s += wv*b[j];
    }
    __shared__ float t1[4];
    #pragma unroll
    for (int o=32;o;o>>=1) s += __shfl_down(s,o,64);
    int lane = tid & 63, wid = tid >> 6;
    if (!lane) t1[wid]=s;
    __syncthreads();
    if (tid==0) bv[row] = aqb[row] + t1[0]+t1[1]+t1[2]+t1[3];
}

// ---------------- MFMA GEMM (small-N): 128x128, 4 waves, 3-buffer counted vmcnt ----
template<typename TO, int ACT, int RES>
__global__ __launch_bounds__(256) void k_gemm_mfma(const bf16* __restrict__ A, const bf16* __restrict__ W,
                                                   const float* __restrict__ bias, const float* __restrict__ res,
                                                   TO* __restrict__ out, int M, int N, int K){
    __shared__ short As[3][128*32];
    __shared__ short Ws[3][128*32];
    int nbx = (N + 127) >> 7;
    int nwg = gridDim.x;
    int orig = blockIdx.x;
    int xcd = orig & 7, sl = orig >> 3;
    int q8 = nwg >> 3, r8 = nwg & 7;
    int wg = (xcd < r8 ? xcd*(q8+1) : r8*(q8+1) + (xcd - r8)*q8) + sl;
    int by = wg / nbx;
    int bm = by*128, bn = (wg - by*nbx)*128;
    int tid = threadIdx.x, wid = tid>>6, lane = tid&63, quad = lane>>4, l16 = lane&15;
    int wr = (wid>>1)*64, wc = (wid&1)*64;
    fx4 acc[4][4];
    #pragma unroll
    for (int i=0;i<4;i++)
        #pragma unroll
        for (int j=0;j<4;j++) acc[i][j] = (fx4){0.f,0.f,0.f,0.f};
    int lrow = lane>>2;
    int gchunk = (lane&3) ^ ((lane>>3)&3);           // global k-chunk (XOR swizzle)
    int r0a0 = wid*32 + lrow,  r0a1 = wid*32 + 16 + lrow;
    int ra0 = bm + r0a0; if (ra0 > M-1) ra0 = M-1;
    int ra1 = bm + r0a1; if (ra1 > M-1) ra1 = M-1;
    int rw0 = bn + r0a0; if (rw0 > N-1) rw0 = N-1;
    int rw1 = bn + r0a1; if (rw1 > N-1) rw1 = N-1;
    const bf16* pa0 = A + (size_t)ra0*K + gchunk*8;
    const bf16* pa1 = A + (size_t)ra1*K + gchunk*8;
    const bf16* pw0 = W + (size_t)rw0*K + gchunk*8;
    const bf16* pw1 = W + (size_t)rw1*K + gchunk*8;
    int sL0 = (wid*32)*32;           // wave-uniform LDS stripe bases
    int sL1 = (wid*32 + 16)*32;
    int slotx = (l16>>1)&3;                          // read-side swizzle component
    int nt = K >> 5;
    #define STAGE4(bsel, t) do { int _k0 = (t) << 5;               \
        gload_lds16(pa0 + _k0, &As[(bsel)][sL0]);                  \
        gload_lds16(pa1 + _k0, &As[(bsel)][sL1]);                  \
        gload_lds16(pw0 + _k0, &Ws[(bsel)][sL0]);                  \
        gload_lds16(pw1 + _k0, &Ws[(bsel)][sL1]); } while(0)
    STAGE4(0, 0);
    STAGE4(1, 1);
    int cur = 0;
    for (int t = 0; t < nt; ++t){
        if (t + 1 < nt) asm volatile("s_waitcnt vmcnt(4)" ::: "memory");
        else            asm volatile("s_waitcnt vmcnt(0)" ::: "memory");
        __builtin_amdgcn_s_barrier();
        __builtin_amdgcn_sched_barrier(0);
        if (t + 2 < nt){                 // issue next-next tile loads EARLY
            int nb = cur + 2; if (nb >= 3) nb -= 3;
            STAGE4(nb, t + 2);
        }
        const short* Ab = &As[cur][0];
        const short* Wb = &Ws[cur][0];
        bh8 af[4], bf_[4];
        int sa = (quad ^ slotx)*8;
        #pragma unroll
        for (int i=0;i<4;i++) af[i]  = *(const bh8*)&Ab[(wr + i*16 + l16)*32 + sa];
        #pragma unroll
        for (int j=0;j<4;j++) bf_[j] = *(const bh8*)&Wb[(wc + j*16 + l16)*32 + sa];
        #pragma unroll
        for (int i=0;i<4;i++)
            #pragma unroll
            for (int j=0;j<4;j++)
                acc[i][j] = __builtin_amdgcn_mfma_f32_16x16x32_bf16(af[i], bf_[j], acc[i][j], 0,0,0);
        cur += 1; if (cur == 3) cur = 0;
    }
    #undef STAGE4
    #pragma unroll
    for (int i=0;i<4;i++){
        #pragma unroll
        for (int r=0;r<4;r++){
            int row = bm + wr + i*16 + quad*4 + r;
            if (row >= M) continue;
            #pragma unroll
            for (int j=0;j<4;j++){
                int col = bn + wc + j*16 + l16;
                if (col >= N) continue;
                float v = acc[i][j][r] + bias[col];
                if (ACT == 1) v = v / (1.0f + __expf(-1.702f*v));
                if (RES) v += res[(size_t)row*N + col];
                stv(out, (size_t)row*N + col, v);
            }
        }
    }
}

// ---------------- MFMA GEMM (big-N): 128x256, 8 waves (512 thr), same 3-buffer pipeline ----
template<typename TO, int ACT, int RES>
__global__ __launch_bounds__(512) void k_gemm_mfma2(const bf16* __restrict__ A, const bf16* __restrict__ W,
                                                    const float* __restrict__ bias, const float* __restrict__ res,
                                                    TO* __restrict__ out, int M, int N, int K){
    __shared__ short As[3][128*32];
    __shared__ short Ws[3][256*32];
    int nbx = (N + 255) >> 8;
    int nwg = gridDim.x;
    int orig = blockIdx.x;
    int xcd = orig & 7, sl = orig >> 3;
    int q8 = nwg >> 3, r8 = nwg & 7;
    int wg = (xcd < r8 ? xcd*(q8+1) : r8*(q8+1) + (xcd - r8)*q8) + sl;
    int by = wg / nbx;
    int bm = by*128, bn = (wg - by*nbx)*256;
    int tid = threadIdx.x, wid = tid>>6, lane = tid&63, quad = lane>>4, l16 = lane&15;
    int wr = (wid>>2)*64, wc = (wid&3)*64;
    fx4 acc[4][4];
    #pragma unroll
    for (int i=0;i<4;i++)
        #pragma unroll
        for (int j=0;j<4;j++) acc[i][j] = (fx4){0.f,0.f,0.f,0.f};
    int lrow = lane>>2;
    int gchunk = (lane&3) ^ ((lane>>3)&3);           // global k-chunk (XOR swizzle)
    int ra0 = bm + wid*16 + lrow;      if (ra0 > M-1) ra0 = M-1;
    int rw0 = bn + wid*32 + lrow;      if (rw0 > N-1) rw0 = N-1;
    int rw1 = bn + wid*32 + 16 + lrow; if (rw1 > N-1) rw1 = N-1;
    const bf16* pa0 = A + (size_t)ra0*K + gchunk*8;
    const bf16* pw0 = W + (size_t)rw0*K + gchunk*8;
    const bf16* pw1 = W + (size_t)rw1*K + gchunk*8;
    int sA  = (wid*16)*32;
    int sB0 = (wid*32)*32;
    int sB1 = (wid*32 + 16)*32;
    int slotx = (l16>>1)&3;                          // read-side swizzle component
    int nt = K >> 5;
    #define STAGE3(bsel, t) do { int _k0 = (t) << 5;               \
        gload_lds16(pa0 + _k0, &As[(bsel)][sA]);                   \
        gload_lds16(pw0 + _k0, &Ws[(bsel)][sB0]);                  \
        gload_lds16(pw1 + _k0, &Ws[(bsel)][sB1]); } while(0)
    STAGE3(0, 0);
    STAGE3(1, 1);
    int cur = 0;
    for (int t = 0; t < nt; ++t){
        if (t + 1 < nt) asm volatile("s_waitcnt vmcnt(3)" ::: "memory");
        else            asm volatile("s_waitcnt vmcnt(0)" ::: "memory");
        __builtin_amdgcn_s_barrier();
        __builtin_amdgcn_sched_barrier(0);
        if (t + 2 < nt){                 // issue next-next tile loads EARLY
            int nb = cur + 2; if (nb >= 3) nb -= 3;
            STAGE3(nb, t + 2);
        }
        const short* Ab = &As[cur][0];
        const short* Wb = &Ws[cur][0];
        bh8 af[4], bf_[4];
        int sa = (quad ^ slotx)*8;
        #pragma unroll
        for (int i=0;i<4;i++) af[i]  = *(const bh8*)&Ab[(wr + i*16 + l16)*32 + sa];
        #pragma unroll
        for (int j=0;j<4;j++) bf_[j] = *(const bh8*)&Wb[(wc + j*16 + l16)*32 + sa];
        #pragma unroll
        for (int i=0;i<4;i++)
            #pragma unroll
            for (int j=0;j<4;j++)
                acc[i][j] = __builtin_amdgcn_mfma_f32_16x16x32_bf16(af[i], bf_[j], acc[i][j], 0,0,0);
        cur += 1; if (cur == 3) cur = 0;
    }
    #undef STAGE3
    #pragma unroll
    for (int i=0;i<4;i++){
        #pragma unroll
        for (int r=0;r<4;r++){
            int row = bm + wr + i*16 + quad*4 + r;
            if (row >= M) continue;
            #pragma unroll
            for (int j=0;j<4;j++){
                int col = bn + wc + j*16 + l16;
                if (col >= N) continue;
                float v = acc[i][j][r] + bias[col];
                if (ACT == 1) v = v / (1.0f + __expf(-1.702f*v));
                if (RES) v += res[(size_t)row*N + col];
                stv(out, (size_t)row*N + col, v);
            }
        }
    }
}

// ---------------- MFMA GEMM (256x256): 16 waves (1024 thr), 3-buffer counted vmcnt ----
// Wave grid 4(M)x4(N), per-wave output 64x64 (fragment math identical to the 4/8-wave
// kernels). Staging per wave per tile: 1 A-gload (rows [wid*16,+16)) + 1 B-gload -> vmcnt(2).
// LDS 96KB -> 1 block/CU, 16 waves = 4 waves/SIMD (launch_bounds caps VGPR <= 128).
// Halves per-output L2 traffic vs 128x256 (A panel serves 256 cols, B serves 256 rows).
template<typename TO, int ACT, int RES>
__global__ __launch_bounds__(1024) void k_gemm_mfma3(const bf16* __restrict__ A, const bf16* __restrict__ W,
                                                     const float* __restrict__ bias, const float* __restrict__ res,
                                                     TO* __restrict__ out, int M, int N, int K){
    __shared__ short As[3][256*32];
    __shared__ short Ws[3][256*32];
    int nbx = (N + 255) >> 8;
    int nwg = gridDim.x;
    int orig = blockIdx.x;
    int xcd = orig & 7, sl = orig >> 3;
    int q8 = nwg >> 3, r8 = nwg & 7;
    int wg = (xcd < r8 ? xcd*(q8+1) : r8*(q8+1) + (xcd - r8)*q8) + sl;
    int by = wg / nbx;
    int bm = by*256, bn = (wg - by*nbx)*256;
    int tid = threadIdx.x, wid = tid>>6, lane = tid&63, quad = lane>>4, l16 = lane&15;
    int wr = (wid>>2)*64, wc = (wid&3)*64;
    fx4 acc[4][4];
    #pragma unroll
    for (int i=0;i<4;i++)
        #pragma unroll
        for (int j=0;j<4;j++) acc[i][j] = (fx4){0.f,0.f,0.f,0.f};
    int lrow = lane>>2;
    int gchunk = (lane&3) ^ ((lane>>3)&3);           // global k-chunk (XOR swizzle)
    int ra0 = bm + wid*16 + lrow; if (ra0 > M-1) ra0 = M-1;
    int rw0 = bn + wid*16 + lrow; if (rw0 > N-1) rw0 = N-1;
    const bf16* pa0 = A + (size_t)ra0*K + gchunk*8;
    const bf16* pw0 = W + (size_t)rw0*K + gchunk*8;
    int sL = (wid*16)*32;            // wave-uniform LDS stripe base
    int slotx = (l16>>1)&3;                          // read-side swizzle component
    int nt = K >> 5;
    #define STAGE2(bsel, t) do { int _k0 = (t) << 5;               \
        gload_lds16(pa0 + _k0, &As[(bsel)][sL]);                   \
        gload_lds16(pw0 + _k0, &Ws[(bsel)][sL]); } while(0)
    STAGE2(0, 0);
    STAGE2(1, 1);
    int cur = 0;
    for (int t = 0; t < nt; ++t){
        if (t + 1 < nt) asm volatile("s_waitcnt vmcnt(2)" ::: "memory");
        else            asm volatile("s_waitcnt vmcnt(0)" ::: "memory");
        __builtin_amdgcn_s_barrier();
        __builtin_amdgcn_sched_barrier(0);
        if (t + 2 < nt){                 // issue next-next tile loads EARLY
            int nb = cur + 2; if (nb >= 3) nb -= 3;
            STAGE2(nb, t + 2);
        }
        const short* Ab = &As[cur][0];
        const short* Wb = &Ws[cur][0];
        bh8 af[4], bf_[4];
        int sa = (quad ^ slotx)*8;
        #pragma unroll
        for (int i=0;i<4;i++) af[i]  = *(const bh8*)&Ab[(wr + i*16 + l16)*32 + sa];
        #pragma unroll
        for (int j=0;j<4;j++) bf_[j] = *(const bh8*)&Wb[(wc + j*16 + l16)*32 + sa];
        #pragma unroll
        for (int i=0;i<4;i++)
            #pragma unroll
            for (int j=0;j<4;j++)
                acc[i][j] = __builtin_amdgcn_mfma_f32_16x16x32_bf16(af[i], bf_[j], acc[i][j], 0,0,0);
        cur += 1; if (cur == 3) cur = 0;
    }
    #undef STAGE2
    #pragma unroll
    for (int i=0;i<4;i++){
        #pragma unroll
        for (int r=0;r<4;r++){
            int row = bm + wr + i*16 + quad*4 + r;
            if (row >= M) continue;
            #pragma unroll
            for (int j=0;j<4;j++){
                int col = bn + wc + j*16 + l16;
                if (col >= N) continue;
                float v = acc[i][j][r] + bias[col];
                if (ACT == 1) v = v / (1.0f + __expf(-1.702f*v));
                if (RES) v += res[(size_t)row*N + col];
                stv(out, (size_t)row*N + col, v);
            }
        }
    }
}

// ---------------- flash MFMA attention (semi-swapped: S^T QK^T, LDS P, original PV) ----
#define KSTR 72
__global__ __launch_bounds__(256) void k_attn_mfma(const bf16* __restrict__ qkv, bf16* __restrict__ obuf){
    __shared__ short Ks[2][64*KSTR];   // [k][d] row-major, stride 72
    __shared__ short Vs[2][64*KSTR];   // subtiled for tr-read
    __shared__ short Ps[4*16*KSTR];    // per-wave P strip [16 q][64 k] straight layout
    int id = blockIdx.x;
    int qt = (id>>3) % 9;
    int bh = (id&7) + ((id/72)<<3);
    int h = bh % NHEAD, b = bh / NHEAD;
    int tid = threadIdx.x, wid = tid>>6, lane = tid&63, quad = lane>>4, l16 = lane&15;
    size_t base = (size_t)b*SEQ*2304;
    int q_own = qt*64 + wid*16 + l16;
    int q_cl  = q_own > 512 ? 512 : q_own;
    const bf16* qrow = qkv + base + (size_t)q_cl*2304 + h*HD;
    bh8 qa0 = *(const bh8*)(qrow + quad*8);
    bh8 qa1 = *(const bh8*)(qrow + 32 + quad*8);
    {   // fold softmax scale 1/8 into Q once (exact pow2 scale in bf16)
        union { bh8 v; short s[8]; } u0, u1;
        u0.v = qa0; u1.v = qa1;
        #pragma unroll
        for (int j=0;j<8;j++){
            bf16 a = *(bf16*)&u0.s[j]; u0.s[j] = f2bs(0.125f*b2f(a));
            bf16 c = *(bf16*)&u1.s[j]; u1.s[j] = f2bs(0.125f*b2f(c));
        }
        qa0 = u0.v; qa1 = u1.v;
    }
    fx4 o[4];                      // o[dt][r] = O[q = wid*16+quad*4+r][d = dt*16+l16]
    #pragma unroll
    for (int d=0; d<4; d++) o[d] = (fx4){0.f,0.f,0.f,0.f};
    float mrow = -1e30f, lrow = 0.f;   // per-lane scalars for q(local) = l16
    int srow = tid>>2, d0 = (tid&3)*16;
    int s_st = (srow>>2)*4 + (tid&3);
    int vsb  = (s_st ^ ((srow>>3)<<1))*KSTR + (srow&3)*16;
    short* pw = &Ps[(wid*16 + l16)*KSTR];      // this lane's q row
    const short* prd0 = &Ps[(wid*16+l16)*KSTR + quad*8];
    const short* prd1 = &Ps[(wid*16+l16)*KSTR + 32 + quad*8];
    unsigned vls = (unsigned)(size_t)(__attribute__((address_space(3))) short*)&Vs[0][0] + 2u*l16;
    #define TRA(vb,hf,c,dt) ((vb) + 144u*(unsigned)(((32*(hf) + 8*quad + 4*(c) + (dt)) ^ (8*(hf) + 2*quad))))
    bh8 kv0, kv1, vv0, vv1;
    {
        const bf16* krow = qkv + base + 768 + (size_t)srow*2304 + h*HD + d0;
        kv0 = *(const bh8*)(krow);
        kv1 = *(const bh8*)(krow + 8);
        vv0 = *(const bh8*)(krow + 768);
        vv1 = *(const bh8*)(krow + 776);
    }
    int p = 0;
    for (int kt=0; kt<9; kt++){
        short* KsP = &Ks[p][0];
        short* VsP = &Vs[p][0];
        *(bh8*)&KsP[srow*KSTR + d0]     = kv0;
        *(bh8*)&KsP[srow*KSTR + d0 + 8] = kv1;
        *(bh8*)&VsP[vsb]     = vv0;
        *(bh8*)&VsP[vsb + 8] = vv1;
        __syncthreads();
        if (kt < 8){   // prefetch next tile; latency hides under softmax+PV
            int kg = (kt+1)*64 + srow; if (kg > 512) kg = 512;
            const bf16* krow = qkv + base + 768 + (size_t)kg*2304 + h*HD + d0;
            kv0 = *(const bh8*)(krow);
            kv1 = *(const bh8*)(krow + 8);
            vv0 = *(const bh8*)(krow + 768);
            vv1 = *(const bh8*)(krow + 776);
        }
        unsigned vb = vls + 9216u*(unsigned)p;
        fx4 s[4];    // s[nt][r] = S^T[k = nt*16+quad*4+r][q = l16]
        __builtin_amdgcn_s_setprio(1);
        #pragma unroll
        for (int nt=0; nt<4; nt++){
            bh8 kb0 = *(const bh8*)&KsP[(nt*16+l16)*KSTR + quad*8];
            bh8 kb1 = *(const bh8*)&KsP[(nt*16+l16)*KSTR + 32 + quad*8];
            fx4 a = (fx4){0.f,0.f,0.f,0.f};
            a = __builtin_amdgcn_mfma_f32_16x16x32_bf16(kb0, qa0, a, 0,0,0);
            a = __builtin_amdgcn_mfma_f32_16x16x32_bf16(kb1, qa1, a, 0,0,0);
            s[nt] = a;
        }
        __builtin_amdgcn_s_setprio(0);
        // issue V^T transpose-reads early; latency hides under softmax
        u32x2 tv[16];
        #pragma unroll
        for (int dt=0; dt<4; dt++){
            tv[dt*4+0] = ds_tr16(TRA(vb,0,0,dt));
            tv[dt*4+1] = ds_tr16(TRA(vb,0,1,dt));
            tv[dt*4+2] = ds_tr16(TRA(vb,1,0,dt));
            tv[dt*4+3] = ds_tr16(TRA(vb,1,1,dt));
        }
        if (kt == 8){   // only k==512 valid in last tile: k_local = nt*16+quad*4+r == 0
            #pragma unroll
            for (int nt=0; nt<4; nt++)
                #pragma unroll
                for (int r=0;r<4;r++){
                    bool ok = (nt==0) && (r==0) && (quad==0);
                    s[nt][r] = ok ? s[nt][r] : -1e30f;
                }
        }
        // column (q=l16) max: 15 in-lane + 2 cross-quad rounds
        float ml = s[0][0];
        #pragma unroll
        for (int nt=0; nt<4; nt++)
            #pragma unroll
            for (int r=0;r<4;r++) if (nt|r) ml = fmaxf(ml, s[nt][r]);
        ml = fmaxf(ml, __shfl_xor(ml, 16, 64));
        ml = fmaxf(ml, __shfl_xor(ml, 32, 64));
        if (__any(ml > mrow)){           // exact: skipped only when al==1
            float mn = fmaxf(mrow, ml);
            float al = __expf(mrow - mn);
            mrow = mn;
            lrow *= al;
            // redistribute al to the output-layout q = quad*4+r
            float alr[4];
            #pragma unroll
            for (int r=0;r<4;r++) alr[r] = __shfl(al, quad*4 + r, 16);
            #pragma unroll
            for (int d=0; d<4; d++)
                #pragma unroll
                for (int r=0;r<4;r++) o[d][r] *= alr[r];
        }
        float ps = 0.f;
        #pragma unroll
        for (int nt=0; nt<4; nt++)
            #pragma unroll
            for (int r=0;r<4;r++){
                float pp = __expf(s[nt][r] - mrow);
                s[nt][r] = pp;
                ps += pp;
            }
        ps += __shfl_xor(ps, 16, 64);
        ps += __shfl_xor(ps, 32, 64);
        lrow += ps;
        // pack 4 consecutive k per nt -> one b64 store into Ps[q][k] (straight layout)
        #pragma unroll
        for (int nt=0; nt<4; nt++){
            u32x2 w;
            w[0] = cvtpk_bf16(s[nt][0], s[nt][1]);
            w[1] = cvtpk_bf16(s[nt][2], s[nt][3]);
            *(u32x2*)&pw[nt*16 + quad*4] = w;
        }
        bh8 pa0 = *(const bh8*)prd0;
        bh8 pa1 = *(const bh8*)prd1;
        asm volatile("s_waitcnt lgkmcnt(0)" ::: "memory");
        __builtin_amdgcn_sched_barrier(0);
        __builtin_amdgcn_s_setprio(1);
        #pragma unroll
        for (int dt=0; dt<4; dt++){
            union { u32x4 u; bh8 h; } v0, v1;
            v0.u = (u32x4){tv[dt*4+0][0], tv[dt*4+0][1], tv[dt*4+1][0], tv[dt*4+1][1]};
            v1.u = (u32x4){tv[dt*4+2][0], tv[dt*4+2][1], tv[dt*4+3][0], tv[dt*4+3][1]};
            o[dt] = __builtin_amdgcn_mfma_f32_16x16x32_bf16(pa0, v0.h, o[dt], 0,0,0);
            o[dt] = __builtin_amdgcn_mfma_f32_16x16x32_bf16(pa1, v1.h, o[dt], 0,0,0);
        }
        __builtin_amdgcn_s_setprio(0);
        p ^= 1;
    }
    #undef TRA
    // epilogue: redistribute 1/l to output-layout q = quad*4+r, coalesced global write
    float linv[4];
    #pragma unroll
    for (int r=0;r<4;r++) linv[r] = 1.0f / __shfl(lrow, quad*4 + r, 16);
    #pragma unroll
    for (int r=0;r<4;r++){
        int q = qt*64 + wid*16 + quad*4 + r;
        if (q < SEQ){
            size_t ob = ((size_t)(b*SEQ+q))*CDIM + h*HD;
            #pragma unroll
            for (int dt=0; dt<4; dt++)
                obuf[ob + dt*16 + l16] = __float2bfloat16(o[dt][r]*linv[r]);
        }
    }
}

// x2 = x1 + xffn + 0.5*(ah @ Wa2^T + ba2) -> d_out (fp32); block per row
__global__ __launch_bounds__(256) void k_comb(const bf16* __restrict__ x1, const bf16* __restrict__ xffn,
                                              const float* __restrict__ ah, const float* __restrict__ Wa2,
                                              const float* __restrict__ ba2, float* __restrict__ x2){
    int i = blockIdx.x; int tid = threadIdx.x;
    __shared__ float ar[16];
    if (tid < 16) ar[tid] = ah[(size_t)i*16 + tid];
    __syncthreads();
    for (int c=tid; c<CDIM; c+=256){
        const float* w = Wa2 + (size_t)c*16;
        float a = ba2[c];
        #pragma unroll
        for (int mm=0; mm<16; mm++) a += ar[mm]*w[mm];
        size_t o = (size_t)i*CDIM + c;
        x2[o] = b2f(x1[o]) + b2f(xffn[o]) + 0.5f*a;
    }
}

// ---------------- segment index build (cluster path, single) ----------------
__global__ __launch_bounds__(256) void k_icount(const int* __restrict__ idx, int* __restrict__ cnt, int n){
    int i = blockIdx.x*256 + threadIdx.x;
    if (i < n) atomicAdd(&cnt[idx[i]], 1);
}

__global__ __launch_bounds__(256) void k_iscan(const int* __restrict__ cnt, int* __restrict__ base,
                                               int* __restrict__ cur, int nseg){
    __shared__ int part[256], off[256];
    int t = threadIdx.x;
    int chunk = (nseg + 255) >> 8;
    int j0 = t*chunk, j1 = j0 + chunk; if (j1 > nseg) j1 = nseg;
    int s = 0;
    for (int j=j0; j<j1; j++) s += cnt[j];
    part[t] = s; __syncthreads();
    if (t == 0){ int acc=0; for (int i=0;i<256;i++){ off[i]=acc; acc+=part[i]; } }
    __syncthreads();
    int acc = off[t];
    for (int j=j0; j<j1; j++){ base[j]=acc; cur[j]=acc; acc+=cnt[j]; }
}

__global__ __launch_bounds__(256) void k_iscatter(const int* __restrict__ idx, int* __restrict__ cur,
                                                  int* __restrict__ order, int n){
    int i = blockIdx.x*256 + threadIdx.x;
    if (i < n){
        int pos = atomicAdd(&cur[idx[i]], 1);
        order[pos] = i;
    }
}

// ---------------- batched 6-view index build ----------------
__global__ __launch_bounds__(256) void k_icount6(const int* __restrict__ fgi, int* __restrict__ cnt){
    int g = blockIdx.x*256 + threadIdx.x;            // 0..6*NR-1
    int v = g >> 14;                                 // NR = 16384
    atomicAdd(&cnt[v*D1SEG + fgi[g]], 1);
}

__global__ __launch_bounds__(256) void k_iscan6(const int* __restrict__ cnt, int* __restrict__ base,
                                                int* __restrict__ cur){
    __shared__ int part[256], off[256];
    int v = blockIdx.x;
    const int* c = cnt + v*D1SEG;
    int* bs = base + v*D1SEG;
    int* cu = cur + v*D1SEG;
    int t = threadIdx.x;
    int chunk = (D1SEG + 255) >> 8;
    int j0 = t*chunk, j1 = j0 + chunk; if (j1 > D1SEG) j1 = D1SEG;
    int s = 0;
    for (int j=j0; j<j1; j++) s += c[j];
    part[t] = s; __syncthreads();
    if (t == 0){ int acc=0; for (int i=0;i<256;i++){ off[i]=acc; acc+=part[i]; } }
    __syncthreads();
    int acc = off[t];
    for (int j=j0; j<j1; j++){ bs[j]=acc; cu[j]=acc; acc+=c[j]; }
}

__global__ __launch_bounds__(256) void k_iscatter6(const int* __restrict__ fgi, int* __restrict__ cur,
                                                   int* __restrict__ order){
    int g = blockIdx.x*256 + threadIdx.x;
    int v = g >> 14;
    int pos = atomicAdd(&cur[v*D1SEG + fgi[g]], 1);
    order[(size_t)v*NR + pos] = g & (NR-1);
}

// gather + segment max/mean for cluster path
__global__ __launch_bounds__(256) void k_gather_seg(const float* __restrict__ outx, const int* __restrict__ basep,
                                                    const int* __restrict__ cntp, const int* __restrict__ order,
                                                    float* __restrict__ dst){
    int sg = blockIdx.x; int tid = threadIdx.x;
    int n = cntp[sg], b0 = basep[sg];
    float mx[3] = {-1e30f,-1e30f,-1e30f};
    float sm[3] = {0.f,0.f,0.f};
    for (int r=0; r<n; r++){
        int i = order[b0+r];
        size_t rb = (size_t)(i + (i>>9) + 1)*CDIM;
        #pragma unroll
        for (int j=0;j<3;j++){
            float v = outx[rb + tid + j*256];
            mx[j] = fmaxf(mx[j], v); sm[j] += v;
        }
    }
    float den = (float)(n > 1 ? n : 1);
    size_t db = (size_t)sg*CDIM;
    #pragma unroll
    for (int j=0;j<3;j++)
        dst[db + tid + j*256] = (n > 0 ? mx[j] : 0.f) + sm[j]/den;
}

// per-view: flat = o1@Wp^T + bp + feat, then segment max/mean
__global__ __launch_bounds__(256) void k_gather_flat(const float* __restrict__ outx, const float* __restrict__ o1v,
                                                     const float* __restrict__ Wp, const float* __restrict__ bp,
                                                     const int* __restrict__ basep, const int* __restrict__ cntp,
                                                     const int* __restrict__ order, float* __restrict__ dst){
    int sg = blockIdx.x; int tid = threadIdx.x;
    int n = cntp[sg], b0 = basep[sg];
    float w[3][MIDD], bb[3];
    #pragma unroll
    for (int j=0;j<3;j++){
        int c = tid + j*256;
        bb[j] = bp[c];
        #pragma unroll
        for (int mm=0;mm<MIDD;mm++) w[j][mm] = Wp[(size_t)c*MIDD + mm];
    }
    float mx[3] = {-1e30f,-1e30f,-1e30f};
    float sm[3] = {0.f,0.f,0.f};
    for (int r=0; r<n; r++){
        int i = order[b0+r];
        const float* orow = o1v + (size_t)i*MIDD;
        float ov[MIDD];
        #pragma unroll
        for (int mm=0;mm<MIDD;mm++) ov[mm] = orow[mm];
        size_t rb = (size_t)(i + (i>>9) + 1)*CDIM;
        #pragma unroll
        for (int j=0;j<3;j++){
            float a = bb[j];
            #pragma unroll
            for (int mm=0;mm<MIDD;mm++) a += ov[mm]*w[j][mm];
            a += outx[rb + tid + j*256];
            mx[j] = fmaxf(mx[j], a); sm[j] += a;
        }
    }
    float den = (float)(n > 1 ? n : 1);
    size_t db = (size_t)sg*CDIM;
    #pragma unroll
    for (int j=0;j<3;j++)
        dst[db + tid + j*256] = (n > 0 ? mx[j] : 0.f) + sm[j]/den;
}

// two-stage column stats (widened: 85 row-chunks -> 255 blocks)
__global__ __launch_bounds__(256) void k_colstats_part(const float* __restrict__ in, int rows,
                                                       float* __restrict__ sumv, float* __restrict__ sumsq){
    int c = blockIdx.x*256 + threadIdx.x;
    if (c >= CDIM) return;
    int chunk = (rows + 84) / 85;
    int r0 = blockIdx.y*chunk;
    int r1 = r0 + chunk; if (r1 > rows) r1 = rows;
    float s = 0.0f, s2 = 0.0f;
    for (int r=r0; r<r1; r++){
        float v = in[(size_t)r*CDIM + c];
        s += v; s2 += v*v;
    }
    atomicAdd(&sumv[c], s);
    atomicAdd(&sumsq[c], s2);
}

// BN (stats finalized inline from raw sums) + gelu
template<typename TO>
__global__ __launch_bounds__(256) void k_bngelu2(const float* __restrict__ in, TO* __restrict__ outp,
                                                 const float* __restrict__ sv, const float* __restrict__ sq,
                                                 const float* __restrict__ g, const float* __restrict__ b,
                                                 int n, float invn){
    int i = blockIdx.x*256 + threadIdx.x;
    if (i >= n) return;
    int c = i - (i/CDIM)*CDIM;
    float m = sv[c]*invn;
    float var = sq[c]*invn - m*m;
    float r = rsqrtf(fmaxf(var, 0.0f) + 1e-5f);
    float y = (in[i]-m)*r*g[c] + b[c];
    stv(outp, (size_t)i, 0.5f*y*(1.0f + erff(y*0.70710678118654752f)));
}

// per-view micro attention: block per (segblock, view); 256 threads = 2 head-groups x 128 rows.
#define MSTR 33    // mask row stride in dwords (132 B)
__global__ __launch_bounds__(256) void k_attnv(const float* __restrict__ qkv1a,
                                               const unsigned char* __restrict__ mask,
                                               float* __restrict__ o1all){
    __shared__ float Qs[N1V][13], Ksv[N1V][13], Vsv[N1V][13];
    __shared__ int   Ms[N1V*MSTR];
    int blk = blockIdx.x, v = blockIdx.y;
    int tid = threadIdx.x;
    // stage Q/K/V: threads 0..127, one row each (9 float4 = 36 floats)
    if (tid < N1V){
        const float4* rp = (const float4*)(qkv1a + (size_t)(blk*N1V + tid)*216 + v*36);
        #pragma unroll
        for (int j=0;j<3;j++){
            float4 q4 = rp[j], k4 = rp[3+j], v4 = rp[6+j];
            Qs[tid][j*4+0]=q4.x; Qs[tid][j*4+1]=q4.y; Qs[tid][j*4+2]=q4.z; Qs[tid][j*4+3]=q4.w;
            Ksv[tid][j*4+0]=k4.x; Ksv[tid][j*4+1]=k4.y; Ksv[tid][j*4+2]=k4.z; Ksv[tid][j*4+3]=k4.w;
            Vsv[tid][j*4+0]=v4.x; Vsv[tid][j*4+1]=v4.y; Vsv[tid][j*4+2]=v4.z; Vsv[tid][j*4+3]=v4.w;
        }
    }
    // stage mask tile (16 KB) coalesced, write at stride 132 B
    {
        const int4* mp = (const int4*)(mask + ((size_t)v*NB1 + blk)*N1V*N1V);
        #pragma unroll
        for (int it=0; it<4; it++){
            int e = tid + it*256;            // 0..1023 int4s
            int4 m4 = mp[e];
            int row = e >> 3, c4 = (e & 7)*4;
            Ms[row*MSTR + c4 + 0] = m4.x;
            Ms[row*MSTR + c4 + 1] = m4.y;
            Ms[row*MSTR + c4 + 2] = m4.z;
            Ms[row*MSTR + c4 + 3] = m4.w;
        }
    }
    __syncthreads();
    int n = tid & 127, hg = tid >> 7;
    const float scale = 0.28867513459481287f; // 12^-0.5
    #pragma unroll
    for (int hh=0; hh<3; hh++){
        int h = hg*3 + hh;
        float q0 = Qs[n][h*2], q1 = Qs[n][h*2+1];
        float m = -1e30f;
        #pragma unroll 4
        for (int k4=0; k4<32; k4++){
            int mw = Ms[n*MSTR + k4];
            #pragma unroll
            for (int j=0;j<4;j++){
                int k = k4*4 + j;
                float s = (q0*Ksv[k][h*2] + q1*Ksv[k][h*2+1])*scale + (((mw>>(j*8))&0xFF) ? -100000.0f : 0.0f);
                m = fmaxf(m, s);
            }
        }
        float l = 0.f, o0 = 0.f, o1v = 0.f;
        #pragma unroll 4
        for (int k4=0; k4<32; k4++){
            int mw = Ms[n*MSTR + k4];
            #pragma unroll
            for (int j=0;j<4;j++){
                int k = k4*4 + j;
                float s = (q0*Ksv[k][h*2] + q1*Ksv[k][h*2+1])*scale + (((mw>>(j*8))&0xFF) ? -100000.0f : 0.0f);
                float p = __expf(s - m);
                l += p; o0 += p*Vsv[k][h*2]; o1v += p*Vsv[k][h*2+1];
            }
        }
        float inv = 1.0f/l;
        float* orow = o1all + ((size_t)v*NR + blk*N1V + n)*MIDD + h*2;
        orow[0] = o0*inv; orow[1] = o1v*inv;
    }
}

// cossim + sims-normalize + weighted sum + residual; block per token row; in-place on d_out
__global__ __launch_bounds__(256) void k_final(float* __restrict__ outx, const float* __restrict__ x3d,
                                               const bf16* __restrict__ bnv, const int* __restrict__ cluster,
                                               const int* __restrict__ fgi){
    int i = blockIdx.x; int tid = threadIdx.x;
    int cl = cluster[i];
    const float* xr = x3d + (size_t)cl*CDIM;
    const bf16* pr[NVIEW];
    #pragma unroll
    for (int v=0; v<NVIEW; v++)
        pr[v] = bnv + ((size_t)v*D1SEG + fgi[(size_t)v*NR + i])*CDIM;
    size_t rb = (size_t)(i + (i>>9) + 1)*CDIM;
    float pv[NVIEW][3], ft[3];
    float dotv[NVIEW] = {0,0,0,0,0,0};
    float np2[NVIEW]  = {0,0,0,0,0,0};
    float nx2 = 0.0f;
    #pragma unroll
    for (int j=0; j<3; j++){
        int c = tid + j*256;
        float xv = xr[c]; nx2 += xv*xv;
        ft[j] = outx[rb + c];
        #pragma unroll
        for (int v=0; v<NVIEW; v++){
            float p = b2f(pr[v][c]); pv[v][j] = p;
            dotv[v] += p*xv; np2[v] += p*p;
        }
    }
    __shared__ float part[4*13];
    __shared__ float ssim[NVIEW];
    float vals[13];
    vals[0] = nx2;
    #pragma unroll
    for (int v=0; v<NVIEW; v++){ vals[1+v] = dotv[v]; vals[7+v] = np2[v]; }
    int lane = tid & 63, wid = tid >> 6;
    #pragma unroll
    for (int k=0; k<13; k++){
        float w = vals[k];
        #pragma unroll
        for (int o=32;o;o>>=1) w += __shfl_down(w,o,64);
        if (!lane) part[wid*13 + k] = w;
    }
    __syncthreads();
    if (tid == 0){
        float tot[13];
        #pragma unroll
        for (int k=0; k<13; k++) tot[k] = part[k] + part[13+k] + part[26+k] + part[39+k];
        float nb = fmaxf(sqrtf(tot[0]), 1e-8f);
        float sv[NVIEW]; float ssumv = 0.0f;
        #pragma unroll
        for (int v=0; v<NVIEW; v++){
            float na = fmaxf(sqrtf(tot[7+v]), 1e-8f);
            float cs = tot[1+v] / (na*nb);
            sv[v] = (cs + 1.0f)*0.5f;
            ssumv += sv[v];
        }
        #pragma unroll
        for (int v=0; v<NVIEW; v++) ssim[v] = sv[v]/ssumv;
    }
    __syncthreads();
    #pragma unroll
    for (int j=0; j<3; j++){
        int c = tid + j*256;
        float xs = 0.0f;
        #pragma unroll
        for (int v=0; v<NVIEW; v++) xs += ssim[v]*pv[v][j];
        outx[rb + c] = ft[j] + 0.3f*xs;
    }
}

// ---------------- host launcher ----------------
extern "C" void kernel_launch(void* const* d_in, const int* in_sizes, int n_in,
                              void* d_out, int out_size, void* d_ws, size_t ws_size,
                              hipStream_t stream){
    const float* x     = (const float*)d_in[0];
    const float* ln1g  = (const float*)d_in[1];
    const float* ln1b  = (const float*)d_in[2];
    const float* ln2g  = (const float*)d_in[3];
    const float* ln2b  = (const float*)d_in[4];
    const float* Wqkv  = (const float*)d_in[5];
    const float* bqkv  = (const float*)d_in[6];
    const float* Wo    = (const float*)d_in[7];
    const float* bo    = (const float*)d_in[8];
    const float* Wfc   = (const float*)d_in[9];
    const float* bfc   = (const float*)d_in[10];
    const float* Wproj = (const float*)d_in[11];
    const float* bproj = (const float*)d_in[12];
    const float* Wa1   = (const float*)d_in[13];
    const float* ba1   = (const float*)d_in[14];
    const float* Wa2   = (const float*)d_in[15];
    const float* ba2   = (const float*)d_in[16];
    const float* bn3dg = (const float*)d_in[17];
    const float* bn3db = (const float*)d_in[18];
    const float* bn1dg = (const float*)d_in[19];
    const float* bn1db = (const float*)d_in[20];
    const float* n3g   = (const float*)d_in[21];
    const float* n3b   = (const float*)d_in[22];
    const float* aqw   = (const float*)d_in[23];
    const float* aqb   = (const float*)d_in[24];
    const float* apw   = (const float*)d_in[25];
    const float* apb   = (const float*)d_in[26];
    const int*   cluster = (const int*)d_in[27];
    const int*   fgi     = (const int*)d_in[28];
    const unsigned char* mask = (const unsigned char*)d_in[29];
    float* out = (float*)d_out;
    float* ws  = (float*)d_ws;

    bf16*  yb    = (bf16*)(ws + A_FS);
    bf16*  qkvb  = (bf16*)(ws + B_FS);
    bf16*  hb    = (bf16*)(ws + B_FS);          // FFN hidden chunk (8208 rows)
    bf16*  xffb  = (bf16*)(ws + B_FS + 12607488);
    float* qkv1a = ws + B_FS;                   // phase 2
    float* o1all = ws + B_FS + 3538944;
    float* svs   = ws + B_FS + 4718592;
    bf16*  x1b   = (bf16*)(ws + X1_FS);
    float* ah    = ws + AH_FS;
    int*   icnt  = (int*)(ws + DI_CNT);
    int*   ibase = (int*)(ws + DI_BASE);
    int*   icur  = (int*)(ws + DI_CUR);
    int*   iord  = (int*)(ws + DI_ORD);
    float* x3d   = ws + X3D_FS;
    bf16*  bnv   = (bf16*)(ws + BNV_FS);
    float* statm = ws + STATM_FS;
    float* statr = ws + STATR_FS;
    bf16* WqkvB  = (bf16*)(ws + DW_FS);
    bf16* WoB    = WqkvB + 2304*768;
    bf16* WfcB   = WoB   + 768*768;
    bf16* WprojB = WfcB  + 3072*768;
    bf16* WvB    = (bf16*)(ws + DWV_FS);        // 216x768
    float* bvP   = ws + DWV_FS + 82944;
    bf16* Wa1B   = (bf16*)(ws + DWV_FS + 83200);
    // phase-2 batched view index arrays + stats in the (dead) ah region:
    int*   icnt6  = (int*)(ws + AH_FS);
    int*   ibase6 = icnt6 + 6*D1SEG;
    int*   icur6  = ibase6 + 6*D1SEG;
    int*   iord6  = icur6 + 6*D1SEG;
    float* stat6  = (float*)(iord6 + 6*NR);

    // 0. weight conversion / folding (single fused launch + foldw)
    k_f2b5<<<2048, 256, 0, stream>>>(Wqkv, WqkvB, 2304*768,  Wo, WoB, 768*768,
                                     Wfc, WfcB, 3072*768,    Wproj, WprojB, 768*3072,
                                     Wa1, Wa1B, 16*768);
    k_foldw<<<216, 256, 0, stream>>>(aqw, aqb, n3g, n3b, WvB, bvP);
    // 1. LN1
    k_ln<float><<<NT, 256, 0, stream>>>(x, yb, ln1g, ln1b);
    // 2. qkv GEMM (256x256 16-wave)
    k_gemm_mfma3<bf16,0,0><<<(2304/256)*((NT+255)/256), 1024, 0, stream>>>(yb, WqkvB, bqkv, nullptr, qkvb, NT, 2304, 768);
    // 3. flash attention (1D XCD-affine grid: 8 * 9 * 48 = 3456)
    k_attn_mfma<<<3456, 256, 0, stream>>>(qkvb, yb);
    // 4. o-proj + residual(x) (128x256 8-wave)
    k_gemm_mfma2<bf16,0,1><<<(768/256)*((NT+127)/128), 512, 0, stream>>>(yb, WoB, bo, x, x1b, NT, 768, 768);
    // 5. LN2
    k_ln<bf16><<<NT, 256, 0, stream>>>(x1b, yb, ln2g, ln2b);
    // 6/7. FFN in 2 row-chunks: fc1 at 256x256, proj at 128x128 (more blocks for small N)
    for (int cch=0; cch<2; cch++){
        const bf16* a2 = yb + (size_t)cch*CHROWS*CDIM;
        bf16* xo = xffb + (size_t)cch*CHROWS*CDIM;
        k_gemm_mfma3<bf16,1,0><<<(FFDIM/256)*((CHROWS+255)/256), 1024, 0, stream>>>(a2, WfcB, bfc, nullptr, hb, CHROWS, FFDIM, 768);
        k_gemm_mfma<bf16,0,0><<<(768/128)*((CHROWS+127)/128), 256, 0, stream>>>(hb, WprojB, bproj, nullptr, xo, CHROWS, 768, FFDIM);
    }
    // 8. adapt hidden (tiny N: keep 4-wave kernel)
    k_gemm_mfma<float,1,0><<<1*((NT+127)/128), 256, 0, stream>>>(xffb, Wa1B, ba1, nullptr, ah, NT, 16, 768);
    // 9. combine -> d_out
    k_comb<<<NT, 256, 0, stream>>>(x1b, xffb, ah, Wa2, ba2, out);
    // 10. cluster path
    k_zero<<<32, 256, 0, stream>>>((float*)icnt, NCLUST);
    k_icount<<<NR/256, 256, 0, stream>>>(cluster, icnt, NR);
    k_iscan<<<1, 256, 0, stream>>>(icnt, ibase, icur, NCLUST);
    k_iscatter<<<NR/256, 256, 0, stream>>>(cluster, icur, iord, NR);
    k_gather_seg<<<NCLUST, 256, 0, stream>>>(out, ibase, icnt, iord, x3d);
    k_zero<<<6, 256, 0, stream>>>(statm, 1536);
    k_colstats_part<<<dim3(3, 85), 256, 0, stream>>>(x3d, NCLUST, statm, statr);
    k_bngelu2<float><<<(NCLUST*CDIM+255)/256, 256, 0, stream>>>(x3d, x3d, statm, statr, bn3dg, bn3db,
                                                                NCLUST*CDIM, 1.0f/NCLUST);
    // 11. view shared prep
    k_lnn<<<NR, 256, 0, stream>>>(out, yb);
    k_gemm_mfma<float,0,0><<<2*(NR/128), 256, 0, stream>>>(yb, WvB, bvP, nullptr, qkv1a, NR, 216, 768);
    k_attnv<<<dim3(NB1, NVIEW), 256, 0, stream>>>(qkv1a, mask, o1all);
    // 12. batched 6-view index build (one zero covers idx arrays + stat6), then per-view
    k_zero<<<(220416+255)/256, 256, 0, stream>>>((float*)icnt6, 220416);
    k_icount6<<<6*NR/256, 256, 0, stream>>>(fgi, icnt6);
    k_iscan6<<<6, 256, 0, stream>>>(icnt6, ibase6, icur6);
    k_iscatter6<<<6*NR/256, 256, 0, stream>>>(fgi, icur6, iord6);
    for (int v=0; v<NVIEW; v++){
        k_gather_flat<<<D1SEG, 256, 0, stream>>>(out, o1all + (size_t)v*NR*MIDD,
                                                 apw + (size_t)v*CDIM*MIDD, apb + (size_t)v*CDIM,
                                                 ibase6 + v*D1SEG, icnt6 + v*D1SEG, iord6 + (size_t)v*NR, svs);
        k_colstats_part<<<dim3(3, 85), 256, 0, stream>>>(svs, D1SEG, stat6 + v*1536, stat6 + v*1536 + 768);
        k_bngelu2<bf16><<<(D1SEG*CDIM+255)/256, 256, 0, stream>>>(svs, bnv + (size_t)v*D1SEG*CDIM,
                                                                  stat6 + v*1536, stat6 + v*1536 + 768,
                                                                  bn1dg + v*CDIM, bn1db + v*CDIM,
                                                                  D1SEG*CDIM, 1.0f/D1SEG);
    }
    // 13. final combine
    k_final<<<NR, 256, 0, stream>>>(out, x3d, bnv, cluster, fgi);
}